// Round 1
// baseline (9588.258 us; speedup 1.0000x reference)
//
#include <hip/hip_runtime.h>
#include <math.h>

typedef unsigned short u16;
typedef __bf16 bf16x8 __attribute__((ext_vector_type(8)));
typedef float f32x4 __attribute__((ext_vector_type(4)));
struct alignas(8) u16x4 { u16 x0, x1, x2, x3; };

__device__ __forceinline__ int ufl(int v) { return __builtin_amdgcn_readfirstlane(v); }
__device__ __forceinline__ u16 f2b(float f) {
    unsigned u = __float_as_uint(f);
    return (u16)((u + 0x7FFFu + ((u >> 16) & 1u)) >> 16);   // RNE fp32->bf16
}
__device__ __forceinline__ float b2f(u16 h) { return __uint_as_float(((unsigned)h) << 16); }
__device__ __forceinline__ float ldv(const float* p) { return *p; }
__device__ __forceinline__ float ldv(const u16* p)   { return b2f(*p); }
__device__ __forceinline__ u16 tob(float v) { return f2b(v); }
__device__ __forceinline__ u16 tob(u16 v)   { return v; }

// Force a single 8-byte global store (compiler cannot split a scalar i64
// store; u16x4 struct stores of fresh ALU results get split into 4x
// global_store_short -> 64x/128B-block HBM write amplification).
__device__ __forceinline__ void st_b64(u16* p, u16 a, u16 b, u16 c, u16 d) {
    unsigned lo = (unsigned)a | ((unsigned)b << 16);
    unsigned hi = (unsigned)c | ((unsigned)d << 16);
    *(unsigned long long*)p = (unsigned long long)lo | ((unsigned long long)hi << 32);
}

// ---------------------------------------------------------------------------
// Weight repacks. NOTE: paired u32 stores — sub-dword global stores cost a
// full 128B HBM write block each on gfx950 (round-2 evidence: 65x write amp).
// ---------------------------------------------------------------------------
// forward conv: W[COUT][CIN][25] f32 -> A[25][COUT][CIN] bf16 (ci pairs)
template<int CIN, int COUT>
__global__ __launch_bounds__(256) void rk_fwd(const float* __restrict__ w, u16* __restrict__ a) {
    int j = (blockIdx.x * 256 + threadIdx.x) * 2;
    if (j >= 25 * COUT * CIN) return;
    int ci = j % CIN; int r = j / CIN; int co = r % COUT; int t = r / COUT;
    u16 lo = f2b(w[(co * CIN + ci) * 25 + t]);
    u16 hi = f2b(w[(co * CIN + ci + 1) * 25 + t]);
    *(unsigned*)&a[j] = (unsigned)lo | ((unsigned)hi << 16);
}
// deconv1 (s1 gather): W[320ci][256co][25] -> A[t'][256co][320ci], t'=(4-ky)*5+(4-kx)
__global__ __launch_bounds__(256) void rk_d1(const float* __restrict__ w, u16* __restrict__ a) {
    int j = (blockIdx.x * 256 + threadIdx.x) * 2;
    if (j >= 25 * 256 * 320) return;
    int ci = j % 320; int r = j / 320; int co = r % 256; int tp = r / 256;
    int ky = 4 - tp / 5, kx = 4 - tp % 5;
    u16 lo = f2b(w[(ci * 256 + co) * 25 + ky * 5 + kx]);
    u16 hi = f2b(w[((ci + 1) * 256 + co) * 25 + ky * 5 + kx]);
    *(unsigned*)&a[j] = (unsigned)lo | ((unsigned)hi << 16);
}
// deconv2 (s2 parity): W[256ci][256co][25] -> A2[q*9+tt][256co][256ci], zero invalid taps
__global__ __launch_bounds__(256) void rk_d2(const float* __restrict__ w, u16* __restrict__ a) {
    int j = (blockIdx.x * 256 + threadIdx.x) * 2;
    if (j >= 36 * 256 * 256) return;
    int ci = j % 256; int r = j / 256; int co = r % 256; int qt = r / 256;
    int q = qt / 9, tt = qt % 9;
    int qy = q >> 1, qx = q & 1, ty = tt / 3, tx = tt % 3;
    u16 lo = 0, hi = 0;
    if (ty < 3 - qy && tx < 3 - qx) {
        int widx = (qy + 2 * ty) * 5 + (qx + 2 * tx);
        lo = f2b(w[(ci * 256 + co) * 25 + widx]);
        hi = f2b(w[((ci + 1) * 256 + co) * 25 + widx]);
    }
    *(unsigned*)&a[j] = (unsigned)lo | ((unsigned)hi << 16);
}
// deconv3: W[256ci][2co][25] f32 -> W3r[4q][256ci][2co][16] f32 (9 taps zero-padded)
__global__ __launch_bounds__(256) void rk_d3(const float* __restrict__ w, float* __restrict__ a) {
    int i = blockIdx.x * 256 + threadIdx.x;
    if (i >= 4 * 256 * 2 * 16) return;
    int t = i % 16; int r = i / 16; int co = r % 2; int r2 = r / 2; int ci = r2 % 256; int q = r2 / 256;
    int qy = q >> 1, qx = q & 1;
    float v = 0.f;
    if (t < 9) {
        int ty = t / 3, tx = t % 3;
        if (ty < 3 - qy && tx < 3 - qx) v = w[(ci * 2 + co) * 25 + (qy + 2 * ty) * 5 + (qx + 2 * tx)];
    }
    a[i] = v;
}

// ---------------------------------------------------------------------------
// MFMA implicit-GEMM conv (k=5 pad=2 stride S in {1,2}), out 8x8 per image.
// (unchanged from round 2 — f32 dword stores, no amplification)
// ---------------------------------------------------------------------------
template<int CIN, int COUT, int S, int MT, typename TIN>
__global__ __launch_bounds__(256)
void mconv(const TIN* __restrict__ in, const u16* __restrict__ A,
           const float* __restrict__ bias, float* __restrict__ out)
{
    constexpr int HIN = 8 * S, HP = 7 * S + 5, CHUNK = 64, STRIDE = CHUNK + 8;
    constexpr int NCH = CIN / CHUNK;
    constexpr int SP = HP * HP;
    __shared__ u16 bs[SP * STRIDE];

    const int b = blockIdx.x;
    const int tid = threadIdx.x;
    const int lane = tid & 63, wv = tid >> 6;
    const int lm = lane & 15, quad = lane >> 4;
    const int cob = wv * (MT * 16);
    const TIN* inb = in + (size_t)b * CIN * (HIN * HIN);

    int bofs[4];
#pragma unroll
    for (int nt = 0; nt < 4; ++nt) {
        int px = nt * 16 + lm, oy = px >> 3, ox = px & 7;
        bofs[nt] = (S * oy * HP + S * ox) * STRIDE + quad * 8;
    }

    f32x4 acc[MT][4];
#pragma unroll
    for (int m = 0; m < MT; ++m)
#pragma unroll
        for (int n = 0; n < 4; ++n) acc[m][n] = (f32x4){0.f, 0.f, 0.f, 0.f};

#pragma unroll 1
    for (int ch = 0; ch < NCH; ++ch) {
        if (ch) __syncthreads();
        unsigned* bz = (unsigned*)bs;
        for (int i = tid; i < SP * STRIDE / 2; i += 256) bz[i] = 0u;
        __syncthreads();
        for (int i = tid; i < (CHUNK / 4) * (HIN * HIN); i += 256) {
            int px = i % (HIN * HIN), cg = i / (HIN * HIN);
            int iy = px / HIN, ix = px % HIN;
            const TIN* ip = inb + (size_t)(ch * CHUNK + cg * 4) * (HIN * HIN) + px;
            u16x4 p;
            p.x0 = tob(ip[0]);
            p.x1 = tob(ip[HIN * HIN]);
            p.x2 = tob(ip[2 * HIN * HIN]);
            p.x3 = tob(ip[3 * HIN * HIN]);
            *(u16x4*)&bs[((iy + 2) * HP + ix + 2) * STRIDE + cg * 4] = p;
        }
        __syncthreads();

#pragma unroll 1
        for (int tap = 0; tap < 25; ++tap) {
            const int ky = tap / 5, kx = tap % 5;
            const int tofs = (ky * HP + kx) * STRIDE;
            const u16* At = A + (size_t)tap * COUT * CIN + ch * CHUNK + quad * 8;
#pragma unroll
            for (int kc = 0; kc < CHUNK / 32; ++kc) {
                bf16x8 bf[4];
#pragma unroll
                for (int nt = 0; nt < 4; ++nt)
                    bf[nt] = *(const bf16x8*)&bs[bofs[nt] + tofs + kc * 32];
                bf16x8 af[MT];
#pragma unroll
                for (int m = 0; m < MT; ++m)
                    af[m] = *(const bf16x8*)(At + (size_t)(cob + m * 16 + lm) * CIN + kc * 32);
#pragma unroll
                for (int m = 0; m < MT; ++m)
#pragma unroll
                    for (int nt = 0; nt < 4; ++nt)
                        acc[m][nt] = __builtin_amdgcn_mfma_f32_16x16x32_bf16(af[m], bf[nt], acc[m][nt], 0, 0, 0);
            }
        }
    }

    float* ob = out + (size_t)b * COUT * 64;
#pragma unroll
    for (int m = 0; m < MT; ++m)
#pragma unroll
        for (int nt = 0; nt < 4; ++nt) {
            int px = nt * 16 + lm;
#pragma unroll
            for (int r = 0; r < 4; ++r) {
                int co = cob + m * 16 + quad * 4 + r;
                ob[(size_t)co * 64 + px] = acc[m][nt][r] + bias[co];
            }
        }
}

// ---------------------------------------------------------------------------
// MFMA ConvTranspose2d k=5 s=2, 8x8 -> 16x16, 256->256, out bf16 QUADRANT-PLANAR:
// d2[b][q][co][sp] (sp = sy*8+sx). Each quadrant's output = one contiguous
// 32 KB chunk -> LDS bounce + single-u64 packed stores (no sub-dword stores).
// ---------------------------------------------------------------------------
__global__ __launch_bounds__(256)
void mdeconv2(const float* __restrict__ in, const u16* __restrict__ A2,
              const float* __restrict__ bias, u16* __restrict__ out)
{
    constexpr int STRIDE = 264;
    __shared__ u16 bs[100 * STRIDE];
    __shared__ u16 os[256 * 64];
    const int b = blockIdx.x, tid = threadIdx.x;
    const int lane = tid & 63, wv = tid >> 6, lm = lane & 15, quad = lane >> 4;
    const int cob = wv * 64;
    const float* inb = in + (size_t)b * 256 * 64;

    unsigned* bz = (unsigned*)bs;
    for (int i = tid; i < 100 * STRIDE / 2; i += 256) bz[i] = 0u;
    __syncthreads();
    for (int i = tid; i < 64 * 64; i += 256) {
        int px = i & 63, cg = i >> 6;
        int iy = px >> 3, ix = px & 7;
        const float* ip = inb + (size_t)cg * 4 * 64 + px;
        u16x4 p;
        p.x0 = f2b(ip[0]); p.x1 = f2b(ip[64]); p.x2 = f2b(ip[128]); p.x3 = f2b(ip[192]);
        *(u16x4*)&bs[((iy + 1) * 10 + ix + 1) * STRIDE + cg * 4] = p;
    }
    __syncthreads();

    int bofs[4];
#pragma unroll
    for (int nt = 0; nt < 4; ++nt) {
        int sp = nt * 16 + lm, sy = sp >> 3, sx = sp & 7;
        bofs[nt] = ((sy + 2) * 10 + sx + 2) * STRIDE + quad * 8;
    }

#pragma unroll
    for (int qy = 0; qy < 2; ++qy)
#pragma unroll
        for (int qx = 0; qx < 2; ++qx) {
            const int q = qy * 2 + qx;
            f32x4 acc[4][4];
#pragma unroll
            for (int m = 0; m < 4; ++m)
#pragma unroll
                for (int n = 0; n < 4; ++n) acc[m][n] = (f32x4){0.f, 0.f, 0.f, 0.f};

            const int NT = (3 - qy) * (3 - qx);
#pragma unroll 1
            for (int tt = 0; tt < NT; ++tt) {
                const int ty = tt / (3 - qx), tx = tt % (3 - qx);
                const int tofs = -(ty * 10 + tx) * STRIDE;
                const u16* At = A2 + (size_t)(q * 9 + ty * 3 + tx) * 256 * 256 + quad * 8;
#pragma unroll
                for (int kc = 0; kc < 8; ++kc) {
                    bf16x8 bf[4];
#pragma unroll
                    for (int nt = 0; nt < 4; ++nt)
                        bf[nt] = *(const bf16x8*)&bs[bofs[nt] + tofs + kc * 32];
                    bf16x8 af[4];
#pragma unroll
                    for (int m = 0; m < 4; ++m)
                        af[m] = *(const bf16x8*)(At + (size_t)(cob + m * 16 + lm) * 256 + kc * 32);
#pragma unroll
                    for (int m = 0; m < 4; ++m)
#pragma unroll
                        for (int nt = 0; nt < 4; ++nt)
                            acc[m][nt] = __builtin_amdgcn_mfma_f32_16x16x32_bf16(af[m], bf[nt], acc[m][nt], 0, 0, 0);
                }
            }
            // bounce fragments -> LDS -> contiguous single-u64 packed stores
#pragma unroll
            for (int m = 0; m < 4; ++m)
#pragma unroll
                for (int nt = 0; nt < 4; ++nt)
#pragma unroll
                    for (int r = 0; r < 4; ++r) {
                        int co = cob + m * 16 + quad * 4 + r;
                        os[co * 64 + nt * 16 + lm] = f2b(acc[m][nt][r] + bias[co]);
                    }
            __syncthreads();
            u16* od = out + ((size_t)(b * 4 + q)) * 256 * 64;
            const unsigned* osw = (const unsigned*)os;
#pragma unroll
            for (int it = 0; it < 16; ++it) {
                int v = it * 256 + tid;
                unsigned lo = osw[v * 2], hi = osw[v * 2 + 1];
                *(unsigned long long*)&od[v * 4] =
                    (unsigned long long)lo | ((unsigned long long)hi << 32);
            }
            __syncthreads();
        }
}

// ---------------------------------------------------------------------------
// deconv3 (VALU): ConvTranspose2d s2, 256->2, 16x16 -> 32x32, clip [0,1].
// Input d2 bf16 QUADRANT-PLANAR [b][q][ci][sp]. f32 dword output stores.
// ---------------------------------------------------------------------------
__global__ __launch_bounds__(256)
void dec3k(const u16* __restrict__ in, const float* __restrict__ W3r,
           const float* __restrict__ bias, float* __restrict__ out)
{
    constexpr int HT = 18;
    __shared__ float ls[32 * HT * HT];
    const int b = blockIdx.x, tid = threadIdx.x;
    const int sy = tid >> 4, sx = tid & 15;
    const u16* inb = in + (size_t)b * 4 * 256 * 64;
    float acc[4][2] = {};
#pragma unroll 1
    for (int ch = 0; ch < 8; ++ch) {
        if (ch) __syncthreads();
        for (int i = tid; i < 32 * HT * HT; i += 256) ls[i] = 0.f;
        __syncthreads();
        for (int i = tid; i < 32 * 256; i += 256) {
            int ci = i >> 8, px = i & 255, iy = px >> 4, ix = px & 15;
            int q = (iy & 1) * 2 + (ix & 1);
            int sp = (iy >> 1) * 8 + (ix >> 1);
            ls[ci * (HT * HT) + (iy + 1) * HT + ix + 1] =
                b2f(inb[((size_t)q * 256 + ch * 32 + ci) * 64 + sp]);
        }
        __syncthreads();
#pragma unroll 1
        for (int ci = 0; ci < 32; ++ci) {
            float v[9];
            const float* l = &ls[ci * (HT * HT) + (sy + 2) * HT + sx + 2];
#pragma unroll
            for (int ty = 0; ty < 3; ++ty)
#pragma unroll
                for (int tx = 0; tx < 3; ++tx) v[ty * 3 + tx] = l[-(ty * HT) - tx];
#pragma unroll
            for (int q = 0; q < 4; ++q) {
                const float* wp = W3r + (size_t)ufl(((q * 256 + ch * 32 + ci) * 2) * 16);
#pragma unroll
                for (int t = 0; t < 9; ++t) {
                    acc[q][0] = fmaf(wp[t], v[t], acc[q][0]);
                    acc[q][1] = fmaf(wp[16 + t], v[t], acc[q][1]);
                }
            }
        }
    }
    float* ob = out + (size_t)b * 2 * 1024;
#pragma unroll
    for (int q = 0; q < 4; ++q) {
        int qy = q >> 1, qx = q & 1;
        int oy = 2 * sy + qy, ox = 2 * sx + qx;
#pragma unroll
        for (int co = 0; co < 2; ++co) {
            float r = acc[q][co] + bias[co];
            r = fminf(fmaxf(r, 0.f), 1.f);
            ob[(size_t)co * 1024 + oy * 32 + ox] = r;
        }
    }
}

// ---------------------------------------------------------------------------
// conv1: direct conv (CIN=2). bf16 output bounced through LDS -> packed u64
// stores. Only instantiated with PX==256, NCOG==1.
// ---------------------------------------------------------------------------
template<int CIN, int COUT, int HIN, int WIN, int S, int CI_CHUNK, int CO_PER_BLOCK>
__global__ __launch_bounds__(256)
void conv5k(const float* __restrict__ in, const float* __restrict__ wt,
            const float* __restrict__ bias, u16* __restrict__ out)
{
    constexpr int HOUT = HIN / S, WOUT = WIN / S;
    constexpr int PX = HOUT * WOUT;          // 256
    constexpr int CO_ITERS = CO_PER_BLOCK;   // 16
    constexpr int HT = HIN + 4, WT = WIN + 4;
    constexpr int NCHUNK = CIN / CI_CHUNK;
    constexpr int TILE = CI_CHUNK * HT * WT;

    __shared__ float lds[TILE];
    __shared__ u16 os[CO_PER_BLOCK * PX];

    const int b = blockIdx.x;
    const int co_base = blockIdx.y * CO_PER_BLOCK;
    const int tid = threadIdx.x;
    const int px = tid;
    const int oy = px / WOUT, ox = px % WOUT;

    float acc[CO_ITERS];
#pragma unroll
    for (int i = 0; i < CO_ITERS; ++i) acc[i] = 0.f;

    const float* inb = in + (size_t)b * CIN * HIN * WIN;

#pragma unroll 1
    for (int ch = 0; ch < NCHUNK; ++ch) {
        if (ch) __syncthreads();
        for (int idx = tid; idx < TILE; idx += 256) lds[idx] = 0.f;
        __syncthreads();
        for (int idx = tid; idx < CI_CHUNK * HIN * WIN; idx += 256) {
            int ci = idx / (HIN * WIN);
            int r = idx - ci * (HIN * WIN);
            int iy = r / WIN, ix = r - iy * WIN;
            lds[ci * (HT * WT) + (iy + 2) * WT + (ix + 2)] =
                inb[(size_t)(ch * CI_CHUNK + ci) * (HIN * WIN) + r];
        }
        __syncthreads();

#pragma unroll 1
        for (int ci = 0; ci < CI_CHUNK; ++ci) {
            float v[25];
            const float* l = &lds[ci * (HT * WT) + (oy * S) * WT + (ox * S)];
#pragma unroll
            for (int ky = 0; ky < 5; ++ky)
#pragma unroll
                for (int kx = 0; kx < 5; ++kx)
                    v[ky * 5 + kx] = l[ky * WT + kx];
#pragma unroll
            for (int i = 0; i < CO_ITERS; ++i) {
                const int co = co_base + i;
                const float* wp = wt + (size_t)ufl((co * CIN + ch * CI_CHUNK + ci) * 25);
#pragma unroll
                for (int t = 0; t < 25; ++t) acc[i] = fmaf(wp[t], v[t], acc[i]);
            }
        }
    }

#pragma unroll
    for (int i = 0; i < CO_ITERS; ++i)
        os[i * PX + px] = f2b(acc[i] + bias[co_base + i]);
    __syncthreads();
    u16* ob = out + ((size_t)b * COUT + co_base) * PX;
    const unsigned* osw = (const unsigned*)os;
#pragma unroll
    for (int it = 0; it < CO_PER_BLOCK * PX / 1024; ++it) {
        int v = it * 256 + tid;
        unsigned lo = osw[v * 2], hi = osw[v * 2 + 1];
        *(unsigned long long*)&ob[v * 4] =
            (unsigned long long)lo | ((unsigned long long)hi << 32);
    }
}

// ---------------------------------------------------------------------------
// GDN f32 (in-place, dword stores — fine). Used for a2 / d1 (P_IMG=64).
// ---------------------------------------------------------------------------
template<typename T, int P_IMG, bool INVERSE>
__global__ __launch_bounds__(256)
void gdnk(T* __restrict__ x, const float* __restrict__ beta,
          const float* __restrict__ gamma)
{
    __shared__ float xs[256 * 64];
    const int b = blockIdx.x;
    const int pb = blockIdx.y * 64;
    const int tid = threadIdx.x;
    const int px = tid & 63;
    const int og = tid >> 6;

    T* xb = x + (size_t)b * 256 * P_IMG + pb;

#pragma unroll 4
    for (int k = 0; k < 64; ++k) {
        const int c = og + 4 * k;
        xs[c * 64 + px] = ldv(&xb[(size_t)c * P_IMG + px]);
    }
    __syncthreads();

    const int co0 = og * 64;
    float acc[64];
#pragma unroll
    for (int k = 0; k < 64; ++k) acc[k] = beta[ufl(co0 + k)];

#pragma unroll 1
    for (int cc = 0; cc < 32; ++cc) {
        float xv[8];
#pragma unroll
        for (int u = 0; u < 8; ++u) {
            float t = xs[(cc * 8 + u) * 64 + px];
            xv[u] = t * t;
        }
#pragma unroll
        for (int k = 0; k < 64; ++k) {
            const float* g = gamma + (size_t)ufl((co0 + k) * 256 + cc * 8);
#pragma unroll
            for (int u = 0; u < 8; ++u) acc[k] = fmaf(g[u], xv[u], acc[k]);
        }
    }

#pragma unroll 4
    for (int k = 0; k < 64; ++k) {
        const float n = acc[k];
        const float r = INVERSE ? sqrtf(n) : rsqrtf(n);
        xb[(size_t)(co0 + k) * P_IMG + px] = xs[(co0 + k) * 64 + px] * r;
    }
}

// ---------------------------------------------------------------------------
// GDN bf16 (in-place) with single-u64 packed global I/O through the LDS tile.
// PLANAR=false: x is [b][256][256], block = (b, 64-px slice), row stride 256.
// PLANAR=true : x is [b*4+q][256][64] (quadrant-planar d2), row stride 64.
// Grid (1024, 4) in both cases.
// NOTE: previous u16x4 struct stores of fresh f2b() results compiled to 4x
// global_store_short -> 66x HBM write amplification (round-3 counters:
// WRITE_SIZE 8.7e6 KB for a 134 MB tensor). u64 pack forces dwordx2.
// ---------------------------------------------------------------------------
template<bool INVERSE, bool PLANAR>
__global__ __launch_bounds__(256)
void gdnk16(u16* __restrict__ x, const float* __restrict__ beta,
            const float* __restrict__ gamma)
{
    constexpr int RS = PLANAR ? 64 : 256;
    __shared__ float xs[256 * 64];
    const int tid = threadIdx.x;
    u16* xb = x + (size_t)blockIdx.x * 65536 + (size_t)blockIdx.y * (PLANAR ? 16384 : 64);

#pragma unroll
    for (int it = 0; it < 16; ++it) {
        int v = it * 256 + tid;
        int ch = v >> 4, pxg = (v & 15) * 4;
        unsigned long long q = *(const unsigned long long*)&xb[(size_t)ch * RS + pxg];
        f32x4 f = {b2f((u16)q), b2f((u16)(q >> 16)), b2f((u16)(q >> 32)), b2f((u16)(q >> 48))};
        *(f32x4*)&xs[ch * 64 + pxg] = f;
    }
    __syncthreads();

    const int px = tid & 63, og = tid >> 6, co0 = og * 64;
    float acc[64];
#pragma unroll
    for (int k = 0; k < 64; ++k) acc[k] = beta[ufl(co0 + k)];

#pragma unroll 1
    for (int cc = 0; cc < 32; ++cc) {
        float xv[8];
#pragma unroll
        for (int u = 0; u < 8; ++u) {
            float t = xs[(cc * 8 + u) * 64 + px];
            xv[u] = t * t;
        }
#pragma unroll
        for (int k = 0; k < 64; ++k) {
            const float* g = gamma + (size_t)ufl((co0 + k) * 256 + cc * 8);
#pragma unroll
            for (int u = 0; u < 8; ++u) acc[k] = fmaf(g[u], xv[u], acc[k]);
        }
    }

    // in-place multiply in LDS (each element owned by exactly one thread)
#pragma unroll 4
    for (int k = 0; k < 64; ++k) {
        const float n = acc[k];
        const float r = INVERSE ? sqrtf(n) : rsqrtf(n);
        xs[(co0 + k) * 64 + px] *= r;
    }
    __syncthreads();

#pragma unroll
    for (int it = 0; it < 16; ++it) {
        int v = it * 256 + tid;
        int ch = v >> 4, pxg = (v & 15) * 4;
        f32x4 f = *(const f32x4*)&xs[ch * 64 + pxg];
        st_b64(&xb[(size_t)ch * RS + pxg], f2b(f[0]), f2b(f[1]), f2b(f[2]), f2b(f[3]));
    }
}

// ---------------------------------------------------------------------------
// Fused context model (unchanged, verified).
// ---------------------------------------------------------------------------
__global__ __launch_bounds__(256)
void trik(float* __restrict__ y, const float* __restrict__ noise,
          const float* __restrict__ H, const float* __restrict__ mean,
          const float* __restrict__ scale, float* __restrict__ lik)
{
    __shared__ float h[64 * 65];
    const int c = blockIdx.x;
    const int bt = blockIdx.y;
    const int tid = threadIdx.x;
    const int lane = tid & 63;
    const int wv = tid >> 6;

    const float* Hc = H + (size_t)c * 4096;
    for (int idx = tid; idx < 4096; idx += 256) {
        const int i = idx >> 6, j = idx & 63;
        h[i * 65 + j] = Hc[idx];
    }
    __syncthreads();

    const int b = bt * 4 + wv;
    const size_t base = ((size_t)b * 320 + c) * 64 + lane;
    const float* hrow = &h[lane * 65];

    const float yv = y[base];
    float ws = 0.f;
#pragma unroll 8
    for (int j = 0; j < 64; ++j) {
        const float yj = __shfl(yv, j, 64);
        const float hv = (j < lane) ? hrow[j] : 0.f;
        ws = fmaf(hv, yj, ws);
    }
    const float wh = yv - ws + noise[base];

    const float mn = mean[c * 64 + lane];
    const float sc = fmaxf(scale[c * 64 + lane], 0.11f);
    const float vv = fabsf(wh - mn);
    const float cst = -0.70710678118654752f;
    const float upper = 0.5f * erfcf(cst * (0.5f - vv) / sc);
    const float lower = 0.5f * erfcf(cst * (-0.5f - vv) / sc);
    lik[base] = fmaxf(upper - lower, 1e-9f);

    float acc = wh;
#pragma unroll 8
    for (int j = 0; j < 64; ++j) {
        const float yj = __shfl(acc, j, 64);
        const float hv = (j < lane) ? hrow[j] : 0.f;
        acc = fmaf(hv, yj, acc);
    }
    y[base] = acc;
}

// ---------------------------------------------------------------------------
extern "C" void kernel_launch(void* const* d_in, const int* in_sizes, int n_in,
                              void* d_out, int out_size, void* d_ws, size_t ws_size,
                              hipStream_t stream)
{
    (void)in_sizes; (void)n_in; (void)out_size; (void)ws_size;

    const float* x      = (const float*)d_in[0];
    const float* noise  = (const float*)d_in[1];
    const float* w1     = (const float*)d_in[2];
    const float* b1     = (const float*)d_in[3];
    const float* beta1  = (const float*)d_in[4];
    const float* gamma1 = (const float*)d_in[5];
    const float* w2     = (const float*)d_in[6];
    const float* b2     = (const float*)d_in[7];
    const float* beta2  = (const float*)d_in[8];
    const float* gamma2 = (const float*)d_in[9];
    const float* w3     = (const float*)d_in[10];
    const float* b3     = (const float*)d_in[11];
    const float* dw1    = (const float*)d_in[12];
    const float* db1    = (const float*)d_in[13];
    const float* ibeta1 = (const float*)d_in[14];
    const float* igamma1= (const float*)d_in[15];
    const float* dw2    = (const float*)d_in[16];
    const float* db2    = (const float*)d_in[17];
    const float* ibeta2 = (const float*)d_in[18];
    const float* igamma2= (const float*)d_in[19];
    const float* dw3    = (const float*)d_in[20];
    const float* db3    = (const float*)d_in[21];
    const float* mean   = (const float*)d_in[22];
    const float* scale  = (const float*)d_in[23];
    const float* H      = (const float*)d_in[24];

    float* outp = (float*)d_out;
    float* xhat = outp;                                   // [1024,2,32,32]
    float* lik  = outp + (size_t)1024 * 2 * 32 * 32;      // [1024,320,64]

    // workspace layout (peak 217.6 MB):
    //   [0, 134.2M)      a1 bf16 -> y f32 -> d2 bf16 (quadrant-planar)
    //   [134.2M, 201.3M) a2 f32 -> d1 f32
    //   [201.3M, 217.6M) repacked weights (live whole call)
    char* ws = (char*)d_ws;
    u16*   a1  = (u16*)ws;
    float* a2  = (float*)(ws + 134217728);
    float* y   = (float*)ws;
    float* d1  = (float*)(ws + 134217728);
    u16*   d2  = (u16*)ws;
    u16*   Ac2 = (u16*)(ws + 201326592);
    u16*   Ac3 = (u16*)(ws + 204603392);
    u16*   Ad1 = (u16*)(ws + 208699392);
    u16*   Ad2 = (u16*)(ws + 212795392);
    float* W3r = (float*)(ws + 217513984);

    // ---- weight repacks (paired u32 stores) ----
    rk_fwd<256, 256><<<3200, 256, 0, stream>>>(w2, Ac2);
    rk_fwd<256, 320><<<4000, 256, 0, stream>>>(w3, Ac3);
    rk_d1<<<4000, 256, 0, stream>>>(dw1, Ad1);
    rk_d2<<<4608, 256, 0, stream>>>(dw2, Ad2);
    rk_d3<<<128, 256, 0, stream>>>(dw3, W3r);

    // ---- analysis ----
    conv5k<2, 256, 32, 32, 2, 2, 16><<<dim3(1024, 16), 256, 0, stream>>>(x, w1, b1, a1);
    gdnk16<false, false><<<dim3(1024, 4), 256, 0, stream>>>(a1, beta1, gamma1);
    mconv<256, 256, 2, 4, u16><<<1024, 256, 0, stream>>>(a1, Ac2, b2, a2);
    gdnk<float, 64, false><<<dim3(1024, 1), 256, 0, stream>>>(a2, beta2, gamma2);
    mconv<256, 320, 1, 5, float><<<1024, 256, 0, stream>>>(a2, Ac3, b3, y);

    // ---- context model ----
    trik<<<dim3(320, 256), 256, 0, stream>>>(y, noise, H, mean, scale, lik);

    // ---- synthesis ----
    mconv<320, 256, 1, 4, float><<<1024, 256, 0, stream>>>(y, Ad1, db1, d1);
    gdnk<float, 64, true><<<dim3(1024, 1), 256, 0, stream>>>(d1, ibeta1, igamma1);
    mdeconv2<<<1024, 256, 0, stream>>>(d1, Ad2, db2, d2);
    gdnk16<true, true><<<dim3(1024, 4), 256, 0, stream>>>(d2, ibeta2, igamma2);
    dec3k<<<1024, 256, 0, stream>>>(d2, W3r, db3, xhat);
}

// Round 2
// 8177.764 us; speedup vs baseline: 1.1725x; 1.1725x over previous
//
#include <hip/hip_runtime.h>
#include <math.h>

typedef unsigned short u16;
typedef __bf16 bf16x8 __attribute__((ext_vector_type(8)));
typedef float f32x4 __attribute__((ext_vector_type(4)));
struct alignas(8) u16x4 { u16 x0, x1, x2, x3; };

__device__ __forceinline__ int ufl(int v) { return __builtin_amdgcn_readfirstlane(v); }
__device__ __forceinline__ u16 f2b(float f) {
    unsigned u = __float_as_uint(f);
    return (u16)((u + 0x7FFFu + ((u >> 16) & 1u)) >> 16);   // RNE fp32->bf16
}
__device__ __forceinline__ float b2f(u16 h) { return __uint_as_float(((unsigned)h) << 16); }
__device__ __forceinline__ float ldv(const float* p) { return *p; }
__device__ __forceinline__ float ldv(const u16* p)   { return b2f(*p); }
__device__ __forceinline__ u16 tob(float v) { return f2b(v); }
__device__ __forceinline__ u16 tob(u16 v)   { return v; }

// ---------------------------------------------------------------------------
// EMPIRICAL RULE (rounds 2/3/4 counters): global bf16 stores are only clean
// when the store loop is a pure dword-granular LDS->global copy. Stores whose
// operands are freshly f2b()-converted ALU values get emitted sub-dword and
// cost one full 128B HBM write block PER ELEMENT (64x write amplification;
// gdnk16 measured 8.56e6 KB WRITE_SIZE for a 134 MB tensor, while conv5k /
// mdeconv2 writing identical tensors through an LDS bounce are clean).
// => every bf16 producer must stage packed u16 in LDS, then copy out as u32/u64.
// ---------------------------------------------------------------------------

// ---------------------------------------------------------------------------
// Weight repacks (paired u32 stores).
// ---------------------------------------------------------------------------
// forward conv: W[COUT][CIN][25] f32 -> A[25][COUT][CIN] bf16 (ci pairs)
template<int CIN, int COUT>
__global__ __launch_bounds__(256) void rk_fwd(const float* __restrict__ w, u16* __restrict__ a) {
    int j = (blockIdx.x * 256 + threadIdx.x) * 2;
    if (j >= 25 * COUT * CIN) return;
    int ci = j % CIN; int r = j / CIN; int co = r % COUT; int t = r / COUT;
    u16 lo = f2b(w[(co * CIN + ci) * 25 + t]);
    u16 hi = f2b(w[(co * CIN + ci + 1) * 25 + t]);
    *(unsigned*)&a[j] = (unsigned)lo | ((unsigned)hi << 16);
}
// deconv1 (s1 gather): W[320ci][256co][25] -> A[t'][256co][320ci], t'=(4-ky)*5+(4-kx)
__global__ __launch_bounds__(256) void rk_d1(const float* __restrict__ w, u16* __restrict__ a) {
    int j = (blockIdx.x * 256 + threadIdx.x) * 2;
    if (j >= 25 * 256 * 320) return;
    int ci = j % 320; int r = j / 320; int co = r % 256; int tp = r / 256;
    int ky = 4 - tp / 5, kx = 4 - tp % 5;
    u16 lo = f2b(w[(ci * 256 + co) * 25 + ky * 5 + kx]);
    u16 hi = f2b(w[((ci + 1) * 256 + co) * 25 + ky * 5 + kx]);
    *(unsigned*)&a[j] = (unsigned)lo | ((unsigned)hi << 16);
}
// deconv2 (s2 parity): W[256ci][256co][25] -> A2[q*9+tt][256co][256ci], zero invalid taps
__global__ __launch_bounds__(256) void rk_d2(const float* __restrict__ w, u16* __restrict__ a) {
    int j = (blockIdx.x * 256 + threadIdx.x) * 2;
    if (j >= 36 * 256 * 256) return;
    int ci = j % 256; int r = j / 256; int co = r % 256; int qt = r / 256;
    int q = qt / 9, tt = qt % 9;
    int qy = q >> 1, qx = q & 1, ty = tt / 3, tx = tt % 3;
    u16 lo = 0, hi = 0;
    if (ty < 3 - qy && tx < 3 - qx) {
        int widx = (qy + 2 * ty) * 5 + (qx + 2 * tx);
        lo = f2b(w[(ci * 256 + co) * 25 + widx]);
        hi = f2b(w[((ci + 1) * 256 + co) * 25 + widx]);
    }
    *(unsigned*)&a[j] = (unsigned)lo | ((unsigned)hi << 16);
}
// deconv3: W[256ci][2co][25] f32 -> W3r[4q][256ci][2co][16] f32 (9 taps zero-padded)
__global__ __launch_bounds__(256) void rk_d3(const float* __restrict__ w, float* __restrict__ a) {
    int i = blockIdx.x * 256 + threadIdx.x;
    if (i >= 4 * 256 * 2 * 16) return;
    int t = i % 16; int r = i / 16; int co = r % 2; int r2 = r / 2; int ci = r2 % 256; int q = r2 / 256;
    int qy = q >> 1, qx = q & 1;
    float v = 0.f;
    if (t < 9) {
        int ty = t / 3, tx = t % 3;
        if (ty < 3 - qy && tx < 3 - qx) v = w[(ci * 2 + co) * 25 + (qy + 2 * ty) * 5 + (qx + 2 * tx)];
    }
    a[i] = v;
}

// ---------------------------------------------------------------------------
// MFMA implicit-GEMM conv (k=5 pad=2 stride S in {1,2}), out 8x8 per image.
// (f32 dword stores, no amplification)
// ---------------------------------------------------------------------------
template<int CIN, int COUT, int S, int MT, typename TIN>
__global__ __launch_bounds__(256)
void mconv(const TIN* __restrict__ in, const u16* __restrict__ A,
           const float* __restrict__ bias, float* __restrict__ out)
{
    constexpr int HIN = 8 * S, HP = 7 * S + 5, CHUNK = 64, STRIDE = CHUNK + 8;
    constexpr int NCH = CIN / CHUNK;
    constexpr int SP = HP * HP;
    __shared__ u16 bs[SP * STRIDE];

    const int b = blockIdx.x;
    const int tid = threadIdx.x;
    const int lane = tid & 63, wv = tid >> 6;
    const int lm = lane & 15, quad = lane >> 4;
    const int cob = wv * (MT * 16);
    const TIN* inb = in + (size_t)b * CIN * (HIN * HIN);

    int bofs[4];
#pragma unroll
    for (int nt = 0; nt < 4; ++nt) {
        int px = nt * 16 + lm, oy = px >> 3, ox = px & 7;
        bofs[nt] = (S * oy * HP + S * ox) * STRIDE + quad * 8;
    }

    f32x4 acc[MT][4];
#pragma unroll
    for (int m = 0; m < MT; ++m)
#pragma unroll
        for (int n = 0; n < 4; ++n) acc[m][n] = (f32x4){0.f, 0.f, 0.f, 0.f};

#pragma unroll 1
    for (int ch = 0; ch < NCH; ++ch) {
        if (ch) __syncthreads();
        unsigned* bz = (unsigned*)bs;
        for (int i = tid; i < SP * STRIDE / 2; i += 256) bz[i] = 0u;
        __syncthreads();
        for (int i = tid; i < (CHUNK / 4) * (HIN * HIN); i += 256) {
            int px = i % (HIN * HIN), cg = i / (HIN * HIN);
            int iy = px / HIN, ix = px % HIN;
            const TIN* ip = inb + (size_t)(ch * CHUNK + cg * 4) * (HIN * HIN) + px;
            u16x4 p;
            p.x0 = tob(ip[0]);
            p.x1 = tob(ip[HIN * HIN]);
            p.x2 = tob(ip[2 * HIN * HIN]);
            p.x3 = tob(ip[3 * HIN * HIN]);
            *(u16x4*)&bs[((iy + 2) * HP + ix + 2) * STRIDE + cg * 4] = p;
        }
        __syncthreads();

#pragma unroll 1
        for (int tap = 0; tap < 25; ++tap) {
            const int ky = tap / 5, kx = tap % 5;
            const int tofs = (ky * HP + kx) * STRIDE;
            const u16* At = A + (size_t)tap * COUT * CIN + ch * CHUNK + quad * 8;
#pragma unroll
            for (int kc = 0; kc < CHUNK / 32; ++kc) {
                bf16x8 bf[4];
#pragma unroll
                for (int nt = 0; nt < 4; ++nt)
                    bf[nt] = *(const bf16x8*)&bs[bofs[nt] + tofs + kc * 32];
                bf16x8 af[MT];
#pragma unroll
                for (int m = 0; m < MT; ++m)
                    af[m] = *(const bf16x8*)(At + (size_t)(cob + m * 16 + lm) * CIN + kc * 32);
#pragma unroll
                for (int m = 0; m < MT; ++m)
#pragma unroll
                    for (int nt = 0; nt < 4; ++nt)
                        acc[m][nt] = __builtin_amdgcn_mfma_f32_16x16x32_bf16(af[m], bf[nt], acc[m][nt], 0, 0, 0);
            }
        }
    }

    float* ob = out + (size_t)b * COUT * 64;
#pragma unroll
    for (int m = 0; m < MT; ++m)
#pragma unroll
        for (int nt = 0; nt < 4; ++nt) {
            int px = nt * 16 + lm;
#pragma unroll
            for (int r = 0; r < 4; ++r) {
                int co = cob + m * 16 + quad * 4 + r;
                ob[(size_t)co * 64 + px] = acc[m][nt][r] + bias[co];
            }
        }
}

// ---------------------------------------------------------------------------
// MFMA ConvTranspose2d k=5 s=2, 8x8 -> 16x16, 256->256, out bf16 QUADRANT-PLANAR:
// d2[b][q][co][sp] (sp = sy*8+sx). LDS bounce -> u32-pair -> u64 stores (clean).
// ---------------------------------------------------------------------------
__global__ __launch_bounds__(256)
void mdeconv2(const float* __restrict__ in, const u16* __restrict__ A2,
              const float* __restrict__ bias, u16* __restrict__ out)
{
    constexpr int STRIDE = 264;
    __shared__ u16 bs[100 * STRIDE];
    __shared__ u16 os[256 * 64];
    const int b = blockIdx.x, tid = threadIdx.x;
    const int lane = tid & 63, wv = tid >> 6, lm = lane & 15, quad = lane >> 4;
    const int cob = wv * 64;
    const float* inb = in + (size_t)b * 256 * 64;

    unsigned* bz = (unsigned*)bs;
    for (int i = tid; i < 100 * STRIDE / 2; i += 256) bz[i] = 0u;
    __syncthreads();
    for (int i = tid; i < 64 * 64; i += 256) {
        int px = i & 63, cg = i >> 6;
        int iy = px >> 3, ix = px & 7;
        const float* ip = inb + (size_t)cg * 4 * 64 + px;
        u16x4 p;
        p.x0 = f2b(ip[0]); p.x1 = f2b(ip[64]); p.x2 = f2b(ip[128]); p.x3 = f2b(ip[192]);
        *(u16x4*)&bs[((iy + 1) * 10 + ix + 1) * STRIDE + cg * 4] = p;
    }
    __syncthreads();

    int bofs[4];
#pragma unroll
    for (int nt = 0; nt < 4; ++nt) {
        int sp = nt * 16 + lm, sy = sp >> 3, sx = sp & 7;
        bofs[nt] = ((sy + 2) * 10 + sx + 2) * STRIDE + quad * 8;
    }

#pragma unroll
    for (int qy = 0; qy < 2; ++qy)
#pragma unroll
        for (int qx = 0; qx < 2; ++qx) {
            const int q = qy * 2 + qx;
            f32x4 acc[4][4];
#pragma unroll
            for (int m = 0; m < 4; ++m)
#pragma unroll
                for (int n = 0; n < 4; ++n) acc[m][n] = (f32x4){0.f, 0.f, 0.f, 0.f};

            const int NT = (3 - qy) * (3 - qx);
#pragma unroll 1
            for (int tt = 0; tt < NT; ++tt) {
                const int ty = tt / (3 - qx), tx = tt % (3 - qx);
                const int tofs = -(ty * 10 + tx) * STRIDE;
                const u16* At = A2 + (size_t)(q * 9 + ty * 3 + tx) * 256 * 256 + quad * 8;
#pragma unroll
                for (int kc = 0; kc < 8; ++kc) {
                    bf16x8 bf[4];
#pragma unroll
                    for (int nt = 0; nt < 4; ++nt)
                        bf[nt] = *(const bf16x8*)&bs[bofs[nt] + tofs + kc * 32];
                    bf16x8 af[4];
#pragma unroll
                    for (int m = 0; m < 4; ++m)
                        af[m] = *(const bf16x8*)(At + (size_t)(cob + m * 16 + lm) * 256 + kc * 32);
#pragma unroll
                    for (int m = 0; m < 4; ++m)
#pragma unroll
                        for (int nt = 0; nt < 4; ++nt)
                            acc[m][nt] = __builtin_amdgcn_mfma_f32_16x16x32_bf16(af[m], bf[nt], acc[m][nt], 0, 0, 0);
                }
            }
            // bounce fragments -> LDS -> contiguous u32-pair -> u64 stores
#pragma unroll
            for (int m = 0; m < 4; ++m)
#pragma unroll
                for (int nt = 0; nt < 4; ++nt)
#pragma unroll
                    for (int r = 0; r < 4; ++r) {
                        int co = cob + m * 16 + quad * 4 + r;
                        os[co * 64 + nt * 16 + lm] = f2b(acc[m][nt][r] + bias[co]);
                    }
            __syncthreads();
            u16* od = out + ((size_t)(b * 4 + q)) * 256 * 64;
            const unsigned* osw = (const unsigned*)os;
#pragma unroll
            for (int it = 0; it < 16; ++it) {
                int v = it * 256 + tid;
                unsigned lo = osw[v * 2], hi = osw[v * 2 + 1];
                *(unsigned long long*)&od[v * 4] =
                    (unsigned long long)lo | ((unsigned long long)hi << 32);
            }
            __syncthreads();
        }
}

// ---------------------------------------------------------------------------
// deconv3 (VALU): ConvTranspose2d s2, 256->2, 16x16 -> 32x32, clip [0,1].
// Input d2 bf16 QUADRANT-PLANAR [b][q][ci][sp]. f32 dword output stores.
// ---------------------------------------------------------------------------
__global__ __launch_bounds__(256)
void dec3k(const u16* __restrict__ in, const float* __restrict__ W3r,
           const float* __restrict__ bias, float* __restrict__ out)
{
    constexpr int HT = 18;
    __shared__ float ls[32 * HT * HT];
    const int b = blockIdx.x, tid = threadIdx.x;
    const int sy = tid >> 4, sx = tid & 15;
    const u16* inb = in + (size_t)b * 4 * 256 * 64;
    float acc[4][2] = {};
#pragma unroll 1
    for (int ch = 0; ch < 8; ++ch) {
        if (ch) __syncthreads();
        for (int i = tid; i < 32 * HT * HT; i += 256) ls[i] = 0.f;
        __syncthreads();
        for (int i = tid; i < 32 * 256; i += 256) {
            int ci = i >> 8, px = i & 255, iy = px >> 4, ix = px & 15;
            int q = (iy & 1) * 2 + (ix & 1);
            int sp = (iy >> 1) * 8 + (ix >> 1);
            ls[ci * (HT * HT) + (iy + 1) * HT + ix + 1] =
                b2f(inb[((size_t)q * 256 + ch * 32 + ci) * 64 + sp]);
        }
        __syncthreads();
#pragma unroll 1
        for (int ci = 0; ci < 32; ++ci) {
            float v[9];
            const float* l = &ls[ci * (HT * HT) + (sy + 2) * HT + sx + 2];
#pragma unroll
            for (int ty = 0; ty < 3; ++ty)
#pragma unroll
                for (int tx = 0; tx < 3; ++tx) v[ty * 3 + tx] = l[-(ty * HT) - tx];
#pragma unroll
            for (int q = 0; q < 4; ++q) {
                const float* wp = W3r + (size_t)ufl(((q * 256 + ch * 32 + ci) * 2) * 16);
#pragma unroll
                for (int t = 0; t < 9; ++t) {
                    acc[q][0] = fmaf(wp[t], v[t], acc[q][0]);
                    acc[q][1] = fmaf(wp[16 + t], v[t], acc[q][1]);
                }
            }
        }
    }
    float* ob = out + (size_t)b * 2 * 1024;
#pragma unroll
    for (int q = 0; q < 4; ++q) {
        int qy = q >> 1, qx = q & 1;
        int oy = 2 * sy + qy, ox = 2 * sx + qx;
#pragma unroll
        for (int co = 0; co < 2; ++co) {
            float r = acc[q][co] + bias[co];
            r = fminf(fmaxf(r, 0.f), 1.f);
            ob[(size_t)co * 1024 + oy * 32 + ox] = r;
        }
    }
}

// ---------------------------------------------------------------------------
// conv1: direct conv (CIN=2). bf16 output bounced through LDS -> u32-pair ->
// u64 stores (clean pattern). Only instantiated with PX==256, NCOG==1.
// ---------------------------------------------------------------------------
template<int CIN, int COUT, int HIN, int WIN, int S, int CI_CHUNK, int CO_PER_BLOCK>
__global__ __launch_bounds__(256)
void conv5k(const float* __restrict__ in, const float* __restrict__ wt,
            const float* __restrict__ bias, u16* __restrict__ out)
{
    constexpr int HOUT = HIN / S, WOUT = WIN / S;
    constexpr int PX = HOUT * WOUT;          // 256
    constexpr int CO_ITERS = CO_PER_BLOCK;   // 16
    constexpr int HT = HIN + 4, WT = WIN + 4;
    constexpr int NCHUNK = CIN / CI_CHUNK;
    constexpr int TILE = CI_CHUNK * HT * WT;

    __shared__ float lds[TILE];
    __shared__ u16 os[CO_PER_BLOCK * PX];

    const int b = blockIdx.x;
    const int co_base = blockIdx.y * CO_PER_BLOCK;
    const int tid = threadIdx.x;
    const int px = tid;
    const int oy = px / WOUT, ox = px % WOUT;

    float acc[CO_ITERS];
#pragma unroll
    for (int i = 0; i < CO_ITERS; ++i) acc[i] = 0.f;

    const float* inb = in + (size_t)b * CIN * HIN * WIN;

#pragma unroll 1
    for (int ch = 0; ch < NCHUNK; ++ch) {
        if (ch) __syncthreads();
        for (int idx = tid; idx < TILE; idx += 256) lds[idx] = 0.f;
        __syncthreads();
        for (int idx = tid; idx < CI_CHUNK * HIN * WIN; idx += 256) {
            int ci = idx / (HIN * WIN);
            int r = idx - ci * (HIN * WIN);
            int iy = r / WIN, ix = r - iy * WIN;
            lds[ci * (HT * WT) + (iy + 2) * WT + (ix + 2)] =
                inb[(size_t)(ch * CI_CHUNK + ci) * (HIN * WIN) + r];
        }
        __syncthreads();

#pragma unroll 1
        for (int ci = 0; ci < CI_CHUNK; ++ci) {
            float v[25];
            const float* l = &lds[ci * (HT * WT) + (oy * S) * WT + (ox * S)];
#pragma unroll
            for (int ky = 0; ky < 5; ++ky)
#pragma unroll
                for (int kx = 0; kx < 5; ++kx)
                    v[ky * 5 + kx] = l[ky * WT + kx];
#pragma unroll
            for (int i = 0; i < CO_ITERS; ++i) {
                const int co = co_base + i;
                const float* wp = wt + (size_t)ufl((co * CIN + ch * CI_CHUNK + ci) * 25);
#pragma unroll
                for (int t = 0; t < 25; ++t) acc[i] = fmaf(wp[t], v[t], acc[i]);
            }
        }
    }

#pragma unroll
    for (int i = 0; i < CO_ITERS; ++i)
        os[i * PX + px] = f2b(acc[i] + bias[co_base + i]);
    __syncthreads();
    u16* ob = out + ((size_t)b * COUT + co_base) * PX;
    const unsigned* osw = (const unsigned*)os;
#pragma unroll
    for (int it = 0; it < CO_PER_BLOCK * PX / 1024; ++it) {
        int v = it * 256 + tid;
        unsigned lo = osw[v * 2], hi = osw[v * 2 + 1];
        *(unsigned long long*)&ob[v * 4] =
            (unsigned long long)lo | ((unsigned long long)hi << 32);
    }
}

// ---------------------------------------------------------------------------
// GDN f32 (in-place, dword stores — fine). Used for a2 / d1 (P_IMG=64).
// ---------------------------------------------------------------------------
template<typename T, int P_IMG, bool INVERSE>
__global__ __launch_bounds__(256)
void gdnk(T* __restrict__ x, const float* __restrict__ beta,
          const float* __restrict__ gamma)
{
    __shared__ float xs[256 * 64];
    const int b = blockIdx.x;
    const int pb = blockIdx.y * 64;
    const int tid = threadIdx.x;
    const int px = tid & 63;
    const int og = tid >> 6;

    T* xb = x + (size_t)b * 256 * P_IMG + pb;

#pragma unroll 4
    for (int k = 0; k < 64; ++k) {
        const int c = og + 4 * k;
        xs[c * 64 + px] = ldv(&xb[(size_t)c * P_IMG + px]);
    }
    __syncthreads();

    const int co0 = og * 64;
    float acc[64];
#pragma unroll
    for (int k = 0; k < 64; ++k) acc[k] = beta[ufl(co0 + k)];

#pragma unroll 1
    for (int cc = 0; cc < 32; ++cc) {
        float xv[8];
#pragma unroll
        for (int u = 0; u < 8; ++u) {
            float t = xs[(cc * 8 + u) * 64 + px];
            xv[u] = t * t;
        }
#pragma unroll
        for (int k = 0; k < 64; ++k) {
            const float* g = gamma + (size_t)ufl((co0 + k) * 256 + cc * 8);
#pragma unroll
            for (int u = 0; u < 8; ++u) acc[k] = fmaf(g[u], xv[u], acc[k]);
        }
    }

#pragma unroll 4
    for (int k = 0; k < 64; ++k) {
        const float n = acc[k];
        const float r = INVERSE ? sqrtf(n) : rsqrtf(n);
        xb[(size_t)(co0 + k) * P_IMG + px] = xs[(co0 + k) * 64 + px] * r;
    }
}

// ---------------------------------------------------------------------------
// GDN bf16 (in-place), restructured to the PROVEN-CLEAN store shape:
//   1. global -> LDS raw u64 copy (tile stays bf16/u16 in LDS, 32 KB)
//   2. matmul phase reads u16 + b2f
//   3. barrier, then in-place scale in LDS (exact element ownership)
//   4. barrier, then LDS -> global pure u32-pair -> u64 copy (conv5k pattern)
// Numerically bitwise-identical to the previous version.
// PLANAR=false: x is [b][256][256], row stride 256. PLANAR=true: quadrant-
// planar [b*4+q][256][64], row stride 64. Grid (1024, 4) both.
// ---------------------------------------------------------------------------
template<bool INVERSE, bool PLANAR>
__global__ __launch_bounds__(256)
void gdnk16(u16* __restrict__ x, const float* __restrict__ beta,
            const float* __restrict__ gamma)
{
    constexpr int RS = PLANAR ? 64 : 256;
    __shared__ u16 xs[256 * 64];   // 32 KB bf16 tile
    const int tid = threadIdx.x;
    u16* xb = x + (size_t)blockIdx.x * 65536 + (size_t)blockIdx.y * (PLANAR ? 16384 : 64);

    // global -> LDS raw copy (no conversion; flat u16 idx = 4*v)
#pragma unroll
    for (int it = 0; it < 16; ++it) {
        int v = it * 256 + tid;
        int ch = v >> 4, pxg = (v & 15) * 4;
        *(unsigned long long*)&xs[v * 4] =
            *(const unsigned long long*)&xb[(size_t)ch * RS + pxg];
    }
    __syncthreads();

    const int px = tid & 63, og = tid >> 6, co0 = og * 64;
    float acc[64];
#pragma unroll
    for (int k = 0; k < 64; ++k) acc[k] = beta[ufl(co0 + k)];

#pragma unroll 1
    for (int cc = 0; cc < 32; ++cc) {
        float xv[8];
#pragma unroll
        for (int u = 0; u < 8; ++u) {
            float t = b2f(xs[(cc * 8 + u) * 64 + px]);
            xv[u] = t * t;
        }
#pragma unroll
        for (int k = 0; k < 64; ++k) {
            const float* g = gamma + (size_t)ufl((co0 + k) * 256 + cc * 8);
#pragma unroll
            for (int u = 0; u < 8; ++u) acc[k] = fmaf(g[u], xv[u], acc[k]);
        }
    }
    __syncthreads();   // all matmul reads of xs complete before any overwrite

    // in-place scale in LDS (each u16 element owned by exactly one thread)
#pragma unroll 4
    for (int k = 0; k < 64; ++k) {
        const float n = acc[k];
        const float r = INVERSE ? sqrtf(n) : rsqrtf(n);
        u16* p = &xs[(co0 + k) * 64 + px];
        *p = f2b(b2f(*p) * r);
    }
    __syncthreads();

    // LDS -> global pure copy: u32 pairs -> single u64 store (clean pattern)
    const unsigned* xw = (const unsigned*)xs;
#pragma unroll
    for (int it = 0; it < 16; ++it) {
        int v = it * 256 + tid;
        int ch = v >> 4, pxg = (v & 15) * 4;
        unsigned lo = xw[v * 2], hi = xw[v * 2 + 1];
        *(unsigned long long*)&xb[(size_t)ch * RS + pxg] =
            (unsigned long long)lo | ((unsigned long long)hi << 32);
    }
}

// ---------------------------------------------------------------------------
// Fused context model (unchanged, verified).
// ---------------------------------------------------------------------------
__global__ __launch_bounds__(256)
void trik(float* __restrict__ y, const float* __restrict__ noise,
          const float* __restrict__ H, const float* __restrict__ mean,
          const float* __restrict__ scale, float* __restrict__ lik)
{
    __shared__ float h[64 * 65];
    const int c = blockIdx.x;
    const int bt = blockIdx.y;
    const int tid = threadIdx.x;
    const int lane = tid & 63;
    const int wv = tid >> 6;

    const float* Hc = H + (size_t)c * 4096;
    for (int idx = tid; idx < 4096; idx += 256) {
        const int i = idx >> 6, j = idx & 63;
        h[i * 65 + j] = Hc[idx];
    }
    __syncthreads();

    const int b = bt * 4 + wv;
    const size_t base = ((size_t)b * 320 + c) * 64 + lane;
    const float* hrow = &h[lane * 65];

    const float yv = y[base];
    float ws = 0.f;
#pragma unroll 8
    for (int j = 0; j < 64; ++j) {
        const float yj = __shfl(yv, j, 64);
        const float hv = (j < lane) ? hrow[j] : 0.f;
        ws = fmaf(hv, yj, ws);
    }
    const float wh = yv - ws + noise[base];

    const float mn = mean[c * 64 + lane];
    const float sc = fmaxf(scale[c * 64 + lane], 0.11f);
    const float vv = fabsf(wh - mn);
    const float cst = -0.70710678118654752f;
    const float upper = 0.5f * erfcf(cst * (0.5f - vv) / sc);
    const float lower = 0.5f * erfcf(cst * (-0.5f - vv) / sc);
    lik[base] = fmaxf(upper - lower, 1e-9f);

    float acc = wh;
#pragma unroll 8
    for (int j = 0; j < 64; ++j) {
        const float yj = __shfl(acc, j, 64);
        const float hv = (j < lane) ? hrow[j] : 0.f;
        acc = fmaf(hv, yj, acc);
    }
    y[base] = acc;
}

// ---------------------------------------------------------------------------
extern "C" void kernel_launch(void* const* d_in, const int* in_sizes, int n_in,
                              void* d_out, int out_size, void* d_ws, size_t ws_size,
                              hipStream_t stream)
{
    (void)in_sizes; (void)n_in; (void)out_size; (void)ws_size;

    const float* x      = (const float*)d_in[0];
    const float* noise  = (const float*)d_in[1];
    const float* w1     = (const float*)d_in[2];
    const float* b1     = (const float*)d_in[3];
    const float* beta1  = (const float*)d_in[4];
    const float* gamma1 = (const float*)d_in[5];
    const float* w2     = (const float*)d_in[6];
    const float* b2     = (const float*)d_in[7];
    const float* beta2  = (const float*)d_in[8];
    const float* gamma2 = (const float*)d_in[9];
    const float* w3     = (const float*)d_in[10];
    const float* b3     = (const float*)d_in[11];
    const float* dw1    = (const float*)d_in[12];
    const float* db1    = (const float*)d_in[13];
    const float* ibeta1 = (const float*)d_in[14];
    const float* igamma1= (const float*)d_in[15];
    const float* dw2    = (const float*)d_in[16];
    const float* db2    = (const float*)d_in[17];
    const float* ibeta2 = (const float*)d_in[18];
    const float* igamma2= (const float*)d_in[19];
    const float* dw3    = (const float*)d_in[20];
    const float* db3    = (const float*)d_in[21];
    const float* mean   = (const float*)d_in[22];
    const float* scale  = (const float*)d_in[23];
    const float* H      = (const float*)d_in[24];

    float* outp = (float*)d_out;
    float* xhat = outp;                                   // [1024,2,32,32]
    float* lik  = outp + (size_t)1024 * 2 * 32 * 32;      // [1024,320,64]

    // workspace layout (peak 217.6 MB):
    //   [0, 134.2M)      a1 bf16 -> y f32 -> d2 bf16 (quadrant-planar)
    //   [134.2M, 201.3M) a2 f32 -> d1 f32
    //   [201.3M, 217.6M) repacked weights (live whole call)
    char* ws = (char*)d_ws;
    u16*   a1  = (u16*)ws;
    float* a2  = (float*)(ws + 134217728);
    float* y   = (float*)ws;
    float* d1  = (float*)(ws + 134217728);
    u16*   d2  = (u16*)ws;
    u16*   Ac2 = (u16*)(ws + 201326592);
    u16*   Ac3 = (u16*)(ws + 204603392);
    u16*   Ad1 = (u16*)(ws + 208699392);
    u16*   Ad2 = (u16*)(ws + 212795392);
    float* W3r = (float*)(ws + 217513984);

    // ---- weight repacks (paired u32 stores) ----
    rk_fwd<256, 256><<<3200, 256, 0, stream>>>(w2, Ac2);
    rk_fwd<256, 320><<<4000, 256, 0, stream>>>(w3, Ac3);
    rk_d1<<<4000, 256, 0, stream>>>(dw1, Ad1);
    rk_d2<<<4608, 256, 0, stream>>>(dw2, Ad2);
    rk_d3<<<128, 256, 0, stream>>>(dw3, W3r);

    // ---- analysis ----
    conv5k<2, 256, 32, 32, 2, 2, 16><<<dim3(1024, 16), 256, 0, stream>>>(x, w1, b1, a1);
    gdnk16<false, false><<<dim3(1024, 4), 256, 0, stream>>>(a1, beta1, gamma1);
    mconv<256, 256, 2, 4, u16><<<1024, 256, 0, stream>>>(a1, Ac2, b2, a2);
    gdnk<float, 64, false><<<dim3(1024, 1), 256, 0, stream>>>(a2, beta2, gamma2);
    mconv<256, 320, 1, 5, float><<<1024, 256, 0, stream>>>(a2, Ac3, b3, y);

    // ---- context model ----
    trik<<<dim3(320, 256), 256, 0, stream>>>(y, noise, H, mean, scale, lik);

    // ---- synthesis ----
    mconv<320, 256, 1, 4, float><<<1024, 256, 0, stream>>>(y, Ad1, db1, d1);
    gdnk<float, 64, true><<<dim3(1024, 1), 256, 0, stream>>>(d1, ibeta1, igamma1);
    mdeconv2<<<1024, 256, 0, stream>>>(d1, Ad2, db2, d2);
    gdnk16<true, true><<<dim3(1024, 4), 256, 0, stream>>>(d2, ibeta2, igamma2);
    dec3k<<<1024, 256, 0, stream>>>(d2, W3r, db3, xhat);
}

// Round 4
// 5596.700 us; speedup vs baseline: 1.7132x; 1.4612x over previous
//
#include <hip/hip_runtime.h>
#include <math.h>

typedef unsigned short u16;
typedef __bf16 bf16x8 __attribute__((ext_vector_type(8)));
typedef float f32x4 __attribute__((ext_vector_type(4)));
struct alignas(8) u16x4 { u16 x0, x1, x2, x3; };

__device__ __forceinline__ int ufl(int v) { return __builtin_amdgcn_readfirstlane(v); }
__device__ __forceinline__ u16 f2b(float f) {
    unsigned u = __float_as_uint(f);
    return (u16)((u + 0x7FFFu + ((u >> 16) & 1u)) >> 16);   // RNE fp32->bf16
}
__device__ __forceinline__ float b2f(u16 h) { return __uint_as_float(((unsigned)h) << 16); }
__device__ __forceinline__ float ldv(const float* p) { return *p; }
__device__ __forceinline__ float ldv(const u16* p)   { return b2f(*p); }
__device__ __forceinline__ u16 tob(float v) { return f2b(v); }
__device__ __forceinline__ u16 tob(u16 v)   { return v; }

// ---------------------------------------------------------------------------
// SESSION LEDGER (counter evidence):
//  * r0-r2: gdnk16 WRITE_SIZE stuck at 8.7e6 KB (~8.9 GB) for a 134 MB output
//    regardless of store idiom. Store width was NEVER the cause.
//  * r2 diagnosis: VGPR_Count=64 with float acc[64]/thread => acc[] SPILLED
//    to scratch. Spill writes = 32cc * 64k * 4B = 8KB/thread * 1.05M threads
//    = 8.59 GB, matching measured WRITE_SIZE. => memory-bound on spill.
//  * FIX: 512 threads/block, 32 accumulators/thread, launch_bounds(512,2).
//  * r3 FAILED: copy-loop bug (u64 = 4 u16, not 8) => half tile unloaded.
//    Fixed here: 8 its x 512 thr x 4 u16 = 16384 = full tile; LDS idx v*4.
// ---------------------------------------------------------------------------

// ---------------------------------------------------------------------------
// Weight repacks (paired u32 stores).
// ---------------------------------------------------------------------------
// forward conv: W[COUT][CIN][25] f32 -> A[25][COUT][CIN] bf16 (ci pairs)
template<int CIN, int COUT>
__global__ __launch_bounds__(256) void rk_fwd(const float* __restrict__ w, u16* __restrict__ a) {
    int j = (blockIdx.x * 256 + threadIdx.x) * 2;
    if (j >= 25 * COUT * CIN) return;
    int ci = j % CIN; int r = j / CIN; int co = r % COUT; int t = r / COUT;
    u16 lo = f2b(w[(co * CIN + ci) * 25 + t]);
    u16 hi = f2b(w[(co * CIN + ci + 1) * 25 + t]);
    *(unsigned*)&a[j] = (unsigned)lo | ((unsigned)hi << 16);
}
// deconv1 (s1 gather): W[320ci][256co][25] -> A[t'][256co][320ci], t'=(4-ky)*5+(4-kx)
__global__ __launch_bounds__(256) void rk_d1(const float* __restrict__ w, u16* __restrict__ a) {
    int j = (blockIdx.x * 256 + threadIdx.x) * 2;
    if (j >= 25 * 256 * 320) return;
    int ci = j % 320; int r = j / 320; int co = r % 256; int tp = r / 256;
    int ky = 4 - tp / 5, kx = 4 - tp % 5;
    u16 lo = f2b(w[(ci * 256 + co) * 25 + ky * 5 + kx]);
    u16 hi = f2b(w[((ci + 1) * 256 + co) * 25 + ky * 5 + kx]);
    *(unsigned*)&a[j] = (unsigned)lo | ((unsigned)hi << 16);
}
// deconv2 (s2 parity): W[256ci][256co][25] -> A2[q*9+tt][256co][256ci], zero invalid taps
__global__ __launch_bounds__(256) void rk_d2(const float* __restrict__ w, u16* __restrict__ a) {
    int j = (blockIdx.x * 256 + threadIdx.x) * 2;
    if (j >= 36 * 256 * 256) return;
    int ci = j % 256; int r = j / 256; int co = r % 256; int qt = r / 256;
    int q = qt / 9, tt = qt % 9;
    int qy = q >> 1, qx = q & 1, ty = tt / 3, tx = tt % 3;
    u16 lo = 0, hi = 0;
    if (ty < 3 - qy && tx < 3 - qx) {
        int widx = (qy + 2 * ty) * 5 + (qx + 2 * tx);
        lo = f2b(w[(ci * 256 + co) * 25 + widx]);
        hi = f2b(w[((ci + 1) * 256 + co) * 25 + widx]);
    }
    *(unsigned*)&a[j] = (unsigned)lo | ((unsigned)hi << 16);
}
// deconv3: W[256ci][2co][25] f32 -> W3r[4q][256ci][2co][16] f32 (9 taps zero-padded)
__global__ __launch_bounds__(256) void rk_d3(const float* __restrict__ w, float* __restrict__ a) {
    int i = blockIdx.x * 256 + threadIdx.x;
    if (i >= 4 * 256 * 2 * 16) return;
    int t = i % 16; int r = i / 16; int co = r % 2; int r2 = r / 2; int ci = r2 % 256; int q = r2 / 256;
    int qy = q >> 1, qx = q & 1;
    float v = 0.f;
    if (t < 9) {
        int ty = t / 3, tx = t % 3;
        if (ty < 3 - qy && tx < 3 - qx) v = w[(ci * 2 + co) * 25 + (qy + 2 * ty) * 5 + (qx + 2 * tx)];
    }
    a[i] = v;
}

// ---------------------------------------------------------------------------
// MFMA implicit-GEMM conv (k=5 pad=2 stride S in {1,2}), out 8x8 per image.
// (f32 dword stores, no amplification)
// ---------------------------------------------------------------------------
template<int CIN, int COUT, int S, int MT, typename TIN>
__global__ __launch_bounds__(256)
void mconv(const TIN* __restrict__ in, const u16* __restrict__ A,
           const float* __restrict__ bias, float* __restrict__ out)
{
    constexpr int HIN = 8 * S, HP = 7 * S + 5, CHUNK = 64, STRIDE = CHUNK + 8;
    constexpr int NCH = CIN / CHUNK;
    constexpr int SP = HP * HP;
    __shared__ u16 bs[SP * STRIDE];

    const int b = blockIdx.x;
    const int tid = threadIdx.x;
    const int lane = tid & 63, wv = tid >> 6;
    const int lm = lane & 15, quad = lane >> 4;
    const int cob = wv * (MT * 16);
    const TIN* inb = in + (size_t)b * CIN * (HIN * HIN);

    int bofs[4];
#pragma unroll
    for (int nt = 0; nt < 4; ++nt) {
        int px = nt * 16 + lm, oy = px >> 3, ox = px & 7;
        bofs[nt] = (S * oy * HP + S * ox) * STRIDE + quad * 8;
    }

    f32x4 acc[MT][4];
#pragma unroll
    for (int m = 0; m < MT; ++m)
#pragma unroll
        for (int n = 0; n < 4; ++n) acc[m][n] = (f32x4){0.f, 0.f, 0.f, 0.f};

#pragma unroll 1
    for (int ch = 0; ch < NCH; ++ch) {
        if (ch) __syncthreads();
        unsigned* bz = (unsigned*)bs;
        for (int i = tid; i < SP * STRIDE / 2; i += 256) bz[i] = 0u;
        __syncthreads();
        for (int i = tid; i < (CHUNK / 4) * (HIN * HIN); i += 256) {
            int px = i % (HIN * HIN), cg = i / (HIN * HIN);
            int iy = px / HIN, ix = px % HIN;
            const TIN* ip = inb + (size_t)(ch * CHUNK + cg * 4) * (HIN * HIN) + px;
            u16x4 p;
            p.x0 = tob(ip[0]);
            p.x1 = tob(ip[HIN * HIN]);
            p.x2 = tob(ip[2 * HIN * HIN]);
            p.x3 = tob(ip[3 * HIN * HIN]);
            *(u16x4*)&bs[((iy + 2) * HP + ix + 2) * STRIDE + cg * 4] = p;
        }
        __syncthreads();

#pragma unroll 1
        for (int tap = 0; tap < 25; ++tap) {
            const int ky = tap / 5, kx = tap % 5;
            const int tofs = (ky * HP + kx) * STRIDE;
            const u16* At = A + (size_t)tap * COUT * CIN + ch * CHUNK + quad * 8;
#pragma unroll
            for (int kc = 0; kc < CHUNK / 32; ++kc) {
                bf16x8 bf[4];
#pragma unroll
                for (int nt = 0; nt < 4; ++nt)
                    bf[nt] = *(const bf16x8*)&bs[bofs[nt] + tofs + kc * 32];
                bf16x8 af[MT];
#pragma unroll
                for (int m = 0; m < MT; ++m)
                    af[m] = *(const bf16x8*)(At + (size_t)(cob + m * 16 + lm) * CIN + kc * 32);
#pragma unroll
                for (int m = 0; m < MT; ++m)
#pragma unroll
                    for (int nt = 0; nt < 4; ++nt)
                        acc[m][nt] = __builtin_amdgcn_mfma_f32_16x16x32_bf16(af[m], bf[nt], acc[m][nt], 0, 0, 0);
            }
        }
    }

    float* ob = out + (size_t)b * COUT * 64;
#pragma unroll
    for (int m = 0; m < MT; ++m)
#pragma unroll
        for (int nt = 0; nt < 4; ++nt) {
            int px = nt * 16 + lm;
#pragma unroll
            for (int r = 0; r < 4; ++r) {
                int co = cob + m * 16 + quad * 4 + r;
                ob[(size_t)co * 64 + px] = acc[m][nt][r] + bias[co];
            }
        }
}

// ---------------------------------------------------------------------------
// MFMA ConvTranspose2d k=5 s=2, 8x8 -> 16x16, 256->256, out bf16 QUADRANT-PLANAR:
// d2[b][q][co][sp] (sp = sy*8+sx). LDS bounce -> u32-pair -> u64 stores.
// ---------------------------------------------------------------------------
__global__ __launch_bounds__(256)
void mdeconv2(const float* __restrict__ in, const u16* __restrict__ A2,
              const float* __restrict__ bias, u16* __restrict__ out)
{
    constexpr int STRIDE = 264;
    __shared__ u16 bs[100 * STRIDE];
    __shared__ u16 os[256 * 64];
    const int b = blockIdx.x, tid = threadIdx.x;
    const int lane = tid & 63, wv = tid >> 6, lm = lane & 15, quad = lane >> 4;
    const int cob = wv * 64;
    const float* inb = in + (size_t)b * 256 * 64;

    unsigned* bz = (unsigned*)bs;
    for (int i = tid; i < 100 * STRIDE / 2; i += 256) bz[i] = 0u;
    __syncthreads();
    for (int i = tid; i < 64 * 64; i += 256) {
        int px = i & 63, cg = i >> 6;
        int iy = px >> 3, ix = px & 7;
        const float* ip = inb + (size_t)cg * 4 * 64 + px;
        u16x4 p;
        p.x0 = f2b(ip[0]); p.x1 = f2b(ip[64]); p.x2 = f2b(ip[128]); p.x3 = f2b(ip[192]);
        *(u16x4*)&bs[((iy + 1) * 10 + ix + 1) * STRIDE + cg * 4] = p;
    }
    __syncthreads();

    int bofs[4];
#pragma unroll
    for (int nt = 0; nt < 4; ++nt) {
        int sp = nt * 16 + lm, sy = sp >> 3, sx = sp & 7;
        bofs[nt] = ((sy + 2) * 10 + sx + 2) * STRIDE + quad * 8;
    }

#pragma unroll
    for (int qy = 0; qy < 2; ++qy)
#pragma unroll
        for (int qx = 0; qx < 2; ++qx) {
            const int q = qy * 2 + qx;
            f32x4 acc[4][4];
#pragma unroll
            for (int m = 0; m < 4; ++m)
#pragma unroll
                for (int n = 0; n < 4; ++n) acc[m][n] = (f32x4){0.f, 0.f, 0.f, 0.f};

            const int NT = (3 - qy) * (3 - qx);
#pragma unroll 1
            for (int tt = 0; tt < NT; ++tt) {
                const int ty = tt / (3 - qx), tx = tt % (3 - qx);
                const int tofs = -(ty * 10 + tx) * STRIDE;
                const u16* At = A2 + (size_t)(q * 9 + ty * 3 + tx) * 256 * 256 + quad * 8;
#pragma unroll
                for (int kc = 0; kc < 8; ++kc) {
                    bf16x8 bf[4];
#pragma unroll
                    for (int nt = 0; nt < 4; ++nt)
                        bf[nt] = *(const bf16x8*)&bs[bofs[nt] + tofs + kc * 32];
                    bf16x8 af[4];
#pragma unroll
                    for (int m = 0; m < 4; ++m)
                        af[m] = *(const bf16x8*)(At + (size_t)(cob + m * 16 + lm) * 256 + kc * 32);
#pragma unroll
                    for (int m = 0; m < 4; ++m)
#pragma unroll
                        for (int nt = 0; nt < 4; ++nt)
                            acc[m][nt] = __builtin_amdgcn_mfma_f32_16x16x32_bf16(af[m], bf[nt], acc[m][nt], 0, 0, 0);
                }
            }
            // bounce fragments -> LDS -> contiguous u32-pair -> u64 stores
#pragma unroll
            for (int m = 0; m < 4; ++m)
#pragma unroll
                for (int nt = 0; nt < 4; ++nt)
#pragma unroll
                    for (int r = 0; r < 4; ++r) {
                        int co = cob + m * 16 + quad * 4 + r;
                        os[co * 64 + nt * 16 + lm] = f2b(acc[m][nt][r] + bias[co]);
                    }
            __syncthreads();
            u16* od = out + ((size_t)(b * 4 + q)) * 256 * 64;
            const unsigned* osw = (const unsigned*)os;
#pragma unroll
            for (int it = 0; it < 16; ++it) {
                int v = it * 256 + tid;
                unsigned lo = osw[v * 2], hi = osw[v * 2 + 1];
                *(unsigned long long*)&od[v * 4] =
                    (unsigned long long)lo | ((unsigned long long)hi << 32);
            }
            __syncthreads();
        }
}

// ---------------------------------------------------------------------------
// deconv3 (VALU): ConvTranspose2d s2, 256->2, 16x16 -> 32x32, clip [0,1].
// Input d2 bf16 QUADRANT-PLANAR [b][q][ci][sp]. f32 dword output stores.
// ---------------------------------------------------------------------------
__global__ __launch_bounds__(256)
void dec3k(const u16* __restrict__ in, const float* __restrict__ W3r,
           const float* __restrict__ bias, float* __restrict__ out)
{
    constexpr int HT = 18;
    __shared__ float ls[32 * HT * HT];
    const int b = blockIdx.x, tid = threadIdx.x;
    const int sy = tid >> 4, sx = tid & 15;
    const u16* inb = in + (size_t)b * 4 * 256 * 64;
    float acc[4][2] = {};
#pragma unroll 1
    for (int ch = 0; ch < 8; ++ch) {
        if (ch) __syncthreads();
        for (int i = tid; i < 32 * HT * HT; i += 256) ls[i] = 0.f;
        __syncthreads();
        for (int i = tid; i < 32 * 256; i += 256) {
            int ci = i >> 8, px = i & 255, iy = px >> 4, ix = px & 15;
            int q = (iy & 1) * 2 + (ix & 1);
            int sp = (iy >> 1) * 8 + (ix >> 1);
            ls[ci * (HT * HT) + (iy + 1) * HT + ix + 1] =
                b2f(inb[((size_t)q * 256 + ch * 32 + ci) * 64 + sp]);
        }
        __syncthreads();
#pragma unroll 1
        for (int ci = 0; ci < 32; ++ci) {
            float v[9];
            const float* l = &ls[ci * (HT * HT) + (sy + 2) * HT + sx + 2];
#pragma unroll
            for (int ty = 0; ty < 3; ++ty)
#pragma unroll
                for (int tx = 0; tx < 3; ++tx) v[ty * 3 + tx] = l[-(ty * HT) - tx];
#pragma unroll
            for (int q = 0; q < 4; ++q) {
                const float* wp = W3r + (size_t)ufl(((q * 256 + ch * 32 + ci) * 2) * 16);
#pragma unroll
                for (int t = 0; t < 9; ++t) {
                    acc[q][0] = fmaf(wp[t], v[t], acc[q][0]);
                    acc[q][1] = fmaf(wp[16 + t], v[t], acc[q][1]);
                }
            }
        }
    }
    float* ob = out + (size_t)b * 2 * 1024;
#pragma unroll
    for (int q = 0; q < 4; ++q) {
        int qy = q >> 1, qx = q & 1;
        int oy = 2 * sy + qy, ox = 2 * sx + qx;
#pragma unroll
        for (int co = 0; co < 2; ++co) {
            float r = acc[q][co] + bias[co];
            r = fminf(fmaxf(r, 0.f), 1.f);
            ob[(size_t)co * 1024 + oy * 32 + ox] = r;
        }
    }
}

// ---------------------------------------------------------------------------
// conv1: direct conv (CIN=2). bf16 output bounced through LDS -> u32-pair ->
// u64 stores. Only instantiated with PX==256, NCOG==1.
// ---------------------------------------------------------------------------
template<int CIN, int COUT, int HIN, int WIN, int S, int CI_CHUNK, int CO_PER_BLOCK>
__global__ __launch_bounds__(256)
void conv5k(const float* __restrict__ in, const float* __restrict__ wt,
            const float* __restrict__ bias, u16* __restrict__ out)
{
    constexpr int HOUT = HIN / S, WOUT = WIN / S;
    constexpr int PX = HOUT * WOUT;          // 256
    constexpr int CO_ITERS = CO_PER_BLOCK;   // 16
    constexpr int HT = HIN + 4, WT = WIN + 4;
    constexpr int NCHUNK = CIN / CI_CHUNK;
    constexpr int TILE = CI_CHUNK * HT * WT;

    __shared__ float lds[TILE];
    __shared__ u16 os[CO_PER_BLOCK * PX];

    const int b = blockIdx.x;
    const int co_base = blockIdx.y * CO_PER_BLOCK;
    const int tid = threadIdx.x;
    const int px = tid;
    const int oy = px / WOUT, ox = px % WOUT;

    float acc[CO_ITERS];
#pragma unroll
    for (int i = 0; i < CO_ITERS; ++i) acc[i] = 0.f;

    const float* inb = in + (size_t)b * CIN * HIN * WIN;

#pragma unroll 1
    for (int ch = 0; ch < NCHUNK; ++ch) {
        if (ch) __syncthreads();
        for (int idx = tid; idx < TILE; idx += 256) lds[idx] = 0.f;
        __syncthreads();
        for (int idx = tid; idx < CI_CHUNK * HIN * WIN; idx += 256) {
            int ci = idx / (HIN * WIN);
            int r = idx - ci * (HIN * WIN);
            int iy = r / WIN, ix = r - iy * WIN;
            lds[ci * (HT * WT) + (iy + 2) * WT + (ix + 2)] =
                inb[(size_t)(ch * CI_CHUNK + ci) * (HIN * WIN) + r];
        }
        __syncthreads();

#pragma unroll 1
        for (int ci = 0; ci < CI_CHUNK; ++ci) {
            float v[25];
            const float* l = &lds[ci * (HT * WT) + (oy * S) * WT + (ox * S)];
#pragma unroll
            for (int ky = 0; ky < 5; ++ky)
#pragma unroll
                for (int kx = 0; kx < 5; ++kx)
                    v[ky * 5 + kx] = l[ky * WT + kx];
#pragma unroll
            for (int i = 0; i < CO_ITERS; ++i) {
                const int co = co_base + i;
                const float* wp = wt + (size_t)ufl((co * CIN + ch * CI_CHUNK + ci) * 25);
#pragma unroll
                for (int t = 0; t < 25; ++t) acc[i] = fmaf(wp[t], v[t], acc[i]);
            }
        }
    }

#pragma unroll
    for (int i = 0; i < CO_ITERS; ++i)
        os[i * PX + px] = f2b(acc[i] + bias[co_base + i]);
    __syncthreads();
    u16* ob = out + ((size_t)b * COUT + co_base) * PX;
    const unsigned* osw = (const unsigned*)os;
#pragma unroll
    for (int it = 0; it < CO_PER_BLOCK * PX / 1024; ++it) {
        int v = it * 256 + tid;
        unsigned lo = osw[v * 2], hi = osw[v * 2 + 1];
        *(unsigned long long*)&ob[v * 4] =
            (unsigned long long)lo | ((unsigned long long)hi << 32);
    }
}

// ---------------------------------------------------------------------------
// GDN f32 (in-place). SPILL-FREE: 512 threads, 32 accumulators/thread.
// x is [b][256][64] f32; block = one image; thread (og,px) owns channels
// og*32..og*32+31 at pixel px. Same accumulation order as the verified
// 256-thread version (cc asc, u asc) => bitwise-identical results.
// ---------------------------------------------------------------------------
template<int P_IMG, bool INVERSE>
__global__ __launch_bounds__(512, 2)
void gdnk(float* __restrict__ x, const float* __restrict__ beta,
          const float* __restrict__ gamma)
{
    __shared__ float xs[256 * 64];
    const int tid = threadIdx.x;
    float* xb = x + (size_t)blockIdx.x * 256 * P_IMG;

    // flat f32x4 copy: tile is the block's contiguous 64 KB
#pragma unroll
    for (int it = 0; it < 8; ++it) {
        int v = it * 512 + tid;          // [0,4096)
        ((f32x4*)xs)[v] = ((const f32x4*)xb)[v];
    }
    __syncthreads();

    const int px = tid & 63, og = tid >> 6, co0 = og * 32;
    float acc[32];
#pragma unroll
    for (int k = 0; k < 32; ++k) acc[k] = beta[ufl(co0 + k)];

#pragma unroll 1
    for (int cc = 0; cc < 32; ++cc) {
        float xv[8];
#pragma unroll
        for (int u = 0; u < 8; ++u) {
            float t = xs[(cc * 8 + u) * 64 + px];
            xv[u] = t * t;
        }
#pragma unroll
        for (int k = 0; k < 32; ++k) {
            const float* g = gamma + (size_t)ufl((co0 + k) * 256 + cc * 8);
#pragma unroll
            for (int u = 0; u < 8; ++u) acc[k] = fmaf(g[u], xv[u], acc[k]);
        }
    }

    // stores: 64 lanes x 4B contiguous per row segment -> clean dword blocks
#pragma unroll 4
    for (int k = 0; k < 32; ++k) {
        const float n = acc[k];
        const float r = INVERSE ? sqrtf(n) : rsqrtf(n);
        xb[(size_t)(co0 + k) * P_IMG + px] = xs[(co0 + k) * 64 + px] * r;
    }
}

// ---------------------------------------------------------------------------
// GDN bf16 (in-place). SPILL-FREE: 512 threads, 32 accumulators/thread.
// Tile stays u16 in LDS (32 KB); global I/O is raw u64 copies.
// Copy loops: u64 moves FOUR u16 (8 bytes). 8 its x 512 thr x 4 u16 = 16384
// = full 256x64 tile; LDS flat idx v*4 == ch*64+pxg (matmul layout).  [r3 bug fixed]
// PLANAR=false: x is [b][256][256], row stride 256 (blockIdx.y = 64-px slice).
// PLANAR=true : x is [b*4+q][256][64] quadrant-planar, row stride 64.
// Grid (1024, 4), block 512.
// ---------------------------------------------------------------------------
template<bool INVERSE, bool PLANAR>
__global__ __launch_bounds__(512, 2)
void gdnk16(u16* __restrict__ x, const float* __restrict__ beta,
            const float* __restrict__ gamma)
{
    constexpr int RS = PLANAR ? 64 : 256;
    __shared__ u16 xs[256 * 64];   // 32 KB bf16 tile
    const int tid = threadIdx.x;
    u16* xb = x + (size_t)blockIdx.x * 65536 + (size_t)blockIdx.y * (PLANAR ? 16384 : 64);

    // global -> LDS raw u64 copy (4 u16 per op)
#pragma unroll
    for (int it = 0; it < 8; ++it) {
        int v = it * 512 + tid;          // [0,4096)
        int ch = v >> 4, pxg = (v & 15) * 4;
        *(unsigned long long*)&xs[v * 4] =
            *(const unsigned long long*)&xb[(size_t)ch * RS + pxg];
    }
    __syncthreads();

    const int px = tid & 63, og = tid >> 6, co0 = og * 32;
    float acc[32];
#pragma unroll
    for (int k = 0; k < 32; ++k) acc[k] = beta[ufl(co0 + k)];

#pragma unroll 1
    for (int cc = 0; cc < 32; ++cc) {
        float xv[8];
#pragma unroll
        for (int u = 0; u < 8; ++u) {
            float t = b2f(xs[(cc * 8 + u) * 64 + px]);
            xv[u] = t * t;
        }
#pragma unroll
        for (int k = 0; k < 32; ++k) {
            const float* g = gamma + (size_t)ufl((co0 + k) * 256 + cc * 8);
#pragma unroll
            for (int u = 0; u < 8; ++u) acc[k] = fmaf(g[u], xv[u], acc[k]);
        }
    }
    __syncthreads();   // all matmul reads of xs complete before any overwrite

    // in-place scale in LDS (thread (og,px) owns channels co0..co0+31 at px)
#pragma unroll 4
    for (int k = 0; k < 32; ++k) {
        const float n = acc[k];
        const float r = INVERSE ? sqrtf(n) : rsqrtf(n);
        u16* p = &xs[(co0 + k) * 64 + px];
        *p = f2b(b2f(*p) * r);
    }
    __syncthreads();

    // LDS -> global raw u64 copy (4 u16 per op)
#pragma unroll
    for (int it = 0; it < 8; ++it) {
        int v = it * 512 + tid;
        int ch = v >> 4, pxg = (v & 15) * 4;
        *(unsigned long long*)&xb[(size_t)ch * RS + pxg] =
            *(const unsigned long long*)&xs[v * 4];
    }
}

// ---------------------------------------------------------------------------
// Fused context model (unchanged, verified).
// ---------------------------------------------------------------------------
__global__ __launch_bounds__(256)
void trik(float* __restrict__ y, const float* __restrict__ noise,
          const float* __restrict__ H, const float* __restrict__ mean,
          const float* __restrict__ scale, float* __restrict__ lik)
{
    __shared__ float h[64 * 65];
    const int c = blockIdx.x;
    const int bt = blockIdx.y;
    const int tid = threadIdx.x;
    const int lane = tid & 63;
    const int wv = tid >> 6;

    const float* Hc = H + (size_t)c * 4096;
    for (int idx = tid; idx < 4096; idx += 256) {
        const int i = idx >> 6, j = idx & 63;
        h[i * 65 + j] = Hc[idx];
    }
    __syncthreads();

    const int b = bt * 4 + wv;
    const size_t base = ((size_t)b * 320 + c) * 64 + lane;
    const float* hrow = &h[lane * 65];

    const float yv = y[base];
    float ws = 0.f;
#pragma unroll 8
    for (int j = 0; j < 64; ++j) {
        const float yj = __shfl(yv, j, 64);
        const float hv = (j < lane) ? hrow[j] : 0.f;
        ws = fmaf(hv, yj, ws);
    }
    const float wh = yv - ws + noise[base];

    const float mn = mean[c * 64 + lane];
    const float sc = fmaxf(scale[c * 64 + lane], 0.11f);
    const float vv = fabsf(wh - mn);
    const float cst = -0.70710678118654752f;
    const float upper = 0.5f * erfcf(cst * (0.5f - vv) / sc);
    const float lower = 0.5f * erfcf(cst * (-0.5f - vv) / sc);
    lik[base] = fmaxf(upper - lower, 1e-9f);

    float acc = wh;
#pragma unroll 8
    for (int j = 0; j < 64; ++j) {
        const float yj = __shfl(acc, j, 64);
        const float hv = (j < lane) ? hrow[j] : 0.f;
        acc = fmaf(hv, yj, acc);
    }
    y[base] = acc;
}

// ---------------------------------------------------------------------------
extern "C" void kernel_launch(void* const* d_in, const int* in_sizes, int n_in,
                              void* d_out, int out_size, void* d_ws, size_t ws_size,
                              hipStream_t stream)
{
    (void)in_sizes; (void)n_in; (void)out_size; (void)ws_size;

    const float* x      = (const float*)d_in[0];
    const float* noise  = (const float*)d_in[1];
    const float* w1     = (const float*)d_in[2];
    const float* b1     = (const float*)d_in[3];
    const float* beta1  = (const float*)d_in[4];
    const float* gamma1 = (const float*)d_in[5];
    const float* w2     = (const float*)d_in[6];
    const float* b2     = (const float*)d_in[7];
    const float* beta2  = (const float*)d_in[8];
    const float* gamma2 = (const float*)d_in[9];
    const float* w3     = (const float*)d_in[10];
    const float* b3     = (const float*)d_in[11];
    const float* dw1    = (const float*)d_in[12];
    const float* db1    = (const float*)d_in[13];
    const float* ibeta1 = (const float*)d_in[14];
    const float* igamma1= (const float*)d_in[15];
    const float* dw2    = (const float*)d_in[16];
    const float* db2    = (const float*)d_in[17];
    const float* ibeta2 = (const float*)d_in[18];
    const float* igamma2= (const float*)d_in[19];
    const float* dw3    = (const float*)d_in[20];
    const float* db3    = (const float*)d_in[21];
    const float* mean   = (const float*)d_in[22];
    const float* scale  = (const float*)d_in[23];
    const float* H      = (const float*)d_in[24];

    float* outp = (float*)d_out;
    float* xhat = outp;                                   // [1024,2,32,32]
    float* lik  = outp + (size_t)1024 * 2 * 32 * 32;      // [1024,320,64]

    // workspace layout (peak 217.6 MB):
    //   [0, 134.2M)      a1 bf16 -> y f32 -> d2 bf16 (quadrant-planar)
    //   [134.2M, 201.3M) a2 f32 -> d1 f32
    //   [201.3M, 217.6M) repacked weights (live whole call)
    char* ws = (char*)d_ws;
    u16*   a1  = (u16*)ws;
    float* a2  = (float*)(ws + 134217728);
    float* y   = (float*)ws;
    float* d1  = (float*)(ws + 134217728);
    u16*   d2  = (u16*)ws;
    u16*   Ac2 = (u16*)(ws + 201326592);
    u16*   Ac3 = (u16*)(ws + 204603392);
    u16*   Ad1 = (u16*)(ws + 208699392);
    u16*   Ad2 = (u16*)(ws + 212795392);
    float* W3r = (float*)(ws + 217513984);

    // ---- weight repacks (paired u32 stores) ----
    rk_fwd<256, 256><<<3200, 256, 0, stream>>>(w2, Ac2);
    rk_fwd<256, 320><<<4000, 256, 0, stream>>>(w3, Ac3);
    rk_d1<<<4000, 256, 0, stream>>>(dw1, Ad1);
    rk_d2<<<4608, 256, 0, stream>>>(dw2, Ad2);
    rk_d3<<<128, 256, 0, stream>>>(dw3, W3r);

    // ---- analysis ----
    conv5k<2, 256, 32, 32, 2, 2, 16><<<dim3(1024, 16), 256, 0, stream>>>(x, w1, b1, a1);
    gdnk16<false, false><<<dim3(1024, 4), 512, 0, stream>>>(a1, beta1, gamma1);
    mconv<256, 256, 2, 4, u16><<<1024, 256, 0, stream>>>(a1, Ac2, b2, a2);
    gdnk<64, false><<<dim3(1024, 1), 512, 0, stream>>>(a2, beta2, gamma2);
    mconv<256, 320, 1, 5, float><<<1024, 256, 0, stream>>>(a2, Ac3, b3, y);

    // ---- context model ----
    trik<<<dim3(320, 256), 256, 0, stream>>>(y, noise, H, mean, scale, lik);

    // ---- synthesis ----
    mconv<320, 256, 1, 4, float><<<1024, 256, 0, stream>>>(y, Ad1, db1, d1);
    gdnk<64, true><<<dim3(1024, 1), 512, 0, stream>>>(d1, ibeta1, igamma1);
    mdeconv2<<<1024, 256, 0, stream>>>(d1, Ad2, db2, d2);
    gdnk16<true, true><<<dim3(1024, 4), 512, 0, stream>>>(d2, ibeta2, igamma2);
    dec3k<<<1024, 256, 0, stream>>>(d2, W3r, db3, xhat);
}

// Round 5
// 3808.705 us; speedup vs baseline: 2.5175x; 1.4694x over previous
//
#include <hip/hip_runtime.h>
#include <math.h>

typedef unsigned short u16;
typedef unsigned long long u64t;
typedef __bf16 bf16x8 __attribute__((ext_vector_type(8)));
typedef float f32x4 __attribute__((ext_vector_type(4)));
struct alignas(8) u16x4 { u16 x0, x1, x2, x3; };

__device__ __forceinline__ int ufl(int v) { return __builtin_amdgcn_readfirstlane(v); }
__device__ __forceinline__ u16 f2b(float f) {
    unsigned u = __float_as_uint(f);
    return (u16)((u + 0x7FFFu + ((u >> 16) & 1u)) >> 16);   // RNE fp32->bf16
}
__device__ __forceinline__ float b2f(u16 h) { return __uint_as_float(((unsigned)h) << 16); }
__device__ __forceinline__ u16 tob(float v) { return f2b(v); }
__device__ __forceinline__ u16 tob(u16 v)   { return v; }

// ---------------------------------------------------------------------------
// SESSION LEDGER (counter evidence):
//  * r0-r2: gdnk16 WRITE_SIZE 8.7e6 KB for a 134 MB output regardless of
//    store idiom. Cause was NOT store width.
//  * r2/r4: VGPR_Count=64 + float acc[64]/thread => scratch spill. Spill
//    writes 8KB/thread * 1.05M threads = 8.6 GB = measured WRITE_SIZE.
//    Fix (acc[32]/thread, 512 thr) CONFIRMED r4: WRITE_SIZE -> 131072 KB
//    (exactly output), dur 1717->800. ALWAYS check VGPR vs acc array size.
//  * r3 lesson: u64 = FOUR u16. Verify copy-loop element counts.
//  * r4: GDN now VALU-bound at 27% of f32 FMA peak (800 us vs 219 floor,
//    VALUBusy 50%). GDN norm is a GEMM (34.4 GFLOP/dispatch) => MFMA (this
//    round): bf16 gamma & x^2, f32 accumulate; norm ~= 1 + <=0.015 so bf16
//    rounding perturbs norm ~1e-4 rel. All 4 GDN sites -> one gdnm kernel;
//    a2/d1 become bf16 (consumer rounded to bf16 anyway).
// ---------------------------------------------------------------------------

// ---------------------------------------------------------------------------
// Weight repacks (paired u32 stores).
// ---------------------------------------------------------------------------
// forward conv: W[COUT][CIN][25] f32 -> A[25][COUT][CIN] bf16 (ci pairs)
template<int CIN, int COUT>
__global__ __launch_bounds__(256) void rk_fwd(const float* __restrict__ w, u16* __restrict__ a) {
    int j = (blockIdx.x * 256 + threadIdx.x) * 2;
    if (j >= 25 * COUT * CIN) return;
    int ci = j % CIN; int r = j / CIN; int co = r % COUT; int t = r / COUT;
    u16 lo = f2b(w[(co * CIN + ci) * 25 + t]);
    u16 hi = f2b(w[(co * CIN + ci + 1) * 25 + t]);
    *(unsigned*)&a[j] = (unsigned)lo | ((unsigned)hi << 16);
}
// deconv1 (s1 gather): W[320ci][256co][25] -> A[t'][256co][320ci], t'=(4-ky)*5+(4-kx)
__global__ __launch_bounds__(256) void rk_d1(const float* __restrict__ w, u16* __restrict__ a) {
    int j = (blockIdx.x * 256 + threadIdx.x) * 2;
    if (j >= 25 * 256 * 320) return;
    int ci = j % 320; int r = j / 320; int co = r % 256; int tp = r / 256;
    int ky = 4 - tp / 5, kx = 4 - tp % 5;
    u16 lo = f2b(w[(ci * 256 + co) * 25 + ky * 5 + kx]);
    u16 hi = f2b(w[((ci + 1) * 256 + co) * 25 + ky * 5 + kx]);
    *(unsigned*)&a[j] = (unsigned)lo | ((unsigned)hi << 16);
}
// deconv2 (s2 parity): W[256ci][256co][25] -> A2[q*9+tt][256co][256ci], zero invalid taps
__global__ __launch_bounds__(256) void rk_d2(const float* __restrict__ w, u16* __restrict__ a) {
    int j = (blockIdx.x * 256 + threadIdx.x) * 2;
    if (j >= 36 * 256 * 256) return;
    int ci = j % 256; int r = j / 256; int co = r % 256; int qt = r / 256;
    int q = qt / 9, tt = qt % 9;
    int qy = q >> 1, qx = q & 1, ty = tt / 3, tx = tt % 3;
    u16 lo = 0, hi = 0;
    if (ty < 3 - qy && tx < 3 - qx) {
        int widx = (qy + 2 * ty) * 5 + (qx + 2 * tx);
        lo = f2b(w[(ci * 256 + co) * 25 + widx]);
        hi = f2b(w[((ci + 1) * 256 + co) * 25 + widx]);
    }
    *(unsigned*)&a[j] = (unsigned)lo | ((unsigned)hi << 16);
}
// deconv3: W[256ci][2co][25] f32 -> W3r[4q][256ci][2co][16] f32 (9 taps zero-padded)
__global__ __launch_bounds__(256) void rk_d3(const float* __restrict__ w, float* __restrict__ a) {
    int i = blockIdx.x * 256 + threadIdx.x;
    if (i >= 4 * 256 * 2 * 16) return;
    int t = i % 16; int r = i / 16; int co = r % 2; int r2 = r / 2; int ci = r2 % 256; int q = r2 / 256;
    int qy = q >> 1, qx = q & 1;
    float v = 0.f;
    if (t < 9) {
        int ty = t / 3, tx = t % 3;
        if (ty < 3 - qy && tx < 3 - qx) v = w[(ci * 2 + co) * 25 + (qy + 2 * ty) * 5 + (qx + 2 * tx)];
    }
    a[i] = v;
}
// GDN gamma: f32 [256co][256ci] -> bf16 [co][ci] (ci pairs)
__global__ __launch_bounds__(256) void rk_g(const float* __restrict__ g, u16* __restrict__ a) {
    int j = (blockIdx.x * 256 + threadIdx.x) * 2;
    if (j >= 256 * 256) return;
    u16 lo = f2b(g[j]);
    u16 hi = f2b(g[j + 1]);
    *(unsigned*)&a[j] = (unsigned)lo | ((unsigned)hi << 16);
}

// ---------------------------------------------------------------------------
// MFMA implicit-GEMM conv (k=5 pad=2 stride S in {1,2}), out 8x8 per image.
// TOUT=float: dword stores. TOUT=u16: LDS-bounce epilogue (mdeconv2 pattern,
// bs reused as the 32 KB output staging buffer) -> u64 stores.
// ---------------------------------------------------------------------------
template<int CIN, int COUT, int S, int MT, typename TIN, typename TOUT>
__global__ __launch_bounds__(256)
void mconv(const TIN* __restrict__ in, const u16* __restrict__ A,
           const float* __restrict__ bias, TOUT* __restrict__ out)
{
    constexpr bool O16 = (sizeof(TOUT) == 2);
    constexpr int HIN = 8 * S, HP = 7 * S + 5, CHUNK = 64, STRIDE = CHUNK + 8;
    constexpr int NCH = CIN / CHUNK;
    constexpr int SP = HP * HP;
    constexpr int BSE = SP * STRIDE;
    constexpr int OSE = O16 ? COUT * 64 : 0;
    __shared__ u16 bs[(BSE > OSE) ? BSE : OSE];

    const int b = blockIdx.x;
    const int tid = threadIdx.x;
    const int lane = tid & 63, wv = tid >> 6;
    const int lm = lane & 15, quad = lane >> 4;
    const int cob = wv * (MT * 16);
    const TIN* inb = in + (size_t)b * CIN * (HIN * HIN);

    int bofs[4];
#pragma unroll
    for (int nt = 0; nt < 4; ++nt) {
        int px = nt * 16 + lm, oy = px >> 3, ox = px & 7;
        bofs[nt] = (S * oy * HP + S * ox) * STRIDE + quad * 8;
    }

    f32x4 acc[MT][4];
#pragma unroll
    for (int m = 0; m < MT; ++m)
#pragma unroll
        for (int n = 0; n < 4; ++n) acc[m][n] = (f32x4){0.f, 0.f, 0.f, 0.f};

#pragma unroll 1
    for (int ch = 0; ch < NCH; ++ch) {
        if (ch) __syncthreads();
        unsigned* bz = (unsigned*)bs;
        for (int i = tid; i < BSE / 2; i += 256) bz[i] = 0u;
        __syncthreads();
        for (int i = tid; i < (CHUNK / 4) * (HIN * HIN); i += 256) {
            int px = i % (HIN * HIN), cg = i / (HIN * HIN);
            int iy = px / HIN, ix = px % HIN;
            const TIN* ip = inb + (size_t)(ch * CHUNK + cg * 4) * (HIN * HIN) + px;
            u16x4 p;
            p.x0 = tob(ip[0]);
            p.x1 = tob(ip[HIN * HIN]);
            p.x2 = tob(ip[2 * HIN * HIN]);
            p.x3 = tob(ip[3 * HIN * HIN]);
            *(u16x4*)&bs[((iy + 2) * HP + ix + 2) * STRIDE + cg * 4] = p;
        }
        __syncthreads();

#pragma unroll 1
        for (int tap = 0; tap < 25; ++tap) {
            const int ky = tap / 5, kx = tap % 5;
            const int tofs = (ky * HP + kx) * STRIDE;
            const u16* At = A + (size_t)tap * COUT * CIN + ch * CHUNK + quad * 8;
#pragma unroll
            for (int kc = 0; kc < CHUNK / 32; ++kc) {
                bf16x8 bf[4];
#pragma unroll
                for (int nt = 0; nt < 4; ++nt)
                    bf[nt] = *(const bf16x8*)&bs[bofs[nt] + tofs + kc * 32];
                bf16x8 af[MT];
#pragma unroll
                for (int m = 0; m < MT; ++m)
                    af[m] = *(const bf16x8*)(At + (size_t)(cob + m * 16 + lm) * CIN + kc * 32);
#pragma unroll
                for (int m = 0; m < MT; ++m)
#pragma unroll
                    for (int nt = 0; nt < 4; ++nt)
                        acc[m][nt] = __builtin_amdgcn_mfma_f32_16x16x32_bf16(af[m], bf[nt], acc[m][nt], 0, 0, 0);
            }
        }
    }

    if constexpr (O16) {
        __syncthreads();          // all MFMA reads of bs done before reuse
#pragma unroll
        for (int m = 0; m < MT; ++m)
#pragma unroll
            for (int nt = 0; nt < 4; ++nt)
#pragma unroll
                for (int r = 0; r < 4; ++r) {
                    int co = cob + m * 16 + quad * 4 + r;
                    bs[co * 64 + nt * 16 + lm] = f2b(acc[m][nt][r] + bias[co]);
                }
        __syncthreads();
        u16* ob = out + (size_t)b * COUT * 64;
        const unsigned* osw = (const unsigned*)bs;
#pragma unroll
        for (int it = 0; it < COUT / 16; ++it) {
            int v = it * 256 + tid;
            unsigned lo = osw[v * 2], hi = osw[v * 2 + 1];
            *(u64t*)&ob[v * 4] = (u64t)lo | ((u64t)hi << 32);
        }
    } else {
        float* ob = (float*)out + (size_t)b * COUT * 64;
#pragma unroll
        for (int m = 0; m < MT; ++m)
#pragma unroll
            for (int nt = 0; nt < 4; ++nt) {
                int px = nt * 16 + lm;
#pragma unroll
                for (int r = 0; r < 4; ++r) {
                    int co = cob + m * 16 + quad * 4 + r;
                    ob[(size_t)co * 64 + px] = acc[m][nt][r] + bias[co];
                }
            }
    }
}

// ---------------------------------------------------------------------------
// MFMA GDN, all 4 sites. Tile = [256ch][64px] bf16, in place.
//   norm[co][px] = beta[co] + sum_ci gamma[co][ci] * x[ci][px]^2   (MFMA GEMM
//   M=256,N=64,K=256; A = repacked bf16 gamma [co][ci], B = bf16 x^2 staged
//   [px][ci] stride 264 -- exact mconv/mdeconv2 fragment layout)
//   out = x * rsqrt(norm)  (INVERSE: * sqrt(norm))
// IMG = u16 stride per blockIdx.x, YOFF = per blockIdx.y, RS = channel row
// stride. Sites: a1 <65536,64,256> grid(1024,4); a2/d1 <16384,16384,64>
// grid(1024,1); d2 planar <65536,16384,64> grid(1024,4).
// ---------------------------------------------------------------------------
template<bool INVERSE, int IMG, int YOFF, int RS>
__global__ __launch_bounds__(256)
void gdnm(u16* __restrict__ x, const float* __restrict__ beta,
          const u16* __restrict__ Ag)
{
    constexpr int STR = 264;
    __shared__ u16 xb[256 * 64];   // original bf16 tile [ch][px]  (32 KB)
    __shared__ u16 xq[64 * STR];   // bf16 squares [px][ci]        (33 KB)
    const int tid = threadIdx.x;
    const int lane = tid & 63, wv = tid >> 6;
    const int lm = lane & 15, quad = lane >> 4;
    const int cob = wv * 64;
    u16* xg = x + (size_t)blockIdx.x * IMG + (size_t)blockIdx.y * YOFF;

    // stage in: raw u64 copy (4 u16 each), verified r2/r4 formula
#pragma unroll
    for (int it = 0; it < 16; ++it) {
        int v = it * 256 + tid;          // [0,4096)
        int ch = v >> 4, pxg = (v & 15) * 4;
        *(u64t*)&xb[v * 4] = *(const u64t*)&xg[(size_t)ch * RS + pxg];
    }
    __syncthreads();

    // build xq[px][ci] = bf16(x^2); bank-staggered ((w+px)&31) -> conflict-free
    {
        const int px = tid & 63, g = tid >> 6;   // g in [0,4): 64-ci band
#pragma unroll
        for (int w = 0; w < 32; ++w) {
            int ci = g * 64 + ((w + px) & 31) * 2;
            float x0 = b2f(xb[ci * 64 + px]);
            float x1 = b2f(xb[(ci + 1) * 64 + px]);
            unsigned pk = (unsigned)f2b(x0 * x0) | ((unsigned)f2b(x1 * x1) << 16);
            *(unsigned*)&xq[px * STR + ci] = pk;
        }
    }
    __syncthreads();

    f32x4 acc[4][4];
#pragma unroll
    for (int m = 0; m < 4; ++m)
#pragma unroll
        for (int n = 0; n < 4; ++n) acc[m][n] = (f32x4){0.f, 0.f, 0.f, 0.f};

#pragma unroll 1
    for (int kc = 0; kc < 8; ++kc) {
        bf16x8 bf[4];
#pragma unroll
        for (int nt = 0; nt < 4; ++nt)
            bf[nt] = *(const bf16x8*)&xq[(nt * 16 + lm) * STR + kc * 32 + quad * 8];
        bf16x8 af[4];
#pragma unroll
        for (int m = 0; m < 4; ++m)
            af[m] = *(const bf16x8*)(Ag + (size_t)(cob + m * 16 + lm) * 256 + kc * 32 + quad * 8);
#pragma unroll
        for (int m = 0; m < 4; ++m)
#pragma unroll
            for (int nt = 0; nt < 4; ++nt)
                acc[m][nt] = __builtin_amdgcn_mfma_f32_16x16x32_bf16(af[m], bf[nt], acc[m][nt], 0, 0, 0);
    }

    // epilogue: scale xb in place (each cell owned by exactly one lane)
#pragma unroll
    for (int m = 0; m < 4; ++m)
#pragma unroll
        for (int nt = 0; nt < 4; ++nt)
#pragma unroll
            for (int r = 0; r < 4; ++r) {
                int co = cob + m * 16 + quad * 4 + r;
                int px = nt * 16 + lm;
                float norm = acc[m][nt][r] + beta[co];
                float rr = INVERSE ? sqrtf(norm) : rsqrtf(norm);
                u16* p = &xb[co * 64 + px];
                *p = f2b(b2f(*p) * rr);
            }
    __syncthreads();

    // stage out: raw u64 copy
#pragma unroll
    for (int it = 0; it < 16; ++it) {
        int v = it * 256 + tid;
        int ch = v >> 4, pxg = (v & 15) * 4;
        *(u64t*)&xg[(size_t)ch * RS + pxg] = *(const u64t*)&xb[v * 4];
    }
}

// ---------------------------------------------------------------------------
// MFMA ConvTranspose2d k=5 s=2, 8x8 -> 16x16, 256->256, input d1 bf16,
// out bf16 QUADRANT-PLANAR d2[b][q][co][sp]. LDS bounce -> u64 stores.
// ---------------------------------------------------------------------------
__global__ __launch_bounds__(256)
void mdeconv2(const u16* __restrict__ in, const u16* __restrict__ A2,
              const float* __restrict__ bias, u16* __restrict__ out)
{
    constexpr int STRIDE = 264;
    __shared__ u16 bs[100 * STRIDE];
    __shared__ u16 os[256 * 64];
    const int b = blockIdx.x, tid = threadIdx.x;
    const int lane = tid & 63, wv = tid >> 6, lm = lane & 15, quad = lane >> 4;
    const int cob = wv * 64;
    const u16* inb = in + (size_t)b * 256 * 64;

    unsigned* bz = (unsigned*)bs;
    for (int i = tid; i < 100 * STRIDE / 2; i += 256) bz[i] = 0u;
    __syncthreads();
    for (int i = tid; i < 64 * 64; i += 256) {
        int px = i & 63, cg = i >> 6;
        int iy = px >> 3, ix = px & 7;
        const u16* ip = inb + (size_t)cg * 4 * 64 + px;
        u16x4 p;
        p.x0 = ip[0]; p.x1 = ip[64]; p.x2 = ip[128]; p.x3 = ip[192];
        *(u16x4*)&bs[((iy + 1) * 10 + ix + 1) * STRIDE + cg * 4] = p;
    }
    __syncthreads();

    int bofs[4];
#pragma unroll
    for (int nt = 0; nt < 4; ++nt) {
        int sp = nt * 16 + lm, sy = sp >> 3, sx = sp & 7;
        bofs[nt] = ((sy + 2) * 10 + sx + 2) * STRIDE + quad * 8;
    }

#pragma unroll
    for (int qy = 0; qy < 2; ++qy)
#pragma unroll
        for (int qx = 0; qx < 2; ++qx) {
            const int q = qy * 2 + qx;
            f32x4 acc[4][4];
#pragma unroll
            for (int m = 0; m < 4; ++m)
#pragma unroll
                for (int n = 0; n < 4; ++n) acc[m][n] = (f32x4){0.f, 0.f, 0.f, 0.f};

            const int NT = (3 - qy) * (3 - qx);
#pragma unroll 1
            for (int tt = 0; tt < NT; ++tt) {
                const int ty = tt / (3 - qx), tx = tt % (3 - qx);
                const int tofs = -(ty * 10 + tx) * STRIDE;
                const u16* At = A2 + (size_t)(q * 9 + ty * 3 + tx) * 256 * 256 + quad * 8;
#pragma unroll
                for (int kc = 0; kc < 8; ++kc) {
                    bf16x8 bf[4];
#pragma unroll
                    for (int nt = 0; nt < 4; ++nt)
                        bf[nt] = *(const bf16x8*)&bs[bofs[nt] + tofs + kc * 32];
                    bf16x8 af[4];
#pragma unroll
                    for (int m = 0; m < 4; ++m)
                        af[m] = *(const bf16x8*)(At + (size_t)(cob + m * 16 + lm) * 256 + kc * 32);
#pragma unroll
                    for (int m = 0; m < 4; ++m)
#pragma unroll
                        for (int nt = 0; nt < 4; ++nt)
                            acc[m][nt] = __builtin_amdgcn_mfma_f32_16x16x32_bf16(af[m], bf[nt], acc[m][nt], 0, 0, 0);
                }
            }
            // bounce fragments -> LDS -> contiguous u32-pair -> u64 stores
#pragma unroll
            for (int m = 0; m < 4; ++m)
#pragma unroll
                for (int nt = 0; nt < 4; ++nt)
#pragma unroll
                    for (int r = 0; r < 4; ++r) {
                        int co = cob + m * 16 + quad * 4 + r;
                        os[co * 64 + nt * 16 + lm] = f2b(acc[m][nt][r] + bias[co]);
                    }
            __syncthreads();
            u16* od = out + ((size_t)(b * 4 + q)) * 256 * 64;
            const unsigned* osw = (const unsigned*)os;
#pragma unroll
            for (int it = 0; it < 16; ++it) {
                int v = it * 256 + tid;
                unsigned lo = osw[v * 2], hi = osw[v * 2 + 1];
                *(u64t*)&od[v * 4] = (u64t)lo | ((u64t)hi << 32);
            }
            __syncthreads();
        }
}

// ---------------------------------------------------------------------------
// deconv3 (VALU): ConvTranspose2d s2, 256->2, 16x16 -> 32x32, clip [0,1].
// Input d2 bf16 QUADRANT-PLANAR [b][q][ci][sp]. f32 dword output stores.
// ---------------------------------------------------------------------------
__global__ __launch_bounds__(256)
void dec3k(const u16* __restrict__ in, const float* __restrict__ W3r,
           const float* __restrict__ bias, float* __restrict__ out)
{
    constexpr int HT = 18;
    __shared__ float ls[32 * HT * HT];
    const int b = blockIdx.x, tid = threadIdx.x;
    const int sy = tid >> 4, sx = tid & 15;
    const u16* inb = in + (size_t)b * 4 * 256 * 64;
    float acc[4][2] = {};
#pragma unroll 1
    for (int ch = 0; ch < 8; ++ch) {
        if (ch) __syncthreads();
        for (int i = tid; i < 32 * HT * HT; i += 256) ls[i] = 0.f;
        __syncthreads();
        for (int i = tid; i < 32 * 256; i += 256) {
            int ci = i >> 8, px = i & 255, iy = px >> 4, ix = px & 15;
            int q = (iy & 1) * 2 + (ix & 1);
            int sp = (iy >> 1) * 8 + (ix >> 1);
            ls[ci * (HT * HT) + (iy + 1) * HT + ix + 1] =
                b2f(inb[((size_t)q * 256 + ch * 32 + ci) * 64 + sp]);
        }
        __syncthreads();
#pragma unroll 1
        for (int ci = 0; ci < 32; ++ci) {
            float v[9];
            const float* l = &ls[ci * (HT * HT) + (sy + 2) * HT + sx + 2];
#pragma unroll
            for (int ty = 0; ty < 3; ++ty)
#pragma unroll
                for (int tx = 0; tx < 3; ++tx) v[ty * 3 + tx] = l[-(ty * HT) - tx];
#pragma unroll
            for (int q = 0; q < 4; ++q) {
                const float* wp = W3r + (size_t)ufl(((q * 256 + ch * 32 + ci) * 2) * 16);
#pragma unroll
                for (int t = 0; t < 9; ++t) {
                    acc[q][0] = fmaf(wp[t], v[t], acc[q][0]);
                    acc[q][1] = fmaf(wp[16 + t], v[t], acc[q][1]);
                }
            }
        }
    }
    float* ob = out + (size_t)b * 2 * 1024;
#pragma unroll
    for (int q = 0; q < 4; ++q) {
        int qy = q >> 1, qx = q & 1;
        int oy = 2 * sy + qy, ox = 2 * sx + qx;
#pragma unroll
        for (int co = 0; co < 2; ++co) {
            float r = acc[q][co] + bias[co];
            r = fminf(fmaxf(r, 0.f), 1.f);
            ob[(size_t)co * 1024 + oy * 32 + ox] = r;
        }
    }
}

// ---------------------------------------------------------------------------
// conv1: direct conv (CIN=2). bf16 output bounced through LDS -> u32-pair ->
// u64 stores. Only instantiated with PX==256, NCOG==1.
// ---------------------------------------------------------------------------
template<int CIN, int COUT, int HIN, int WIN, int S, int CI_CHUNK, int CO_PER_BLOCK>
__global__ __launch_bounds__(256)
void conv5k(const float* __restrict__ in, const float* __restrict__ wt,
            const float* __restrict__ bias, u16* __restrict__ out)
{
    constexpr int HOUT = HIN / S, WOUT = WIN / S;
    constexpr int PX = HOUT * WOUT;          // 256
    constexpr int CO_ITERS = CO_PER_BLOCK;   // 16
    constexpr int HT = HIN + 4, WT = WIN + 4;
    constexpr int NCHUNK = CIN / CI_CHUNK;
    constexpr int TILE = CI_CHUNK * HT * WT;

    __shared__ float lds[TILE];
    __shared__ u16 os[CO_PER_BLOCK * PX];

    const int b = blockIdx.x;
    const int co_base = blockIdx.y * CO_PER_BLOCK;
    const int tid = threadIdx.x;
    const int px = tid;
    const int oy = px / WOUT, ox = px % WOUT;

    float acc[CO_ITERS];
#pragma unroll
    for (int i = 0; i < CO_ITERS; ++i) acc[i] = 0.f;

    const float* inb = in + (size_t)b * CIN * HIN * WIN;

#pragma unroll 1
    for (int ch = 0; ch < NCHUNK; ++ch) {
        if (ch) __syncthreads();
        for (int idx = tid; idx < TILE; idx += 256) lds[idx] = 0.f;
        __syncthreads();
        for (int idx = tid; idx < CI_CHUNK * HIN * WIN; idx += 256) {
            int ci = idx / (HIN * WIN);
            int r = idx - ci * (HIN * WIN);
            int iy = r / WIN, ix = r - iy * WIN;
            lds[ci * (HT * WT) + (iy + 2) * WT + (ix + 2)] =
                inb[(size_t)(ch * CI_CHUNK + ci) * (HIN * WIN) + r];
        }
        __syncthreads();

#pragma unroll 1
        for (int ci = 0; ci < CI_CHUNK; ++ci) {
            float v[25];
            const float* l = &lds[ci * (HT * WT) + (oy * S) * WT + (ox * S)];
#pragma unroll
            for (int ky = 0; ky < 5; ++ky)
#pragma unroll
                for (int kx = 0; kx < 5; ++kx)
                    v[ky * 5 + kx] = l[ky * WT + kx];
#pragma unroll
            for (int i = 0; i < CO_ITERS; ++i) {
                const int co = co_base + i;
                const float* wp = wt + (size_t)ufl((co * CIN + ch * CI_CHUNK + ci) * 25);
#pragma unroll
                for (int t = 0; t < 25; ++t) acc[i] = fmaf(wp[t], v[t], acc[i]);
            }
        }
    }

#pragma unroll
    for (int i = 0; i < CO_ITERS; ++i)
        os[i * PX + px] = f2b(acc[i] + bias[co_base + i]);
    __syncthreads();
    u16* ob = out + ((size_t)b * COUT + co_base) * PX;
    const unsigned* osw = (const unsigned*)os;
#pragma unroll
    for (int it = 0; it < CO_PER_BLOCK * PX / 1024; ++it) {
        int v = it * 256 + tid;
        unsigned lo = osw[v * 2], hi = osw[v * 2 + 1];
        *(u64t*)&ob[v * 4] = (u64t)lo | ((u64t)hi << 32);
    }
}

// ---------------------------------------------------------------------------
// Fused context model (unchanged, verified).
// ---------------------------------------------------------------------------
__global__ __launch_bounds__(256)
void trik(float* __restrict__ y, const float* __restrict__ noise,
          const float* __restrict__ H, const float* __restrict__ mean,
          const float* __restrict__ scale, float* __restrict__ lik)
{
    __shared__ float h[64 * 65];
    const int c = blockIdx.x;
    const int bt = blockIdx.y;
    const int tid = threadIdx.x;
    const int lane = tid & 63;
    const int wv = tid >> 6;

    const float* Hc = H + (size_t)c * 4096;
    for (int idx = tid; idx < 4096; idx += 256) {
        const int i = idx >> 6, j = idx & 63;
        h[i * 65 + j] = Hc[idx];
    }
    __syncthreads();

    const int b = bt * 4 + wv;
    const size_t base = ((size_t)b * 320 + c) * 64 + lane;
    const float* hrow = &h[lane * 65];

    const float yv = y[base];
    float ws = 0.f;
#pragma unroll 8
    for (int j = 0; j < 64; ++j) {
        const float yj = __shfl(yv, j, 64);
        const float hv = (j < lane) ? hrow[j] : 0.f;
        ws = fmaf(hv, yj, ws);
    }
    const float wh = yv - ws + noise[base];

    const float mn = mean[c * 64 + lane];
    const float sc = fmaxf(scale[c * 64 + lane], 0.11f);
    const float vv = fabsf(wh - mn);
    const float cst = -0.70710678118654752f;
    const float upper = 0.5f * erfcf(cst * (0.5f - vv) / sc);
    const float lower = 0.5f * erfcf(cst * (-0.5f - vv) / sc);
    lik[base] = fmaxf(upper - lower, 1e-9f);

    float acc = wh;
#pragma unroll 8
    for (int j = 0; j < 64; ++j) {
        const float yj = __shfl(acc, j, 64);
        const float hv = (j < lane) ? hrow[j] : 0.f;
        acc = fmaf(hv, yj, acc);
    }
    y[base] = acc;
}

// ---------------------------------------------------------------------------
extern "C" void kernel_launch(void* const* d_in, const int* in_sizes, int n_in,
                              void* d_out, int out_size, void* d_ws, size_t ws_size,
                              hipStream_t stream)
{
    (void)in_sizes; (void)n_in; (void)out_size; (void)ws_size;

    const float* x      = (const float*)d_in[0];
    const float* noise  = (const float*)d_in[1];
    const float* w1     = (const float*)d_in[2];
    const float* b1     = (const float*)d_in[3];
    const float* beta1  = (const float*)d_in[4];
    const float* gamma1 = (const float*)d_in[5];
    const float* w2     = (const float*)d_in[6];
    const float* b2     = (const float*)d_in[7];
    const float* beta2  = (const float*)d_in[8];
    const float* gamma2 = (const float*)d_in[9];
    const float* w3     = (const float*)d_in[10];
    const float* b3     = (const float*)d_in[11];
    const float* dw1    = (const float*)d_in[12];
    const float* db1    = (const float*)d_in[13];
    const float* ibeta1 = (const float*)d_in[14];
    const float* igamma1= (const float*)d_in[15];
    const float* dw2    = (const float*)d_in[16];
    const float* db2    = (const float*)d_in[17];
    const float* ibeta2 = (const float*)d_in[18];
    const float* igamma2= (const float*)d_in[19];
    const float* dw3    = (const float*)d_in[20];
    const float* db3    = (const float*)d_in[21];
    const float* mean   = (const float*)d_in[22];
    const float* scale  = (const float*)d_in[23];
    const float* H      = (const float*)d_in[24];

    float* outp = (float*)d_out;
    float* xhat = outp;                                   // [1024,2,32,32]
    float* lik  = outp + (size_t)1024 * 2 * 32 * 32;      // [1024,320,64]

    // workspace layout:
    //   [0, 134.2M)        a1 bf16 -> y f32 -> d2 bf16 (quadrant-planar)
    //   [134.2M, 167.8M)   a2 bf16 -> d1 bf16  (33.5 MB)
    //   [167.8M, 168.3M)   repacked gammas (4 x 128 KB, live whole call)
    //   [201.3M, 217.8M)   repacked conv weights (live whole call)
    char* ws = (char*)d_ws;
    u16*   a1  = (u16*)ws;
    float* y   = (float*)ws;
    u16*   d2  = (u16*)ws;
    u16*   a2  = (u16*)(ws + 134217728);
    u16*   d1  = (u16*)(ws + 134217728);
    u16*   Ag1 = (u16*)(ws + 167772160);
    u16*   Ag2 = (u16*)(ws + 167903232);
    u16*   Ag3 = (u16*)(ws + 168034304);
    u16*   Ag4 = (u16*)(ws + 168165376);
    u16*   Ac2 = (u16*)(ws + 201326592);
    u16*   Ac3 = (u16*)(ws + 204603392);
    u16*   Ad1 = (u16*)(ws + 208699392);
    u16*   Ad2 = (u16*)(ws + 212795392);
    float* W3r = (float*)(ws + 217513984);

    // ---- weight repacks ----
    rk_fwd<256, 256><<<3200, 256, 0, stream>>>(w2, Ac2);
    rk_fwd<256, 320><<<4000, 256, 0, stream>>>(w3, Ac3);
    rk_d1<<<4000, 256, 0, stream>>>(dw1, Ad1);
    rk_d2<<<4608, 256, 0, stream>>>(dw2, Ad2);
    rk_d3<<<128, 256, 0, stream>>>(dw3, W3r);
    rk_g<<<128, 256, 0, stream>>>(gamma1, Ag1);
    rk_g<<<128, 256, 0, stream>>>(gamma2, Ag2);
    rk_g<<<128, 256, 0, stream>>>(igamma1, Ag3);
    rk_g<<<128, 256, 0, stream>>>(igamma2, Ag4);

    // ---- analysis ----
    conv5k<2, 256, 32, 32, 2, 2, 16><<<dim3(1024, 16), 256, 0, stream>>>(x, w1, b1, a1);
    gdnm<false, 65536, 64, 256><<<dim3(1024, 4), 256, 0, stream>>>(a1, beta1, Ag1);
    mconv<256, 256, 2, 4, u16, u16><<<1024, 256, 0, stream>>>(a1, Ac2, b2, a2);
    gdnm<false, 16384, 16384, 64><<<dim3(1024, 1), 256, 0, stream>>>(a2, beta2, Ag2);
    mconv<256, 320, 1, 5, u16, float><<<1024, 256, 0, stream>>>(a2, Ac3, b3, y);

    // ---- context model ----
    trik<<<dim3(320, 256), 256, 0, stream>>>(y, noise, H, mean, scale, lik);

    // ---- synthesis ----
    mconv<320, 256, 1, 4, float, u16><<<1024, 256, 0, stream>>>(y, Ad1, db1, d1);
    gdnm<true, 16384, 16384, 64><<<dim3(1024, 1), 256, 0, stream>>>(d1, ibeta1, Ag3);
    mdeconv2<<<1024, 256, 0, stream>>>(d1, Ad2, db2, d2);
    gdnm<true, 65536, 16384, 64><<<dim3(1024, 4), 256, 0, stream>>>(d2, ibeta2, Ag4);
    dec3k<<<1024, 256, 0, stream>>>(d2, W3r, db3, xhat);
}

// Round 7
// 3466.172 us; speedup vs baseline: 2.7662x; 1.0988x over previous
//
#include <hip/hip_runtime.h>
#include <math.h>

typedef unsigned short u16;
typedef unsigned long long u64t;
typedef __bf16 bf16x8 __attribute__((ext_vector_type(8)));
typedef float f32x4 __attribute__((ext_vector_type(4)));
struct alignas(8) u16x4 { u16 x0, x1, x2, x3; };

__device__ __forceinline__ int ufl(int v) { return __builtin_amdgcn_readfirstlane(v); }
__device__ __forceinline__ u16 f2b(float f) {
    unsigned u = __float_as_uint(f);
    return (u16)((u + 0x7FFFu + ((u >> 16) & 1u)) >> 16);   // RNE fp32->bf16
}
__device__ __forceinline__ float b2f(u16 h) { return __uint_as_float(((unsigned)h) << 16); }
__device__ __forceinline__ u16 tob(float v) { return f2b(v); }
__device__ __forceinline__ u16 tob(u16 v)   { return v; }

// ---------------------------------------------------------------------------
// SESSION LEDGER (counter evidence):
//  * r0-r2: WRITE_SIZE 66x amp was scratch SPILL (acc[64] @ VGPR 64), not
//    store width. Fix confirmed r4. ALWAYS check VGPR vs per-thread arrays.
//  * r3 lesson: u64 = FOUR u16. Verify copy-loop element counts.
//  * r4->r5: GDN moved to MFMA (gdnm) -> off critical path. 5597->3808.
//  * r5: mconv<320,256> 697us: MfmaUtil 15.6%, VALUBusy 6%, HBM 2%, occ 22%
//    => LATENCY-bound: inner iter = 4 global A-loads (L2 ~200cy) + 4
//    ds_read_b128 + 16 MFMA (77cy), '#pragma unroll 1' blocks overlap.
//    Fix (this round): flatten (tap,kc), reg-double-buffer af one half-iter
//    ahead (global loads issued before current MFMA block). Same acc order.
//  * r6: bench infra failure (container acquisition), kernel never ran.
//    Resubmitted unchanged.
// ---------------------------------------------------------------------------

// ---------------------------------------------------------------------------
// Weight repacks (paired u32 stores).
// ---------------------------------------------------------------------------
// forward conv: W[COUT][CIN][25] f32 -> A[25][COUT][CIN] bf16 (ci pairs)
template<int CIN, int COUT>
__global__ __launch_bounds__(256) void rk_fwd(const float* __restrict__ w, u16* __restrict__ a) {
    int j = (blockIdx.x * 256 + threadIdx.x) * 2;
    if (j >= 25 * COUT * CIN) return;
    int ci = j % CIN; int r = j / CIN; int co = r % COUT; int t = r / COUT;
    u16 lo = f2b(w[(co * CIN + ci) * 25 + t]);
    u16 hi = f2b(w[(co * CIN + ci + 1) * 25 + t]);
    *(unsigned*)&a[j] = (unsigned)lo | ((unsigned)hi << 16);
}
// deconv1 (s1 gather): W[320ci][256co][25] -> A[t'][256co][320ci], t'=(4-ky)*5+(4-kx)
__global__ __launch_bounds__(256) void rk_d1(const float* __restrict__ w, u16* __restrict__ a) {
    int j = (blockIdx.x * 256 + threadIdx.x) * 2;
    if (j >= 25 * 256 * 320) return;
    int ci = j % 320; int r = j / 320; int co = r % 256; int tp = r / 256;
    int ky = 4 - tp / 5, kx = 4 - tp % 5;
    u16 lo = f2b(w[(ci * 256 + co) * 25 + ky * 5 + kx]);
    u16 hi = f2b(w[((ci + 1) * 256 + co) * 25 + ky * 5 + kx]);
    *(unsigned*)&a[j] = (unsigned)lo | ((unsigned)hi << 16);
}
// deconv2 (s2 parity): W[256ci][256co][25] -> A2[q*9+tt][256co][256ci], zero invalid taps
__global__ __launch_bounds__(256) void rk_d2(const float* __restrict__ w, u16* __restrict__ a) {
    int j = (blockIdx.x * 256 + threadIdx.x) * 2;
    if (j >= 36 * 256 * 256) return;
    int ci = j % 256; int r = j / 256; int co = r % 256; int qt = r / 256;
    int q = qt / 9, tt = qt % 9;
    int qy = q >> 1, qx = q & 1, ty = tt / 3, tx = tt % 3;
    u16 lo = 0, hi = 0;
    if (ty < 3 - qy && tx < 3 - qx) {
        int widx = (qy + 2 * ty) * 5 + (qx + 2 * tx);
        lo = f2b(w[(ci * 256 + co) * 25 + widx]);
        hi = f2b(w[((ci + 1) * 256 + co) * 25 + widx]);
    }
    *(unsigned*)&a[j] = (unsigned)lo | ((unsigned)hi << 16);
}
// deconv3: W[256ci][2co][25] f32 -> W3r[4q][256ci][2co][16] f32 (9 taps zero-padded)
__global__ __launch_bounds__(256) void rk_d3(const float* __restrict__ w, float* __restrict__ a) {
    int i = blockIdx.x * 256 + threadIdx.x;
    if (i >= 4 * 256 * 2 * 16) return;
    int t = i % 16; int r = i / 16; int co = r % 2; int r2 = r / 2; int ci = r2 % 256; int q = r2 / 256;
    int qy = q >> 1, qx = q & 1;
    float v = 0.f;
    if (t < 9) {
        int ty = t / 3, tx = t % 3;
        if (ty < 3 - qy && tx < 3 - qx) v = w[(ci * 2 + co) * 25 + (qy + 2 * ty) * 5 + (qx + 2 * tx)];
    }
    a[i] = v;
}
// GDN gamma: f32 [256co][256ci] -> bf16 [co][ci] (ci pairs)
__global__ __launch_bounds__(256) void rk_g(const float* __restrict__ g, u16* __restrict__ a) {
    int j = (blockIdx.x * 256 + threadIdx.x) * 2;
    if (j >= 256 * 256) return;
    u16 lo = f2b(g[j]);
    u16 hi = f2b(g[j + 1]);
    *(unsigned*)&a[j] = (unsigned)lo | ((unsigned)hi << 16);
}

// ---------------------------------------------------------------------------
// MFMA implicit-GEMM conv (k=5 pad=2 stride S in {1,2}), out 8x8 per image.
// Inner loop flattened over it=(tap,kc) with af (global A-fragments) register
// double-buffered one half-iter ahead to hide L2 latency under MFMA.
// TOUT=float: dword stores. TOUT=u16: LDS-bounce epilogue -> u64 stores.
// ---------------------------------------------------------------------------
template<int CIN, int COUT, int S, int MT, typename TIN, typename TOUT>
__global__ __launch_bounds__(256)
void mconv(const TIN* __restrict__ in, const u16* __restrict__ A,
           const float* __restrict__ bias, TOUT* __restrict__ out)
{
    constexpr bool O16 = (sizeof(TOUT) == 2);
    constexpr int HIN = 8 * S, HP = 7 * S + 5, CHUNK = 64, STRIDE = CHUNK + 8;
    constexpr int NCH = CIN / CHUNK;
    constexpr int SP = HP * HP;
    constexpr int BSE = SP * STRIDE;
    constexpr int OSE = O16 ? COUT * 64 : 0;
    constexpr int NIT = 50;                    // 25 taps * KCN, KCN = CHUNK/32 = 2
    __shared__ u16 bs[(BSE > OSE) ? BSE : OSE];

    const int b = blockIdx.x;
    const int tid = threadIdx.x;
    const int lane = tid & 63, wv = tid >> 6;
    const int lm = lane & 15, quad = lane >> 4;
    const int cob = wv * (MT * 16);
    const TIN* inb = in + (size_t)b * CIN * (HIN * HIN);

    int bofs[4];
#pragma unroll
    for (int nt = 0; nt < 4; ++nt) {
        int px = nt * 16 + lm, oy = px >> 3, ox = px & 7;
        bofs[nt] = (S * oy * HP + S * ox) * STRIDE + quad * 8;
    }

    f32x4 acc[MT][4];
#pragma unroll
    for (int m = 0; m < MT; ++m)
#pragma unroll
        for (int n = 0; n < 4; ++n) acc[m][n] = (f32x4){0.f, 0.f, 0.f, 0.f};

#pragma unroll 1
    for (int ch = 0; ch < NCH; ++ch) {
        if (ch) __syncthreads();
        unsigned* bz = (unsigned*)bs;
        for (int i = tid; i < BSE / 2; i += 256) bz[i] = 0u;
        __syncthreads();
        for (int i = tid; i < (CHUNK / 4) * (HIN * HIN); i += 256) {
            int px = i % (HIN * HIN), cg = i / (HIN * HIN);
            int iy = px / HIN, ix = px % HIN;
            const TIN* ip = inb + (size_t)(ch * CHUNK + cg * 4) * (HIN * HIN) + px;
            u16x4 p;
            p.x0 = tob(ip[0]);
            p.x1 = tob(ip[HIN * HIN]);
            p.x2 = tob(ip[2 * HIN * HIN]);
            p.x3 = tob(ip[3 * HIN * HIN]);
            *(u16x4*)&bs[((iy + 2) * HP + ix + 2) * STRIDE + cg * 4] = p;
        }
        __syncthreads();

        // per-m A row base pointers for this ci-chunk
        const u16* Ar[MT];
#pragma unroll
        for (int m = 0; m < MT; ++m)
            Ar[m] = A + ch * CHUNK + quad * 8 + (size_t)(cob + m * 16 + lm) * CIN;

        bf16x8 af0[MT], af1[MT];
#pragma unroll
        for (int m = 0; m < MT; ++m) af0[m] = *(const bf16x8*)(Ar[m]);   // it=0

#pragma unroll 1
        for (int it = 0; it < NIT; it += 2) {
            // prefetch it+1 (same tap, kc=1)
            const int tapB = (it + 1) >> 1, kcB = (it + 1) & 1;
            const size_t oB = (size_t)tapB * (COUT * CIN) + kcB * 32;
#pragma unroll
            for (int m = 0; m < MT; ++m) af1[m] = *(const bf16x8*)(Ar[m] + oB);
            {
                const int tap = it >> 1, kc = it & 1;
                const int tofs = ((tap / 5) * HP + (tap % 5)) * STRIDE + kc * 32;
                bf16x8 bf[4];
#pragma unroll
                for (int nt = 0; nt < 4; ++nt)
                    bf[nt] = *(const bf16x8*)&bs[bofs[nt] + tofs];
#pragma unroll
                for (int m = 0; m < MT; ++m)
#pragma unroll
                    for (int nt = 0; nt < 4; ++nt)
                        acc[m][nt] = __builtin_amdgcn_mfma_f32_16x16x32_bf16(af0[m], bf[nt], acc[m][nt], 0, 0, 0);
            }
            // prefetch it+2 (next tap, kc=0)
            if (it + 2 < NIT) {
                const size_t oC = (size_t)((it + 2) >> 1) * (COUT * CIN);
#pragma unroll
                for (int m = 0; m < MT; ++m) af0[m] = *(const bf16x8*)(Ar[m] + oC);
            }
            {
                const int tofs = ((tapB / 5) * HP + (tapB % 5)) * STRIDE + kcB * 32;
                bf16x8 bf[4];
#pragma unroll
                for (int nt = 0; nt < 4; ++nt)
                    bf[nt] = *(const bf16x8*)&bs[bofs[nt] + tofs];
#pragma unroll
                for (int m = 0; m < MT; ++m)
#pragma unroll
                    for (int nt = 0; nt < 4; ++nt)
                        acc[m][nt] = __builtin_amdgcn_mfma_f32_16x16x32_bf16(af1[m], bf[nt], acc[m][nt], 0, 0, 0);
            }
        }
    }

    if constexpr (O16) {
        __syncthreads();          // all MFMA reads of bs done before reuse
#pragma unroll
        for (int m = 0; m < MT; ++m)
#pragma unroll
            for (int nt = 0; nt < 4; ++nt)
#pragma unroll
                for (int r = 0; r < 4; ++r) {
                    int co = cob + m * 16 + quad * 4 + r;
                    bs[co * 64 + nt * 16 + lm] = f2b(acc[m][nt][r] + bias[co]);
                }
        __syncthreads();
        u16* ob = out + (size_t)b * COUT * 64;
        const unsigned* osw = (const unsigned*)bs;
#pragma unroll
        for (int it = 0; it < COUT / 16; ++it) {
            int v = it * 256 + tid;
            unsigned lo = osw[v * 2], hi = osw[v * 2 + 1];
            *(u64t*)&ob[v * 4] = (u64t)lo | ((u64t)hi << 32);
        }
    } else {
        float* ob = (float*)out + (size_t)b * COUT * 64;
#pragma unroll
        for (int m = 0; m < MT; ++m)
#pragma unroll
            for (int nt = 0; nt < 4; ++nt) {
                int px = nt * 16 + lm;
#pragma unroll
                for (int r = 0; r < 4; ++r) {
                    int co = cob + m * 16 + quad * 4 + r;
                    ob[(size_t)co * 64 + px] = acc[m][nt][r] + bias[co];
                }
            }
    }
}

// ---------------------------------------------------------------------------
// MFMA GDN, all 4 sites (verified r5). Tile = [256ch][64px] bf16, in place.
// ---------------------------------------------------------------------------
template<bool INVERSE, int IMG, int YOFF, int RS>
__global__ __launch_bounds__(256)
void gdnm(u16* __restrict__ x, const float* __restrict__ beta,
          const u16* __restrict__ Ag)
{
    constexpr int STR = 264;
    __shared__ u16 xb[256 * 64];   // original bf16 tile [ch][px]  (32 KB)
    __shared__ u16 xq[64 * STR];   // bf16 squares [px][ci]        (33 KB)
    const int tid = threadIdx.x;
    const int lane = tid & 63, wv = tid >> 6;
    const int lm = lane & 15, quad = lane >> 4;
    const int cob = wv * 64;
    u16* xg = x + (size_t)blockIdx.x * IMG + (size_t)blockIdx.y * YOFF;

#pragma unroll
    for (int it = 0; it < 16; ++it) {
        int v = it * 256 + tid;          // [0,4096)
        int ch = v >> 4, pxg = (v & 15) * 4;
        *(u64t*)&xb[v * 4] = *(const u64t*)&xg[(size_t)ch * RS + pxg];
    }
    __syncthreads();

    // build xq[px][ci] = bf16(x^2); bank-staggered ((w+px)&31) -> conflict-free
    {
        const int px = tid & 63, g = tid >> 6;   // g in [0,4): 64-ci band
#pragma unroll
        for (int w = 0; w < 32; ++w) {
            int ci = g * 64 + ((w + px) & 31) * 2;
            float x0 = b2f(xb[ci * 64 + px]);
            float x1 = b2f(xb[(ci + 1) * 64 + px]);
            unsigned pk = (unsigned)f2b(x0 * x0) | ((unsigned)f2b(x1 * x1) << 16);
            *(unsigned*)&xq[px * STR + ci] = pk;
        }
    }
    __syncthreads();

    f32x4 acc[4][4];
#pragma unroll
    for (int m = 0; m < 4; ++m)
#pragma unroll
        for (int n = 0; n < 4; ++n) acc[m][n] = (f32x4){0.f, 0.f, 0.f, 0.f};

#pragma unroll 1
    for (int kc = 0; kc < 8; ++kc) {
        bf16x8 bf[4];
#pragma unroll
        for (int nt = 0; nt < 4; ++nt)
            bf[nt] = *(const bf16x8*)&xq[(nt * 16 + lm) * STR + kc * 32 + quad * 8];
        bf16x8 af[4];
#pragma unroll
        for (int m = 0; m < 4; ++m)
            af[m] = *(const bf16x8*)(Ag + (size_t)(cob + m * 16 + lm) * 256 + kc * 32 + quad * 8);
#pragma unroll
        for (int m = 0; m < 4; ++m)
#pragma unroll
            for (int nt = 0; nt < 4; ++nt)
                acc[m][nt] = __builtin_amdgcn_mfma_f32_16x16x32_bf16(af[m], bf[nt], acc[m][nt], 0, 0, 0);
    }

    // epilogue: scale xb in place (each cell owned by exactly one lane)
#pragma unroll
    for (int m = 0; m < 4; ++m)
#pragma unroll
        for (int nt = 0; nt < 4; ++nt)
#pragma unroll
            for (int r = 0; r < 4; ++r) {
                int co = cob + m * 16 + quad * 4 + r;
                int px = nt * 16 + lm;
                float norm = acc[m][nt][r] + beta[co];
                float rr = INVERSE ? sqrtf(norm) : rsqrtf(norm);
                u16* p = &xb[co * 64 + px];
                *p = f2b(b2f(*p) * rr);
            }
    __syncthreads();

#pragma unroll
    for (int it = 0; it < 16; ++it) {
        int v = it * 256 + tid;
        int ch = v >> 4, pxg = (v & 15) * 4;
        *(u64t*)&xg[(size_t)ch * RS + pxg] = *(const u64t*)&xb[v * 4];
    }
}

// ---------------------------------------------------------------------------
// MFMA ConvTranspose2d k=5 s=2, 8x8 -> 16x16, 256->256, input d1 bf16,
// out bf16 QUADRANT-PLANAR d2[b][q][co][sp]. Same af double-buffer prefetch.
// ---------------------------------------------------------------------------
__global__ __launch_bounds__(256)
void mdeconv2(const u16* __restrict__ in, const u16* __restrict__ A2,
              const float* __restrict__ bias, u16* __restrict__ out)
{
    constexpr int STRIDE = 264;
    __shared__ u16 bs[100 * STRIDE];
    __shared__ u16 os[256 * 64];
    const int b = blockIdx.x, tid = threadIdx.x;
    const int lane = tid & 63, wv = tid >> 6, lm = lane & 15, quad = lane >> 4;
    const int cob = wv * 64;
    const u16* inb = in + (size_t)b * 256 * 64;

    unsigned* bz = (unsigned*)bs;
    for (int i = tid; i < 100 * STRIDE / 2; i += 256) bz[i] = 0u;
    __syncthreads();
    for (int i = tid; i < 64 * 64; i += 256) {
        int px = i & 63, cg = i >> 6;
        int iy = px >> 3, ix = px & 7;
        const u16* ip = inb + (size_t)cg * 4 * 64 + px;
        u16x4 p;
        p.x0 = ip[0]; p.x1 = ip[64]; p.x2 = ip[128]; p.x3 = ip[192];
        *(u16x4*)&bs[((iy + 1) * 10 + ix + 1) * STRIDE + cg * 4] = p;
    }
    __syncthreads();

    int bofs[4];
#pragma unroll
    for (int nt = 0; nt < 4; ++nt) {
        int sp = nt * 16 + lm, sy = sp >> 3, sx = sp & 7;
        bofs[nt] = ((sy + 2) * 10 + sx + 2) * STRIDE + quad * 8;
    }

#pragma unroll
    for (int qy = 0; qy < 2; ++qy)
#pragma unroll
        for (int qx = 0; qx < 2; ++qx) {
            const int q = qy * 2 + qx;
            const int W = 3 - qx;                  // compile-time (unrolled)
            const int NT = (3 - qy) * W;
            const int NITq = NT * 8;               // even
            f32x4 acc[4][4];
#pragma unroll
            for (int m = 0; m < 4; ++m)
#pragma unroll
                for (int n = 0; n < 4; ++n) acc[m][n] = (f32x4){0.f, 0.f, 0.f, 0.f};

            const u16* Ar[4];
#pragma unroll
            for (int m = 0; m < 4; ++m)
                Ar[m] = A2 + (size_t)(q * 9) * 65536 + quad * 8 + (size_t)(cob + m * 16 + lm) * 256;

            bf16x8 af0[4], af1[4];
#pragma unroll
            for (int m = 0; m < 4; ++m) af0[m] = *(const bf16x8*)(Ar[m]);  // it=0

#pragma unroll 1
            for (int it = 0; it < NITq; it += 2) {
                const int itB = it + 1;
                const int ttB = itB >> 3, kcB = itB & 7;
                const int tyB = ttB / W, txB = ttB % W;
                const size_t oB = (size_t)(tyB * 3 + txB) * 65536 + kcB * 32;
#pragma unroll
                for (int m = 0; m < 4; ++m) af1[m] = *(const bf16x8*)(Ar[m] + oB);
                {
                    const int tt = it >> 3, kc = it & 7;
                    const int ty = tt / W, tx = tt % W;
                    const int boff = -(ty * 10 + tx) * STRIDE + kc * 32;
                    bf16x8 bf[4];
#pragma unroll
                    for (int nt = 0; nt < 4; ++nt)
                        bf[nt] = *(const bf16x8*)&bs[bofs[nt] + boff];
#pragma unroll
                    for (int m = 0; m < 4; ++m)
#pragma unroll
                        for (int nt = 0; nt < 4; ++nt)
                            acc[m][nt] = __builtin_amdgcn_mfma_f32_16x16x32_bf16(af0[m], bf[nt], acc[m][nt], 0, 0, 0);
                }
                if (it + 2 < NITq) {
                    const int ttC = (it + 2) >> 3, kcC = (it + 2) & 7;
                    const int tyC = ttC / W, txC = ttC % W;
                    const size_t oC = (size_t)(tyC * 3 + txC) * 65536 + kcC * 32;
#pragma unroll
                    for (int m = 0; m < 4; ++m) af0[m] = *(const bf16x8*)(Ar[m] + oC);
                }
                {
                    const int boff = -(tyB * 10 + txB) * STRIDE + kcB * 32;
                    bf16x8 bf[4];
#pragma unroll
                    for (int nt = 0; nt < 4; ++nt)
                        bf[nt] = *(const bf16x8*)&bs[bofs[nt] + boff];
#pragma unroll
                    for (int m = 0; m < 4; ++m)
#pragma unroll
                        for (int nt = 0; nt < 4; ++nt)
                            acc[m][nt] = __builtin_amdgcn_mfma_f32_16x16x32_bf16(af1[m], bf[nt], acc[m][nt], 0, 0, 0);
                }
            }
            // bounce fragments -> LDS -> contiguous u32-pair -> u64 stores
#pragma unroll
            for (int m = 0; m < 4; ++m)
#pragma unroll
                for (int nt = 0; nt < 4; ++nt)
#pragma unroll
                    for (int r = 0; r < 4; ++r) {
                        int co = cob + m * 16 + quad * 4 + r;
                        os[co * 64 + nt * 16 + lm] = f2b(acc[m][nt][r] + bias[co]);
                    }
            __syncthreads();
            u16* od = out + ((size_t)(b * 4 + q)) * 256 * 64;
            const unsigned* osw = (const unsigned*)os;
#pragma unroll
            for (int it = 0; it < 16; ++it) {
                int v = it * 256 + tid;
                unsigned lo = osw[v * 2], hi = osw[v * 2 + 1];
                *(u64t*)&od[v * 4] = (u64t)lo | ((u64t)hi << 32);
            }
            __syncthreads();
        }
}

// ---------------------------------------------------------------------------
// deconv3 (VALU): ConvTranspose2d s2, 256->2, 16x16 -> 32x32, clip [0,1].
// Input d2 bf16 QUADRANT-PLANAR [b][q][ci][sp]. f32 dword output stores.
// ---------------------------------------------------------------------------
__global__ __launch_bounds__(256)
void dec3k(const u16* __restrict__ in, const float* __restrict__ W3r,
           const float* __restrict__ bias, float* __restrict__ out)
{
    constexpr int HT = 18;
    __shared__ float ls[32 * HT * HT];
    const int b = blockIdx.x, tid = threadIdx.x;
    const int sy = tid >> 4, sx = tid & 15;
    const u16* inb = in + (size_t)b * 4 * 256 * 64;
    float acc[4][2] = {};
#pragma unroll 1
    for (int ch = 0; ch < 8; ++ch) {
        if (ch) __syncthreads();
        for (int i = tid; i < 32 * HT * HT; i += 256) ls[i] = 0.f;
        __syncthreads();
        for (int i = tid; i < 32 * 256; i += 256) {
            int ci = i >> 8, px = i & 255, iy = px >> 4, ix = px & 15;
            int q = (iy & 1) * 2 + (ix & 1);
            int sp = (iy >> 1) * 8 + (ix >> 1);
            ls[ci * (HT * HT) + (iy + 1) * HT + ix + 1] =
                b2f(inb[((size_t)q * 256 + ch * 32 + ci) * 64 + sp]);
        }
        __syncthreads();
#pragma unroll 1
        for (int ci = 0; ci < 32; ++ci) {
            float v[9];
            const float* l = &ls[ci * (HT * HT) + (sy + 2) * HT + sx + 2];
#pragma unroll
            for (int ty = 0; ty < 3; ++ty)
#pragma unroll
                for (int tx = 0; tx < 3; ++tx) v[ty * 3 + tx] = l[-(ty * HT) - tx];
#pragma unroll
            for (int q = 0; q < 4; ++q) {
                const float* wp = W3r + (size_t)ufl(((q * 256 + ch * 32 + ci) * 2) * 16);
#pragma unroll
                for (int t = 0; t < 9; ++t) {
                    acc[q][0] = fmaf(wp[t], v[t], acc[q][0]);
                    acc[q][1] = fmaf(wp[16 + t], v[t], acc[q][1]);
                }
            }
        }
    }
    float* ob = out + (size_t)b * 2 * 1024;
#pragma unroll
    for (int q = 0; q < 4; ++q) {
        int qy = q >> 1, qx = q & 1;
        int oy = 2 * sy + qy, ox = 2 * sx + qx;
#pragma unroll
        for (int co = 0; co < 2; ++co) {
            float r = acc[q][co] + bias[co];
            r = fminf(fmaxf(r, 0.f), 1.f);
            ob[(size_t)co * 1024 + oy * 32 + ox] = r;
        }
    }
}

// ---------------------------------------------------------------------------
// conv1: direct conv (CIN=2). bf16 output bounced through LDS -> u32-pair ->
// u64 stores. Only instantiated with PX==256, NCOG==1.
// ---------------------------------------------------------------------------
template<int CIN, int COUT, int HIN, int WIN, int S, int CI_CHUNK, int CO_PER_BLOCK>
__global__ __launch_bounds__(256)
void conv5k(const float* __restrict__ in, const float* __restrict__ wt,
            const float* __restrict__ bias, u16* __restrict__ out)
{
    constexpr int HOUT = HIN / S, WOUT = WIN / S;
    constexpr int PX = HOUT * WOUT;          // 256
    constexpr int CO_ITERS = CO_PER_BLOCK;   // 16
    constexpr int HT = HIN + 4, WT = WIN + 4;
    constexpr int NCHUNK = CIN / CI_CHUNK;
    constexpr int TILE = CI_CHUNK * HT * WT;

    __shared__ float lds[TILE];
    __shared__ u16 os[CO_PER_BLOCK * PX];

    const int b = blockIdx.x;
    const int co_base = blockIdx.y * CO_PER_BLOCK;
    const int tid = threadIdx.x;
    const int px = tid;
    const int oy = px / WOUT, ox = px % WOUT;

    float acc[CO_ITERS];
#pragma unroll
    for (int i = 0; i < CO_ITERS; ++i) acc[i] = 0.f;

    const float* inb = in + (size_t)b * CIN * HIN * WIN;

#pragma unroll 1
    for (int ch = 0; ch < NCHUNK; ++ch) {
        if (ch) __syncthreads();
        for (int idx = tid; idx < TILE; idx += 256) lds[idx] = 0.f;
        __syncthreads();
        for (int idx = tid; idx < CI_CHUNK * HIN * WIN; idx += 256) {
            int ci = idx / (HIN * WIN);
            int r = idx - ci * (HIN * WIN);
            int iy = r / WIN, ix = r - iy * WIN;
            lds[ci * (HT * WT) + (iy + 2) * WT + (ix + 2)] =
                inb[(size_t)(ch * CI_CHUNK + ci) * (HIN * WIN) + r];
        }
        __syncthreads();

#pragma unroll 1
        for (int ci = 0; ci < CI_CHUNK; ++ci) {
            float v[25];
            const float* l = &lds[ci * (HT * WT) + (oy * S) * WT + (ox * S)];
#pragma unroll
            for (int ky = 0; ky < 5; ++ky)
#pragma unroll
                for (int kx = 0; kx < 5; ++kx)
                    v[ky * 5 + kx] = l[ky * WT + kx];
#pragma unroll
            for (int i = 0; i < CO_ITERS; ++i) {
                const int co = co_base + i;
                const float* wp = wt + (size_t)ufl((co * CIN + ch * CI_CHUNK + ci) * 25);
#pragma unroll
                for (int t = 0; t < 25; ++t) acc[i] = fmaf(wp[t], v[t], acc[i]);
            }
        }
    }

#pragma unroll
    for (int i = 0; i < CO_ITERS; ++i)
        os[i * PX + px] = f2b(acc[i] + bias[co_base + i]);
    __syncthreads();
    u16* ob = out + ((size_t)b * COUT + co_base) * PX;
    const unsigned* osw = (const unsigned*)os;
#pragma unroll
    for (int it = 0; it < CO_PER_BLOCK * PX / 1024; ++it) {
        int v = it * 256 + tid;
        unsigned lo = osw[v * 2], hi = osw[v * 2 + 1];
        *(u64t*)&ob[v * 4] = (u64t)lo | ((u64t)hi << 32);
    }
}

// ---------------------------------------------------------------------------
// Fused context model (unchanged, verified).
// ---------------------------------------------------------------------------
__global__ __launch_bounds__(256)
void trik(float* __restrict__ y, const float* __restrict__ noise,
          const float* __restrict__ H, const float* __restrict__ mean,
          const float* __restrict__ scale, float* __restrict__ lik)
{
    __shared__ float h[64 * 65];
    const int c = blockIdx.x;
    const int bt = blockIdx.y;
    const int tid = threadIdx.x;
    const int lane = tid & 63;
    const int wv = tid >> 6;

    const float* Hc = H + (size_t)c * 4096;
    for (int idx = tid; idx < 4096; idx += 256) {
        const int i = idx >> 6, j = idx & 63;
        h[i * 65 + j] = Hc[idx];
    }
    __syncthreads();

    const int b = bt * 4 + wv;
    const size_t base = ((size_t)b * 320 + c) * 64 + lane;
    const float* hrow = &h[lane * 65];

    const float yv = y[base];
    float ws = 0.f;
#pragma unroll 8
    for (int j = 0; j < 64; ++j) {
        const float yj = __shfl(yv, j, 64);
        const float hv = (j < lane) ? hrow[j] : 0.f;
        ws = fmaf(hv, yj, ws);
    }
    const float wh = yv - ws + noise[base];

    const float mn = mean[c * 64 + lane];
    const float sc = fmaxf(scale[c * 64 + lane], 0.11f);
    const float vv = fabsf(wh - mn);
    const float cst = -0.70710678118654752f;
    const float upper = 0.5f * erfcf(cst * (0.5f - vv) / sc);
    const float lower = 0.5f * erfcf(cst * (-0.5f - vv) / sc);
    lik[base] = fmaxf(upper - lower, 1e-9f);

    float acc = wh;
#pragma unroll 8
    for (int j = 0; j < 64; ++j) {
        const float yj = __shfl(acc, j, 64);
        const float hv = (j < lane) ? hrow[j] : 0.f;
        acc = fmaf(hv, yj, acc);
    }
    y[base] = acc;
}

// ---------------------------------------------------------------------------
extern "C" void kernel_launch(void* const* d_in, const int* in_sizes, int n_in,
                              void* d_out, int out_size, void* d_ws, size_t ws_size,
                              hipStream_t stream)
{
    (void)in_sizes; (void)n_in; (void)out_size; (void)ws_size;

    const float* x      = (const float*)d_in[0];
    const float* noise  = (const float*)d_in[1];
    const float* w1     = (const float*)d_in[2];
    const float* b1     = (const float*)d_in[3];
    const float* beta1  = (const float*)d_in[4];
    const float* gamma1 = (const float*)d_in[5];
    const float* w2     = (const float*)d_in[6];
    const float* b2     = (const float*)d_in[7];
    const float* beta2  = (const float*)d_in[8];
    const float* gamma2 = (const float*)d_in[9];
    const float* w3     = (const float*)d_in[10];
    const float* b3     = (const float*)d_in[11];
    const float* dw1    = (const float*)d_in[12];
    const float* db1    = (const float*)d_in[13];
    const float* ibeta1 = (const float*)d_in[14];
    const float* igamma1= (const float*)d_in[15];
    const float* dw2    = (const float*)d_in[16];
    const float* db2    = (const float*)d_in[17];
    const float* ibeta2 = (const float*)d_in[18];
    const float* igamma2= (const float*)d_in[19];
    const float* dw3    = (const float*)d_in[20];
    const float* db3    = (const float*)d_in[21];
    const float* mean   = (const float*)d_in[22];
    const float* scale  = (const float*)d_in[23];
    const float* H      = (const float*)d_in[24];

    float* outp = (float*)d_out;
    float* xhat = outp;                                   // [1024,2,32,32]
    float* lik  = outp + (size_t)1024 * 2 * 32 * 32;      // [1024,320,64]

    // workspace layout:
    //   [0, 134.2M)        a1 bf16 -> y f32 -> d2 bf16 (quadrant-planar)
    //   [134.2M, 167.8M)   a2 bf16 -> d1 bf16  (33.5 MB)
    //   [167.8M, 168.3M)   repacked gammas (4 x 128 KB, live whole call)
    //   [201.3M, 217.8M)   repacked conv weights (live whole call)
    char* ws = (char*)d_ws;
    u16*   a1  = (u16*)ws;
    float* y   = (float*)ws;
    u16*   d2  = (u16*)ws;
    u16*   a2  = (u16*)(ws + 134217728);
    u16*   d1  = (u16*)(ws + 134217728);
    u16*   Ag1 = (u16*)(ws + 167772160);
    u16*   Ag2 = (u16*)(ws + 167903232);
    u16*   Ag3 = (u16*)(ws + 168034304);
    u16*   Ag4 = (u16*)(ws + 168165376);
    u16*   Ac2 = (u16*)(ws + 201326592);
    u16*   Ac3 = (u16*)(ws + 204603392);
    u16*   Ad1 = (u16*)(ws + 208699392);
    u16*   Ad2 = (u16*)(ws + 212795392);
    float* W3r = (float*)(ws + 217513984);

    // ---- weight repacks ----
    rk_fwd<256, 256><<<3200, 256, 0, stream>>>(w2, Ac2);
    rk_fwd<256, 320><<<4000, 256, 0, stream>>>(w3, Ac3);
    rk_d1<<<4000, 256, 0, stream>>>(dw1, Ad1);
    rk_d2<<<4608, 256, 0, stream>>>(dw2, Ad2);
    rk_d3<<<128, 256, 0, stream>>>(dw3, W3r);
    rk_g<<<128, 256, 0, stream>>>(gamma1, Ag1);
    rk_g<<<128, 256, 0, stream>>>(gamma2, Ag2);
    rk_g<<<128, 256, 0, stream>>>(igamma1, Ag3);
    rk_g<<<128, 256, 0, stream>>>(igamma2, Ag4);

    // ---- analysis ----
    conv5k<2, 256, 32, 32, 2, 2, 16><<<dim3(1024, 16), 256, 0, stream>>>(x, w1, b1, a1);
    gdnm<false, 65536, 64, 256><<<dim3(1024, 4), 256, 0, stream>>>(a1, beta1, Ag1);
    mconv<256, 256, 2, 4, u16, u16><<<1024, 256, 0, stream>>>(a1, Ac2, b2, a2);
    gdnm<false, 16384, 16384, 64><<<dim3(1024, 1), 256, 0, stream>>>(a2, beta2, Ag2);
    mconv<256, 320, 1, 5, u16, float><<<1024, 256, 0, stream>>>(a2, Ac3, b3, y);

    // ---- context model ----
    trik<<<dim3(320, 256), 256, 0, stream>>>(y, noise, H, mean, scale, lik);

    // ---- synthesis ----
    mconv<320, 256, 1, 4, float, u16><<<1024, 256, 0, stream>>>(y, Ad1, db1, d1);
    gdnm<true, 16384, 16384, 64><<<dim3(1024, 1), 256, 0, stream>>>(d1, ibeta1, Ag3);
    mdeconv2<<<1024, 256, 0, stream>>>(d1, Ad2, db2, d2);
    gdnm<true, 65536, 16384, 64><<<dim3(1024, 4), 256, 0, stream>>>(d2, ibeta2, Ag4);
    dec3k<<<1024, 256, 0, stream>>>(d2, W3r, db3, xhat);
}

// Round 8
// 3035.628 us; speedup vs baseline: 3.1586x; 1.1418x over previous
//
#include <hip/hip_runtime.h>
#include <math.h>

typedef unsigned short u16;
typedef unsigned long long u64t;
typedef __bf16 bf16x8 __attribute__((ext_vector_type(8)));
typedef float f32x4 __attribute__((ext_vector_type(4)));
struct alignas(8) u16x4 { u16 x0, x1, x2, x3; };

__device__ __forceinline__ int ufl(int v) { return __builtin_amdgcn_readfirstlane(v); }
__device__ __forceinline__ u16 f2b(float f) {
    unsigned u = __float_as_uint(f);
    return (u16)((u + 0x7FFFu + ((u >> 16) & 1u)) >> 16);   // RNE fp32->bf16
}
__device__ __forceinline__ float b2f(u16 h) { return __uint_as_float(((unsigned)h) << 16); }
__device__ __forceinline__ u16 tob(float v) { return f2b(v); }
__device__ __forceinline__ u16 tob(u16 v)   { return v; }

// ---------------------------------------------------------------------------
// SESSION LEDGER (counter evidence):
//  * r0-r2: WRITE_SIZE 66x amp was scratch SPILL (acc[64] @ VGPR 64), not
//    store width. Fix confirmed r4. ALWAYS check VGPR vs per-thread arrays.
//  * r3 lesson: u64 = FOUR u16. Verify copy-loop element counts.
//  * r4->r5: GDN moved to MFMA (gdnm) -> off critical path. 5597->3808.
//  * r5->r7: mconv af reg-double-buffer: 3808->3466 (partial; predicted more).
//  * r7: trik 664us: VALUBusy 53%, occ 91%, HBM 5% -> shuffle-serial bound.
//    2x 64-iter __shfl loops (loop2 = sequential forward substitution chain)
//    per (b,c); 42M ds_bpermute total, 20x off the 34us VALU floor.
//    Fix (this round): precompute Minv=(I-L)^-1 per channel once (rk_inv),
//    batch both context matvecs into 64x64x64 MFMA GEMMs per (c, 64b tile)
//    (trik_m). Identity part stays f32-exact; only L*Y and (Minv-I)*W_hat
//    corrections pass through bf16 (~1e-3 perturbation, thr 2e-2).
// ---------------------------------------------------------------------------

// ---------------------------------------------------------------------------
// Weight repacks (paired u32 stores).
// ---------------------------------------------------------------------------
// forward conv: W[COUT][CIN][25] f32 -> A[25][COUT][CIN] bf16 (ci pairs)
template<int CIN, int COUT>
__global__ __launch_bounds__(256) void rk_fwd(const float* __restrict__ w, u16* __restrict__ a) {
    int j = (blockIdx.x * 256 + threadIdx.x) * 2;
    if (j >= 25 * COUT * CIN) return;
    int ci = j % CIN; int r = j / CIN; int co = r % COUT; int t = r / COUT;
    u16 lo = f2b(w[(co * CIN + ci) * 25 + t]);
    u16 hi = f2b(w[(co * CIN + ci + 1) * 25 + t]);
    *(unsigned*)&a[j] = (unsigned)lo | ((unsigned)hi << 16);
}
// deconv1 (s1 gather): W[320ci][256co][25] -> A[t'][256co][320ci], t'=(4-ky)*5+(4-kx)
__global__ __launch_bounds__(256) void rk_d1(const float* __restrict__ w, u16* __restrict__ a) {
    int j = (blockIdx.x * 256 + threadIdx.x) * 2;
    if (j >= 25 * 256 * 320) return;
    int ci = j % 320; int r = j / 320; int co = r % 256; int tp = r / 256;
    int ky = 4 - tp / 5, kx = 4 - tp % 5;
    u16 lo = f2b(w[(ci * 256 + co) * 25 + ky * 5 + kx]);
    u16 hi = f2b(w[((ci + 1) * 256 + co) * 25 + ky * 5 + kx]);
    *(unsigned*)&a[j] = (unsigned)lo | ((unsigned)hi << 16);
}
// deconv2 (s2 parity): W[256ci][256co][25] -> A2[q*9+tt][256co][256ci], zero invalid taps
__global__ __launch_bounds__(256) void rk_d2(const float* __restrict__ w, u16* __restrict__ a) {
    int j = (blockIdx.x * 256 + threadIdx.x) * 2;
    if (j >= 36 * 256 * 256) return;
    int ci = j % 256; int r = j / 256; int co = r % 256; int qt = r / 256;
    int q = qt / 9, tt = qt % 9;
    int qy = q >> 1, qx = q & 1, ty = tt / 3, tx = tt % 3;
    u16 lo = 0, hi = 0;
    if (ty < 3 - qy && tx < 3 - qx) {
        int widx = (qy + 2 * ty) * 5 + (qx + 2 * tx);
        lo = f2b(w[(ci * 256 + co) * 25 + widx]);
        hi = f2b(w[((ci + 1) * 256 + co) * 25 + widx]);
    }
    *(unsigned*)&a[j] = (unsigned)lo | ((unsigned)hi << 16);
}
// deconv3: W[256ci][2co][25] f32 -> W3r[4q][256ci][2co][16] f32 (9 taps zero-padded)
__global__ __launch_bounds__(256) void rk_d3(const float* __restrict__ w, float* __restrict__ a) {
    int i = blockIdx.x * 256 + threadIdx.x;
    if (i >= 4 * 256 * 2 * 16) return;
    int t = i % 16; int r = i / 16; int co = r % 2; int r2 = r / 2; int ci = r2 % 256; int q = r2 / 256;
    int qy = q >> 1, qx = q & 1;
    float v = 0.f;
    if (t < 9) {
        int ty = t / 3, tx = t % 3;
        if (ty < 3 - qy && tx < 3 - qx) v = w[(ci * 2 + co) * 25 + (qy + 2 * ty) * 5 + (qx + 2 * tx)];
    }
    a[i] = v;
}
// GDN gamma: f32 [256co][256ci] -> bf16 [co][ci] (ci pairs)
__global__ __launch_bounds__(256) void rk_g(const float* __restrict__ g, u16* __restrict__ a) {
    int j = (blockIdx.x * 256 + threadIdx.x) * 2;
    if (j >= 256 * 256) return;
    u16 lo = f2b(g[j]);
    u16 hi = f2b(g[j + 1]);
    *(unsigned*)&a[j] = (unsigned)lo | ((unsigned)hi << 16);
}
// context H: f32 [320c][64i][64j] -> bf16 strictly-lower-masked, row-major
__global__ __launch_bounds__(256) void rk_hb(const float* __restrict__ H, u16* __restrict__ a) {
    int p = blockIdx.x * 256 + threadIdx.x;   // pair index
    if (p >= 320 * 2048) return;
    int j2 = (p & 31) * 2;
    int r = p >> 5;                           // c*64 + i
    int i = r & 63;
    u16 lo = (j2 < i) ? f2b(H[(size_t)r * 64 + j2]) : (u16)0;
    u16 hi = (j2 + 1 < i) ? f2b(H[(size_t)r * 64 + j2 + 1]) : (u16)0;
    *(unsigned*)&a[(size_t)r * 64 + j2] = (unsigned)lo | ((unsigned)hi << 16);
}
// context inverse: Mb[c] = ((I - H_tril)^{-1} - I) strictly lower, bf16.
// M[i][j] = d_ij + sum_{k<i} L[i][k] M[k][j]; column j is lane-independent
// (lane j only ever reads its own column) -> safe within one warp.
__global__ __launch_bounds__(256)
void rk_inv(const float* __restrict__ H, u16* __restrict__ Mb)
{
    __shared__ float Ls[64 * 68];
    __shared__ float Ms[64 * 68];
    const int c = blockIdx.x, tid = threadIdx.x;
    const float* Hc = H + (size_t)c * 4096;
#pragma unroll
    for (int it = 0; it < 16; ++it) {
        int v = it * 256 + tid;               // [0,4096)
        int i = v >> 6, j = v & 63;
        Ls[i * 68 + j] = (j < i) ? Hc[v] : 0.f;
    }
    __syncthreads();
    if (tid < 64) {
        const int j = tid;
#pragma unroll 1
        for (int i = 0; i < 64; ++i) {
            float s = (i == j) ? 1.f : 0.f;
#pragma unroll 1
            for (int k = 0; k < i; ++k)
                s = fmaf(Ls[i * 68 + k], Ms[k * 68 + j], s);
            Ms[i * 68 + j] = s;
        }
    }
    __syncthreads();
#pragma unroll
    for (int it = 0; it < 8; ++it) {
        int p = it * 256 + tid;               // [0,2048) pairs
        int i = p >> 5, j2 = (p & 31) * 2;
        u16 lo = (j2 < i) ? f2b(Ms[i * 68 + j2]) : (u16)0;
        u16 hi = (j2 + 1 < i) ? f2b(Ms[i * 68 + j2 + 1]) : (u16)0;
        *(unsigned*)&Mb[(size_t)c * 4096 + i * 64 + j2] = (unsigned)lo | ((unsigned)hi << 16);
    }
}

// ---------------------------------------------------------------------------
// MFMA implicit-GEMM conv (k=5 pad=2 stride S in {1,2}), out 8x8 per image.
// Inner loop flattened over it=(tap,kc) with af (global A-fragments) register
// double-buffered one half-iter ahead to hide L2 latency under MFMA.
// TOUT=float: dword stores. TOUT=u16: LDS-bounce epilogue -> u64 stores.
// ---------------------------------------------------------------------------
template<int CIN, int COUT, int S, int MT, typename TIN, typename TOUT>
__global__ __launch_bounds__(256)
void mconv(const TIN* __restrict__ in, const u16* __restrict__ A,
           const float* __restrict__ bias, TOUT* __restrict__ out)
{
    constexpr bool O16 = (sizeof(TOUT) == 2);
    constexpr int HIN = 8 * S, HP = 7 * S + 5, CHUNK = 64, STRIDE = CHUNK + 8;
    constexpr int NCH = CIN / CHUNK;
    constexpr int SP = HP * HP;
    constexpr int BSE = SP * STRIDE;
    constexpr int OSE = O16 ? COUT * 64 : 0;
    constexpr int NIT = 50;                    // 25 taps * KCN, KCN = CHUNK/32 = 2
    __shared__ u16 bs[(BSE > OSE) ? BSE : OSE];

    const int b = blockIdx.x;
    const int tid = threadIdx.x;
    const int lane = tid & 63, wv = tid >> 6;
    const int lm = lane & 15, quad = lane >> 4;
    const int cob = wv * (MT * 16);
    const TIN* inb = in + (size_t)b * CIN * (HIN * HIN);

    int bofs[4];
#pragma unroll
    for (int nt = 0; nt < 4; ++nt) {
        int px = nt * 16 + lm, oy = px >> 3, ox = px & 7;
        bofs[nt] = (S * oy * HP + S * ox) * STRIDE + quad * 8;
    }

    f32x4 acc[MT][4];
#pragma unroll
    for (int m = 0; m < MT; ++m)
#pragma unroll
        for (int n = 0; n < 4; ++n) acc[m][n] = (f32x4){0.f, 0.f, 0.f, 0.f};

#pragma unroll 1
    for (int ch = 0; ch < NCH; ++ch) {
        if (ch) __syncthreads();
        unsigned* bz = (unsigned*)bs;
        for (int i = tid; i < BSE / 2; i += 256) bz[i] = 0u;
        __syncthreads();
        for (int i = tid; i < (CHUNK / 4) * (HIN * HIN); i += 256) {
            int px = i % (HIN * HIN), cg = i / (HIN * HIN);
            int iy = px / HIN, ix = px % HIN;
            const TIN* ip = inb + (size_t)(ch * CHUNK + cg * 4) * (HIN * HIN) + px;
            u16x4 p;
            p.x0 = tob(ip[0]);
            p.x1 = tob(ip[HIN * HIN]);
            p.x2 = tob(ip[2 * HIN * HIN]);
            p.x3 = tob(ip[3 * HIN * HIN]);
            *(u16x4*)&bs[((iy + 2) * HP + ix + 2) * STRIDE + cg * 4] = p;
        }
        __syncthreads();

        // per-m A row base pointers for this ci-chunk
        const u16* Ar[MT];
#pragma unroll
        for (int m = 0; m < MT; ++m)
            Ar[m] = A + ch * CHUNK + quad * 8 + (size_t)(cob + m * 16 + lm) * CIN;

        bf16x8 af0[MT], af1[MT];
#pragma unroll
        for (int m = 0; m < MT; ++m) af0[m] = *(const bf16x8*)(Ar[m]);   // it=0

#pragma unroll 1
        for (int it = 0; it < NIT; it += 2) {
            // prefetch it+1 (same tap, kc=1)
            const int tapB = (it + 1) >> 1, kcB = (it + 1) & 1;
            const size_t oB = (size_t)tapB * (COUT * CIN) + kcB * 32;
#pragma unroll
            for (int m = 0; m < MT; ++m) af1[m] = *(const bf16x8*)(Ar[m] + oB);
            {
                const int tap = it >> 1, kc = it & 1;
                const int tofs = ((tap / 5) * HP + (tap % 5)) * STRIDE + kc * 32;
                bf16x8 bf[4];
#pragma unroll
                for (int nt = 0; nt < 4; ++nt)
                    bf[nt] = *(const bf16x8*)&bs[bofs[nt] + tofs];
#pragma unroll
                for (int m = 0; m < MT; ++m)
#pragma unroll
                    for (int nt = 0; nt < 4; ++nt)
                        acc[m][nt] = __builtin_amdgcn_mfma_f32_16x16x32_bf16(af0[m], bf[nt], acc[m][nt], 0, 0, 0);
            }
            // prefetch it+2 (next tap, kc=0)
            if (it + 2 < NIT) {
                const size_t oC = (size_t)((it + 2) >> 1) * (COUT * CIN);
#pragma unroll
                for (int m = 0; m < MT; ++m) af0[m] = *(const bf16x8*)(Ar[m] + oC);
            }
            {
                const int tofs = ((tapB / 5) * HP + (tapB % 5)) * STRIDE + kcB * 32;
                bf16x8 bf[4];
#pragma unroll
                for (int nt = 0; nt < 4; ++nt)
                    bf[nt] = *(const bf16x8*)&bs[bofs[nt] + tofs];
#pragma unroll
                for (int m = 0; m < MT; ++m)
#pragma unroll
                    for (int nt = 0; nt < 4; ++nt)
                        acc[m][nt] = __builtin_amdgcn_mfma_f32_16x16x32_bf16(af1[m], bf[nt], acc[m][nt], 0, 0, 0);
            }
        }
    }

    if constexpr (O16) {
        __syncthreads();          // all MFMA reads of bs done before reuse
#pragma unroll
        for (int m = 0; m < MT; ++m)
#pragma unroll
            for (int nt = 0; nt < 4; ++nt)
#pragma unroll
                for (int r = 0; r < 4; ++r) {
                    int co = cob + m * 16 + quad * 4 + r;
                    bs[co * 64 + nt * 16 + lm] = f2b(acc[m][nt][r] + bias[co]);
                }
        __syncthreads();
        u16* ob = out + (size_t)b * COUT * 64;
        const unsigned* osw = (const unsigned*)bs;
#pragma unroll
        for (int it = 0; it < COUT / 16; ++it) {
            int v = it * 256 + tid;
            unsigned lo = osw[v * 2], hi = osw[v * 2 + 1];
            *(u64t*)&ob[v * 4] = (u64t)lo | ((u64t)hi << 32);
        }
    } else {
        float* ob = (float*)out + (size_t)b * COUT * 64;
#pragma unroll
        for (int m = 0; m < MT; ++m)
#pragma unroll
            for (int nt = 0; nt < 4; ++nt) {
                int px = nt * 16 + lm;
#pragma unroll
                for (int r = 0; r < 4; ++r) {
                    int co = cob + m * 16 + quad * 4 + r;
                    ob[(size_t)co * 64 + px] = acc[m][nt][r] + bias[co];
                }
            }
    }
}

// ---------------------------------------------------------------------------
// MFMA GDN, all 4 sites (verified r5). Tile = [256ch][64px] bf16, in place.
// ---------------------------------------------------------------------------
template<bool INVERSE, int IMG, int YOFF, int RS>
__global__ __launch_bounds__(256)
void gdnm(u16* __restrict__ x, const float* __restrict__ beta,
          const u16* __restrict__ Ag)
{
    constexpr int STR = 264;
    __shared__ u16 xb[256 * 64];   // original bf16 tile [ch][px]  (32 KB)
    __shared__ u16 xq[64 * STR];   // bf16 squares [px][ci]        (33 KB)
    const int tid = threadIdx.x;
    const int lane = tid & 63, wv = tid >> 6;
    const int lm = lane & 15, quad = lane >> 4;
    const int cob = wv * 64;
    u16* xg = x + (size_t)blockIdx.x * IMG + (size_t)blockIdx.y * YOFF;

#pragma unroll
    for (int it = 0; it < 16; ++it) {
        int v = it * 256 + tid;          // [0,4096)
        int ch = v >> 4, pxg = (v & 15) * 4;
        *(u64t*)&xb[v * 4] = *(const u64t*)&xg[(size_t)ch * RS + pxg];
    }
    __syncthreads();

    // build xq[px][ci] = bf16(x^2); bank-staggered ((w+px)&31) -> conflict-free
    {
        const int px = tid & 63, g = tid >> 6;   // g in [0,4): 64-ci band
#pragma unroll
        for (int w = 0; w < 32; ++w) {
            int ci = g * 64 + ((w + px) & 31) * 2;
            float x0 = b2f(xb[ci * 64 + px]);
            float x1 = b2f(xb[(ci + 1) * 64 + px]);
            unsigned pk = (unsigned)f2b(x0 * x0) | ((unsigned)f2b(x1 * x1) << 16);
            *(unsigned*)&xq[px * STR + ci] = pk;
        }
    }
    __syncthreads();

    f32x4 acc[4][4];
#pragma unroll
    for (int m = 0; m < 4; ++m)
#pragma unroll
        for (int n = 0; n < 4; ++n) acc[m][n] = (f32x4){0.f, 0.f, 0.f, 0.f};

#pragma unroll 1
    for (int kc = 0; kc < 8; ++kc) {
        bf16x8 bf[4];
#pragma unroll
        for (int nt = 0; nt < 4; ++nt)
            bf[nt] = *(const bf16x8*)&xq[(nt * 16 + lm) * STR + kc * 32 + quad * 8];
        bf16x8 af[4];
#pragma unroll
        for (int m = 0; m < 4; ++m)
            af[m] = *(const bf16x8*)(Ag + (size_t)(cob + m * 16 + lm) * 256 + kc * 32 + quad * 8);
#pragma unroll
        for (int m = 0; m < 4; ++m)
#pragma unroll
            for (int nt = 0; nt < 4; ++nt)
                acc[m][nt] = __builtin_amdgcn_mfma_f32_16x16x32_bf16(af[m], bf[nt], acc[m][nt], 0, 0, 0);
    }

    // epilogue: scale xb in place (each cell owned by exactly one lane)
#pragma unroll
    for (int m = 0; m < 4; ++m)
#pragma unroll
        for (int nt = 0; nt < 4; ++nt)
#pragma unroll
            for (int r = 0; r < 4; ++r) {
                int co = cob + m * 16 + quad * 4 + r;
                int px = nt * 16 + lm;
                float norm = acc[m][nt][r] + beta[co];
                float rr = INVERSE ? sqrtf(norm) : rsqrtf(norm);
                u16* p = &xb[co * 64 + px];
                *p = f2b(b2f(*p) * rr);
            }
    __syncthreads();

#pragma unroll
    for (int it = 0; it < 16; ++it) {
        int v = it * 256 + tid;
        int ch = v >> 4, pxg = (v & 15) * 4;
        *(u64t*)&xg[(size_t)ch * RS + pxg] = *(const u64t*)&xb[v * 4];
    }
}

// ---------------------------------------------------------------------------
// MFMA ConvTranspose2d k=5 s=2, 8x8 -> 16x16, 256->256, input d1 bf16,
// out bf16 QUADRANT-PLANAR d2[b][q][co][sp]. Same af double-buffer prefetch.
// ---------------------------------------------------------------------------
__global__ __launch_bounds__(256)
void mdeconv2(const u16* __restrict__ in, const u16* __restrict__ A2,
              const float* __restrict__ bias, u16* __restrict__ out)
{
    constexpr int STRIDE = 264;
    __shared__ u16 bs[100 * STRIDE];
    __shared__ u16 os[256 * 64];
    const int b = blockIdx.x, tid = threadIdx.x;
    const int lane = tid & 63, wv = tid >> 6, lm = lane & 15, quad = lane >> 4;
    const int cob = wv * 64;
    const u16* inb = in + (size_t)b * 256 * 64;

    unsigned* bz = (unsigned*)bs;
    for (int i = tid; i < 100 * STRIDE / 2; i += 256) bz[i] = 0u;
    __syncthreads();
    for (int i = tid; i < 64 * 64; i += 256) {
        int px = i & 63, cg = i >> 6;
        int iy = px >> 3, ix = px & 7;
        const u16* ip = inb + (size_t)cg * 4 * 64 + px;
        u16x4 p;
        p.x0 = ip[0]; p.x1 = ip[64]; p.x2 = ip[128]; p.x3 = ip[192];
        *(u16x4*)&bs[((iy + 1) * 10 + ix + 1) * STRIDE + cg * 4] = p;
    }
    __syncthreads();

    int bofs[4];
#pragma unroll
    for (int nt = 0; nt < 4; ++nt) {
        int sp = nt * 16 + lm, sy = sp >> 3, sx = sp & 7;
        bofs[nt] = ((sy + 2) * 10 + sx + 2) * STRIDE + quad * 8;
    }

#pragma unroll
    for (int qy = 0; qy < 2; ++qy)
#pragma unroll
        for (int qx = 0; qx < 2; ++qx) {
            const int q = qy * 2 + qx;
            const int W = 3 - qx;                  // compile-time (unrolled)
            const int NT = (3 - qy) * W;
            const int NITq = NT * 8;               // even
            f32x4 acc[4][4];
#pragma unroll
            for (int m = 0; m < 4; ++m)
#pragma unroll
                for (int n = 0; n < 4; ++n) acc[m][n] = (f32x4){0.f, 0.f, 0.f, 0.f};

            const u16* Ar[4];
#pragma unroll
            for (int m = 0; m < 4; ++m)
                Ar[m] = A2 + (size_t)(q * 9) * 65536 + quad * 8 + (size_t)(cob + m * 16 + lm) * 256;

            bf16x8 af0[4], af1[4];
#pragma unroll
            for (int m = 0; m < 4; ++m) af0[m] = *(const bf16x8*)(Ar[m]);  // it=0

#pragma unroll 1
            for (int it = 0; it < NITq; it += 2) {
                const int itB = it + 1;
                const int ttB = itB >> 3, kcB = itB & 7;
                const int tyB = ttB / W, txB = ttB % W;
                const size_t oB = (size_t)(tyB * 3 + txB) * 65536 + kcB * 32;
#pragma unroll
                for (int m = 0; m < 4; ++m) af1[m] = *(const bf16x8*)(Ar[m] + oB);
                {
                    const int tt = it >> 3, kc = it & 7;
                    const int ty = tt / W, tx = tt % W;
                    const int boff = -(ty * 10 + tx) * STRIDE + kc * 32;
                    bf16x8 bf[4];
#pragma unroll
                    for (int nt = 0; nt < 4; ++nt)
                        bf[nt] = *(const bf16x8*)&bs[bofs[nt] + boff];
#pragma unroll
                    for (int m = 0; m < 4; ++m)
#pragma unroll
                        for (int nt = 0; nt < 4; ++nt)
                            acc[m][nt] = __builtin_amdgcn_mfma_f32_16x16x32_bf16(af0[m], bf[nt], acc[m][nt], 0, 0, 0);
                }
                if (it + 2 < NITq) {
                    const int ttC = (it + 2) >> 3, kcC = (it + 2) & 7;
                    const int tyC = ttC / W, txC = ttC % W;
                    const size_t oC = (size_t)(tyC * 3 + txC) * 65536 + kcC * 32;
#pragma unroll
                    for (int m = 0; m < 4; ++m) af0[m] = *(const bf16x8*)(Ar[m] + oC);
                }
                {
                    const int boff = -(tyB * 10 + txB) * STRIDE + kcB * 32;
                    bf16x8 bf[4];
#pragma unroll
                    for (int nt = 0; nt < 4; ++nt)
                        bf[nt] = *(const bf16x8*)&bs[bofs[nt] + boff];
#pragma unroll
                    for (int m = 0; m < 4; ++m)
#pragma unroll
                        for (int nt = 0; nt < 4; ++nt)
                            acc[m][nt] = __builtin_amdgcn_mfma_f32_16x16x32_bf16(af1[m], bf[nt], acc[m][nt], 0, 0, 0);
                }
            }
            // bounce fragments -> LDS -> contiguous u32-pair -> u64 stores
#pragma unroll
            for (int m = 0; m < 4; ++m)
#pragma unroll
                for (int nt = 0; nt < 4; ++nt)
#pragma unroll
                    for (int r = 0; r < 4; ++r) {
                        int co = cob + m * 16 + quad * 4 + r;
                        os[co * 64 + nt * 16 + lm] = f2b(acc[m][nt][r] + bias[co]);
                    }
            __syncthreads();
            u16* od = out + ((size_t)(b * 4 + q)) * 256 * 64;
            const unsigned* osw = (const unsigned*)os;
#pragma unroll
            for (int it = 0; it < 16; ++it) {
                int v = it * 256 + tid;
                unsigned lo = osw[v * 2], hi = osw[v * 2 + 1];
                *(u64t*)&od[v * 4] = (u64t)lo | ((u64t)hi << 32);
            }
            __syncthreads();
        }
}

// ---------------------------------------------------------------------------
// deconv3 (VALU): ConvTranspose2d s2, 256->2, 16x16 -> 32x32, clip [0,1].
// Input d2 bf16 QUADRANT-PLANAR [b][q][ci][sp]. f32 dword output stores.
// ---------------------------------------------------------------------------
__global__ __launch_bounds__(256)
void dec3k(const u16* __restrict__ in, const float* __restrict__ W3r,
           const float* __restrict__ bias, float* __restrict__ out)
{
    constexpr int HT = 18;
    __shared__ float ls[32 * HT * HT];
    const int b = blockIdx.x, tid = threadIdx.x;
    const int sy = tid >> 4, sx = tid & 15;
    const u16* inb = in + (size_t)b * 4 * 256 * 64;
    float acc[4][2] = {};
#pragma unroll 1
    for (int ch = 0; ch < 8; ++ch) {
        if (ch) __syncthreads();
        for (int i = tid; i < 32 * HT * HT; i += 256) ls[i] = 0.f;
        __syncthreads();
        for (int i = tid; i < 32 * 256; i += 256) {
            int ci = i >> 8, px = i & 255, iy = px >> 4, ix = px & 15;
            int q = (iy & 1) * 2 + (ix & 1);
            int sp = (iy >> 1) * 8 + (ix >> 1);
            ls[ci * (HT * HT) + (iy + 1) * HT + ix + 1] =
                b2f(inb[((size_t)q * 256 + ch * 32 + ci) * 64 + sp]);
        }
        __syncthreads();
#pragma unroll 1
        for (int ci = 0; ci < 32; ++ci) {
            float v[9];
            const float* l = &ls[ci * (HT * HT) + (sy + 2) * HT + sx + 2];
#pragma unroll
            for (int ty = 0; ty < 3; ++ty)
#pragma unroll
                for (int tx = 0; tx < 3; ++tx) v[ty * 3 + tx] = l[-(ty * HT) - tx];
#pragma unroll
            for (int q = 0; q < 4; ++q) {
                const float* wp = W3r + (size_t)ufl(((q * 256 + ch * 32 + ci) * 2) * 16);
#pragma unroll
                for (int t = 0; t < 9; ++t) {
                    acc[q][0] = fmaf(wp[t], v[t], acc[q][0]);
                    acc[q][1] = fmaf(wp[16 + t], v[t], acc[q][1]);
                }
            }
        }
    }
    float* ob = out + (size_t)b * 2 * 1024;
#pragma unroll
    for (int q = 0; q < 4; ++q) {
        int qy = q >> 1, qx = q & 1;
        int oy = 2 * sy + qy, ox = 2 * sx + qx;
#pragma unroll
        for (int co = 0; co < 2; ++co) {
            float r = acc[q][co] + bias[co];
            r = fminf(fmaxf(r, 0.f), 1.f);
            ob[(size_t)co * 1024 + oy * 32 + ox] = r;
        }
    }
}

// ---------------------------------------------------------------------------
// conv1: direct conv (CIN=2). bf16 output bounced through LDS -> u32-pair ->
// u64 stores. Only instantiated with PX==256, NCOG==1.
// ---------------------------------------------------------------------------
template<int CIN, int COUT, int HIN, int WIN, int S, int CI_CHUNK, int CO_PER_BLOCK>
__global__ __launch_bounds__(256)
void conv5k(const float* __restrict__ in, const float* __restrict__ wt,
            const float* __restrict__ bias, u16* __restrict__ out)
{
    constexpr int HOUT = HIN / S, WOUT = WIN / S;
    constexpr int PX = HOUT * WOUT;          // 256
    constexpr int CO_ITERS = CO_PER_BLOCK;   // 16
    constexpr int HT = HIN + 4, WT = WIN + 4;
    constexpr int NCHUNK = CIN / CI_CHUNK;
    constexpr int TILE = CI_CHUNK * HT * WT;

    __shared__ float lds[TILE];
    __shared__ u16 os[CO_PER_BLOCK * PX];

    const int b = blockIdx.x;
    const int co_base = blockIdx.y * CO_PER_BLOCK;
    const int tid = threadIdx.x;
    const int px = tid;
    const int oy = px / WOUT, ox = px % WOUT;

    float acc[CO_ITERS];
#pragma unroll
    for (int i = 0; i < CO_ITERS; ++i) acc[i] = 0.f;

    const float* inb = in + (size_t)b * CIN * HIN * WIN;

#pragma unroll 1
    for (int ch = 0; ch < NCHUNK; ++ch) {
        if (ch) __syncthreads();
        for (int idx = tid; idx < TILE; idx += 256) lds[idx] = 0.f;
        __syncthreads();
        for (int idx = tid; idx < CI_CHUNK * HIN * WIN; idx += 256) {
            int ci = idx / (HIN * WIN);
            int r = idx - ci * (HIN * WIN);
            int iy = r / WIN, ix = r - iy * WIN;
            lds[ci * (HT * WT) + (iy + 2) * WT + (ix + 2)] =
                inb[(size_t)(ch * CI_CHUNK + ci) * (HIN * WIN) + r];
        }
        __syncthreads();

#pragma unroll 1
        for (int ci = 0; ci < CI_CHUNK; ++ci) {
            float v[25];
            const float* l = &lds[ci * (HT * WT) + (oy * S) * WT + (ox * S)];
#pragma unroll
            for (int ky = 0; ky < 5; ++ky)
#pragma unroll
                for (int kx = 0; kx < 5; ++kx)
                    v[ky * 5 + kx] = l[ky * WT + kx];
#pragma unroll
            for (int i = 0; i < CO_ITERS; ++i) {
                const int co = co_base + i;
                const float* wp = wt + (size_t)ufl((co * CIN + ch * CI_CHUNK + ci) * 25);
#pragma unroll
                for (int t = 0; t < 25; ++t) acc[i] = fmaf(wp[t], v[t], acc[i]);
            }
        }
    }

#pragma unroll
    for (int i = 0; i < CO_ITERS; ++i)
        os[i * PX + px] = f2b(acc[i] + bias[co_base + i]);
    __syncthreads();
    u16* ob = out + ((size_t)b * COUT + co_base) * PX;
    const unsigned* osw = (const unsigned*)os;
#pragma unroll
    for (int it = 0; it < CO_PER_BLOCK * PX / 1024; ++it) {
        int v = it * 256 + tid;
        unsigned lo = osw[v * 2], hi = osw[v * 2 + 1];
        *(u64t*)&ob[v * 4] = (u64t)lo | ((u64t)hi << 32);
    }
}

// ---------------------------------------------------------------------------
// Batched context model (replaces shuffle-serial trik):
// per block (c, 64-b tile):
//   GEMM1: C = H_tril @ Y (MFMA bf16, K=64); w_hat = y(f32) - C + noise(f32)
//   lik from w_hat (f32 erfc path, unchanged math)
//   GEMM2: y_hat = w_hat + (Minv - I) @ bf16(w_hat)   [identity part exact]
// Fragment layout = verified mconv mapping (MT=1): af row co=cob+lm,
// C element (co=cob+quad*4+r, px=nt*16+lm).
// ---------------------------------------------------------------------------
__global__ __launch_bounds__(256)
void trik_m(float* __restrict__ y, const float* __restrict__ noise,
            const u16* __restrict__ Hb, const u16* __restrict__ Mb,
            const float* __restrict__ mean, const float* __restrict__ scale,
            float* __restrict__ lik)
{
    __shared__ float Ysf[64 * 68];   // f32 y tile [b][i]
    __shared__ u16 Yt[64 * 72];      // bf16 B operand [b][k]; reused for W_hat
    const int c = blockIdx.x;
    const int b0 = blockIdx.y * 64;
    const int tid = threadIdx.x;
    const int lane = tid & 63, wv = tid >> 6;
    const int lm = lane & 15, quad = lane >> 4;
    const int cob = wv * 16;

    // stage y -> Ysf (f32) + Yt (bf16)
#pragma unroll
    for (int it = 0; it < 4; ++it) {
        int v = it * 256 + tid;            // [0,1024)
        int b = v >> 4, i0 = (v & 15) * 4;
        f32x4 t = *(const f32x4*)(y + (size_t)(b0 + b) * 20480 + c * 64 + i0);
        *(f32x4*)&Ysf[b * 68 + i0] = t;
        u16x4 p;
        p.x0 = f2b(t[0]); p.x1 = f2b(t[1]); p.x2 = f2b(t[2]); p.x3 = f2b(t[3]);
        *(u16x4*)&Yt[b * 72 + i0] = p;
    }
    __syncthreads();

    // GEMM1: C[i][b] = sum_k H_tril[i][k] * Y[k][b]
    f32x4 acc[4];
#pragma unroll
    for (int nt = 0; nt < 4; ++nt) acc[nt] = (f32x4){0.f, 0.f, 0.f, 0.f};
    const u16* Ha = Hb + (size_t)c * 4096 + (cob + lm) * 64 + quad * 8;
#pragma unroll
    for (int kc = 0; kc < 2; ++kc) {
        bf16x8 af = *(const bf16x8*)(Ha + kc * 32);
#pragma unroll
        for (int nt = 0; nt < 4; ++nt) {
            bf16x8 bf = *(const bf16x8*)&Yt[(nt * 16 + lm) * 72 + kc * 32 + quad * 8];
            acc[nt] = __builtin_amdgcn_mfma_f32_16x16x32_bf16(af, bf, acc[nt], 0, 0, 0);
        }
    }
    __syncthreads();   // all GEMM1 reads of Yt complete before overwrite

    // w_hat (f32, kept in regs) + lik; write bf16 W_hat into Yt
    const int i0 = cob + quad * 4;
    const f32x4 mn4 = *(const f32x4*)(mean + c * 64 + i0);
    const f32x4 sc4 = *(const f32x4*)(scale + c * 64 + i0);
    float whf[4][4];
#pragma unroll
    for (int nt = 0; nt < 4; ++nt) {
        int b = nt * 16 + lm;
        f32x4 nz = *(const f32x4*)(noise + (size_t)(b0 + b) * 20480 + c * 64 + i0);
        f32x4 lk;
#pragma unroll
        for (int r = 0; r < 4; ++r) {
            float wh = Ysf[b * 68 + i0 + r] - acc[nt][r] + nz[r];
            whf[nt][r] = wh;
            const float sc = fmaxf(sc4[r], 0.11f);
            const float vv = fabsf(wh - mn4[r]);
            const float cst = -0.70710678118654752f;
            const float upper = 0.5f * erfcf(cst * (0.5f - vv) / sc);
            const float lower = 0.5f * erfcf(cst * (-0.5f - vv) / sc);
            lk[r] = fmaxf(upper - lower, 1e-9f);
        }
        *(f32x4*)(lik + (size_t)(b0 + b) * 20480 + c * 64 + i0) = lk;
        u16x4 p;
        p.x0 = f2b(whf[nt][0]); p.x1 = f2b(whf[nt][1]);
        p.x2 = f2b(whf[nt][2]); p.x3 = f2b(whf[nt][3]);
        *(u16x4*)&Yt[b * 72 + i0] = p;
    }
    __syncthreads();

    // GEMM2: y_hat = w_hat + (Minv - I) @ W_hat
    f32x4 acc2[4];
#pragma unroll
    for (int nt = 0; nt < 4; ++nt) acc2[nt] = (f32x4){0.f, 0.f, 0.f, 0.f};
    const u16* Ma = Mb + (size_t)c * 4096 + (cob + lm) * 64 + quad * 8;
#pragma unroll
    for (int kc = 0; kc < 2; ++kc) {
        bf16x8 af = *(const bf16x8*)(Ma + kc * 32);
#pragma unroll
        for (int nt = 0; nt < 4; ++nt) {
            bf16x8 bf = *(const bf16x8*)&Yt[(nt * 16 + lm) * 72 + kc * 32 + quad * 8];
            acc2[nt] = __builtin_amdgcn_mfma_f32_16x16x32_bf16(af, bf, acc2[nt], 0, 0, 0);
        }
    }
#pragma unroll
    for (int nt = 0; nt < 4; ++nt) {
        int b = nt * 16 + lm;
        f32x4 yh;
#pragma unroll
        for (int r = 0; r < 4; ++r) yh[r] = whf[nt][r] + acc2[nt][r];
        *(f32x4*)(y + (size_t)(b0 + b) * 20480 + c * 64 + i0) = yh;
    }
}

// ---------------------------------------------------------------------------
extern "C" void kernel_launch(void* const* d_in, const int* in_sizes, int n_in,
                              void* d_out, int out_size, void* d_ws, size_t ws_size,
                              hipStream_t stream)
{
    (void)in_sizes; (void)n_in; (void)out_size; (void)ws_size;

    const float* x      = (const float*)d_in[0];
    const float* noise  = (const float*)d_in[1];
    const float* w1     = (const float*)d_in[2];
    const float* b1     = (const float*)d_in[3];
    const float* beta1  = (const float*)d_in[4];
    const float* gamma1 = (const float*)d_in[5];
    const float* w2     = (const float*)d_in[6];
    const float* b2     = (const float*)d_in[7];
    const float* beta2  = (const float*)d_in[8];
    const float* gamma2 = (const float*)d_in[9];
    const float* w3     = (const float*)d_in[10];
    const float* b3     = (const float*)d_in[11];
    const float* dw1    = (const float*)d_in[12];
    const float* db1    = (const float*)d_in[13];
    const float* ibeta1 = (const float*)d_in[14];
    const float* igamma1= (const float*)d_in[15];
    const float* dw2    = (const float*)d_in[16];
    const float* db2    = (const float*)d_in[17];
    const float* ibeta2 = (const float*)d_in[18];
    const float* igamma2= (const float*)d_in[19];
    const float* dw3    = (const float*)d_in[20];
    const float* db3    = (const float*)d_in[21];
    const float* mean   = (const float*)d_in[22];
    const float* scale  = (const float*)d_in[23];
    const float* H      = (const float*)d_in[24];

    float* outp = (float*)d_out;
    float* xhat = outp;                                   // [1024,2,32,32]
    float* lik  = outp + (size_t)1024 * 2 * 32 * 32;      // [1024,320,64]

    // workspace layout:
    //   [0, 134.2M)        a1 bf16 -> y f32 -> d2 bf16 (quadrant-planar)
    //   [134.2M, 167.8M)   a2 bf16 -> d1 bf16  (33.5 MB)
    //   [167.8M, 168.3M)   repacked gammas (4 x 128 KB)
    //   [168.3M, 173.6M)   Hb, Mb (context bf16 mats, 2 x 2.62 MB)
    //   [201.3M, 217.8M)   repacked conv weights
    char* ws = (char*)d_ws;
    u16*   a1  = (u16*)ws;
    float* y   = (float*)ws;
    u16*   d2  = (u16*)ws;
    u16*   a2  = (u16*)(ws + 134217728);
    u16*   d1  = (u16*)(ws + 134217728);
    u16*   Ag1 = (u16*)(ws + 167772160);
    u16*   Ag2 = (u16*)(ws + 167903232);
    u16*   Ag3 = (u16*)(ws + 168034304);
    u16*   Ag4 = (u16*)(ws + 168165376);
    u16*   Hb  = (u16*)(ws + 168296448);
    u16*   Mb  = (u16*)(ws + 170917888);
    u16*   Ac2 = (u16*)(ws + 201326592);
    u16*   Ac3 = (u16*)(ws + 204603392);
    u16*   Ad1 = (u16*)(ws + 208699392);
    u16*   Ad2 = (u16*)(ws + 212795392);
    float* W3r = (float*)(ws + 217513984);

    // ---- weight repacks ----
    rk_fwd<256, 256><<<3200, 256, 0, stream>>>(w2, Ac2);
    rk_fwd<256, 320><<<4000, 256, 0, stream>>>(w3, Ac3);
    rk_d1<<<4000, 256, 0, stream>>>(dw1, Ad1);
    rk_d2<<<4608, 256, 0, stream>>>(dw2, Ad2);
    rk_d3<<<128, 256, 0, stream>>>(dw3, W3r);
    rk_g<<<128, 256, 0, stream>>>(gamma1, Ag1);
    rk_g<<<128, 256, 0, stream>>>(gamma2, Ag2);
    rk_g<<<128, 256, 0, stream>>>(igamma1, Ag3);
    rk_g<<<128, 256, 0, stream>>>(igamma2, Ag4);
    rk_hb<<<2560, 256, 0, stream>>>(H, Hb);
    rk_inv<<<320, 256, 0, stream>>>(H, Mb);

    // ---- analysis ----
    conv5k<2, 256, 32, 32, 2, 2, 16><<<dim3(1024, 16), 256, 0, stream>>>(x, w1, b1, a1);
    gdnm<false, 65536, 64, 256><<<dim3(1024, 4), 256, 0, stream>>>(a1, beta1, Ag1);
    mconv<256, 256, 2, 4, u16, u16><<<1024, 256, 0, stream>>>(a1, Ac2, b2, a2);
    gdnm<false, 16384, 16384, 64><<<dim3(1024, 1), 256, 0, stream>>>(a2, beta2, Ag2);
    mconv<256, 320, 1, 5, u16, float><<<1024, 256, 0, stream>>>(a2, Ac3, b3, y);

    // ---- context model (batched MFMA form) ----
    trik_m<<<dim3(320, 16), 256, 0, stream>>>(y, noise, Hb, Mb, mean, scale, lik);

    // ---- synthesis ----
    mconv<320, 256, 1, 4, float, u16><<<1024, 256, 0, stream>>>(y, Ad1, db1, d1);
    gdnm<true, 16384, 16384, 64><<<dim3(1024, 1), 256, 0, stream>>>(d1, ibeta1, Ag3);
    mdeconv2<<<1024, 256, 0, stream>>>(d1, Ad2, db2, d2);
    gdnm<true, 65536, 16384, 64><<<dim3(1024, 4), 256, 0, stream>>>(d2, ibeta2, Ag4);
    dec3k<<<1024, 256, 0, stream>>>(d2, W3r, db3, xhat);
}